// Round 13
// baseline (1409.023 us; speedup 1.0000x reference)
//
#include <hip/hip_runtime.h>
#include <hip/hip_bf16.h>

// FFT-tiled conv: B=8, IMG=256, CIN=COUT=64, TILE=64, FFT=68, PAD=2.
// Frequency-domain per-tile conv via DFT-as-matmul, Hermitian half-spectrum
// (k2 in [0,35)), direct overlap-add (plain stores interior, atomics on seams,
// seam bands pre-zeroed). All fp32. Register-blocked outer-product sweeps.
//
// Layouts (per 16-tile chunk slot of CHS floats):
//   Y  [nl][k2][r][i][c]      in bufA     ((nl*35+k2)*64+r)*128
//   X  [nl][k1][k2][i][c]     in bufB     ((nl*68+k1)*35+k2)*128
//   K_t[bin][i][o][c]         78 MB, one-time (bin = k1*35+k2)
//   O  [nl][k2][k1][o][c]     in bufA     ((nl*35+k2)*68+k1)*128
//   Z  [nl][p][k2][o][c]      in bufB     ((nl*68+p)*35+k2)*128
//
// Twiddle tables (zero-padded for fixed-trip register blocking):
//   Wf  [72][64] cplx   rows 68..71 zero      (9216 floats)
//   Wi2 [2][40][68] cplx rows pl=34..39 zero  (10880 floats)
//   Wg  [68][35] cplx                          (4760 floats)

#define KH   35
#define CHS  4874240ull                       // floats per chunk slot
#define KT_FLOATS (68ull * KH * 64 * 64 * 2)  // 19,496,960
#define WS_HEAD 24856ull                      // 9216 + 10880 + 4760

__global__ void k_twiddle(float* ws) {
    const float TWO_PI = 6.28318530717958647692f;
    int t = threadIdx.x;
    float* Wf = ws;                       // 72 x 64 cplx
    for (int e = t; e < 72 * 64; e += 256) {
        int k = e >> 6, m = e & 63;
        float vr = 0.f, vi = 0.f;
        if (k < 68) {
            int ph = (k * (m + 2)) % 68;
            float a = TWO_PI * (float)ph / 68.0f;
            vr = cosf(a); vi = -sinf(a);
        }
        Wf[2 * e] = vr; Wf[2 * e + 1] = vi;
    }
    float* Wi2 = ws + 9216;               // 2 x 40 x 68 cplx
    for (int e = t; e < 2 * 40 * 68; e += 256) {
        int hp = e / 2720, rem2 = e % 2720;
        int pl = rem2 / 68, k = rem2 % 68;
        float vr = 0.f, vi = 0.f;
        if (pl < 34) {
            int p = hp * 34 + pl;
            int ph = (p * k) % 68;
            float a = TWO_PI * (float)ph / 68.0f;
            vr = cosf(a) / 68.0f; vi = sinf(a) / 68.0f;
        }
        Wi2[2 * e] = vr; Wi2[2 * e + 1] = vi;
    }
    float* Wg = ws + 20096;               // 68 x 35 cplx
    for (int e = t; e < 68 * KH; e += 256) {
        int q = e / KH, k2 = e % KH;
        int ph = (q * k2) % 68;
        float a = TWO_PI * (float)ph / 68.0f;
        float alpha = (k2 == 0 || k2 == 34) ? 1.0f : 2.0f;
        Wg[2 * e]     = alpha * cosf(a) / 68.0f;
        Wg[2 * e + 1] = alpha * sinf(a) / 68.0f;
    }
}

// zero only the seam bands (rows/cols 66,67,132,133,198,199 of each image):
// those are the only pixels receiving atomicAdd.
__global__ void k_zero_seams(float* out) {
    int b = blockIdx.x / 12, line = blockIdx.x % 12;
    const int seam[6] = {66, 67, 132, 133, 198, 199};
    int t = threadIdx.x;
    if (line < 6) {
        int y = seam[line];
        float4* dst = (float4*)(out + ((size_t)(b * 256 + y)) * 256 * 64);
        for (int e = t; e < 4096; e += 256) dst[e] = make_float4(0, 0, 0, 0);
    } else {
        int x = seam[line - 6];
        float4* dst = (float4*)out;
        for (int e = t; e < 4096; e += 256) {
            int y = e >> 4, f = e & 15;
            dst[(((size_t)(b * 256 + y)) * 256 + x) * 16 + f] = make_float4(0, 0, 0, 0);
        }
    }
}

// ---------- one-time kernel-spectrum transpose: K_t[bin][i][o][c] ----------
__global__ void k_ktrans(const float* __restrict__ kr, const float* __restrict__ ki,
                         float* __restrict__ Kt) {
    __shared__ float tr[64 * 37];
    __shared__ float ti[64 * 37];
    int k1 = blockIdx.x >> 6, i = blockIdx.x & 63;
    int t = threadIdx.x;
    for (int e = t; e < 64 * KH; e += 256) {
        int o = e / KH, k2 = e % KH;
        size_t src = ((size_t)(o * 64 + i) * 68 + k1) * 68 + k2;
        tr[o * 37 + k2] = kr[src];
        ti[o * 37 + k2] = ki[src];
    }
    __syncthreads();
    for (int e = t; e < KH * 64; e += 256) {
        int k2 = e >> 6, o = e & 63;
        size_t dst = ((size_t)(k1 * KH + k2)) * 8192 + (size_t)i * 128 + o * 2;
        Kt[dst]     = tr[o * 37 + k2];
        Kt[dst + 1] = ti[o * 37 + k2];
    }
}

// ---------------- stage 1: row DFT ----------------
// Y[nl][k2][r][i] = sum_c x[b, tr*64+r, tc*64+c, i] * Wf[k2][c]
__global__ void k_fwd_row(const float* __restrict__ x, const float* __restrict__ Wf,
                          float* __restrict__ Y, int c0) {
    __shared__ float xr[64 * 64];        // [c][i]
    __shared__ float wf[KH * 64 * 2];    // [k2][c]
    __shared__ float yout[KH * 128];     // [k2][i][c]
    int lc = blockIdx.x >> 10;
    int rem = blockIdx.x & 1023;
    int nl = rem >> 6, r = rem & 63;
    int n = (c0 + lc) * 16 + nl;
    int b = n >> 4, tr = (n >> 2) & 3, tc = n & 3;
    const float* src = x + (((size_t)(b * 256 + tr * 64 + r)) * 256 + tc * 64) * 64;
    int t = threadIdx.x;
    const float4* src4 = (const float4*)src;
    float4* xr4 = (float4*)xr;
    for (int e = t; e < 1024; e += 256) xr4[e] = src4[e];
    for (int e = t; e < KH * 64 * 2; e += 256) wf[e] = Wf[e];
    __syncthreads();
    int i = t & 63, kg = t >> 6;
    for (int k2 = kg; k2 < KH; k2 += 4) {
        float ar = 0.f, ai = 0.f;
        const float* w = wf + k2 * 128;
        for (int c = 0; c < 64; ++c) {
            float v = xr[(c << 6) | i];
            ar += v * w[2 * c];
            ai += v * w[2 * c + 1];
        }
        yout[(k2 << 7) + 2 * i]     = ar;
        yout[(k2 << 7) + 2 * i + 1] = ai;
    }
    __syncthreads();
    float* Yc = Y + (size_t)lc * CHS;
    const float4* ys4 = (const float4*)yout;
    for (int e = t; e < KH * 32; e += 256) {
        int k2 = e >> 5, f = e & 31;
        ((float4*)(Yc + ((size_t)(nl * KH + k2) * 64 + r) * 128))[f] = ys4[e];
    }
}

// ---------------- stage 2: column DFT (4i x 9k1 outer-product tile) --------
// X[nl][k1][k2][i] = sum_r Wf[k1][r] * Y[nl][k2][r][i]
// 256 thr: q=t&15 (i=4q..4q+3), g=(t>>4)&7 (k1=g+8j, j<9), h=t>>7 (k2 slice).
// Per r: 2 ds_read_b128 (4 cplx zv) + 9 b64 (wv) -> 144 FMA.
// LDS rows bank-deswizzled: float4 j stored at slot (j>>1)|((j&1)<<4),
// so lane q reads slots q and q+16 (2-way bank aliasing = free).
__global__ __launch_bounds__(256) void k_fwd_col(
        const float* __restrict__ Y, const float* __restrict__ Wf,
        float* __restrict__ X) {
    __shared__ float yl[2 * 8192];       // 64 KB   [h][r][slot]
    __shared__ float wfs[72 * 128];      // 36.9 KB [k1][r][c] (rows 68..71 zero)
    int lc = blockIdx.x / 288;
    int rem = blockIdx.x % 288;
    int nl = rem / 18, k2b = rem % 18;
    const float* Yc = Y + (size_t)lc * CHS;
    float* Xc = X + (size_t)lc * CHS;
    int t = threadIdx.x;
    float4* wf4 = (float4*)wfs;
    const float4* wsrc4 = (const float4*)Wf;
    for (int e = t; e < 2304; e += 256) wf4[e] = wsrc4[e];
    float4* yl4 = (float4*)yl;
    for (int e = t; e < 4096; e += 256) {
        int sl = e >> 11, f = e & 2047;
        int k2s = 2 * k2b + sl;
        if (k2s < KH) {
            int row = f >> 5, j = f & 31;
            int slot = (j >> 1) | ((j & 1) << 4);
            yl4[(sl << 11) + (row << 5) + slot]
                = ((const float4*)(Yc + ((size_t)(nl * KH + k2s)) * 8192))[f];
        }
    }
    __syncthreads();
    int q = t & 15, g = (t >> 4) & 7, h = t >> 7;   // 16 x 8 x 2 = 256
    int k2 = 2 * k2b + h;
    if (k2 >= KH) return;
    float ar[9][4], ai[9][4];
    #pragma unroll
    for (int j = 0; j < 9; ++j)
        #pragma unroll
        for (int u = 0; u < 4; ++u) { ar[j][u] = 0.f; ai[j][u] = 0.f; }
    const float* zp = yl + (h << 13) + 4 * q;
    const float* wb = wfs + (g << 7);
    #pragma unroll 4
    for (int r = 0; r < 64; ++r) {
        float4 z01 = *(const float4*)(zp + (r << 7));        // slot q
        float4 z23 = *(const float4*)(zp + (r << 7) + 64);   // slot q+16
        #pragma unroll
        for (int j = 0; j < 9; ++j) {
            float2 wv = *(const float2*)(wb + (j << 10) + 2 * r);
            ar[j][0] += wv.x * z01.x - wv.y * z01.y;
            ai[j][0] += wv.x * z01.y + wv.y * z01.x;
            ar[j][1] += wv.x * z01.z - wv.y * z01.w;
            ai[j][1] += wv.x * z01.w + wv.y * z01.z;
            ar[j][2] += wv.x * z23.x - wv.y * z23.y;
            ai[j][2] += wv.x * z23.y + wv.y * z23.x;
            ar[j][3] += wv.x * z23.z - wv.y * z23.w;
            ai[j][3] += wv.x * z23.w + wv.y * z23.z;
        }
    }
    #pragma unroll
    for (int j = 0; j < 9; ++j) {
        int k1 = g + 8 * j;
        if (k1 < 68) {
            float* dst = Xc + ((size_t)(nl * 68 + k1) * KH + k2) * 128 + 8 * q;
            *(float4*)dst       = make_float4(ar[j][0], ai[j][0], ar[j][1], ai[j][1]);
            *(float4*)(dst + 4) = make_float4(ar[j][2], ai[j][2], ar[j][3], ai[j][3]);
        }
    }
}

// ---------------- stage 3: per-bin channel mix (2o x 2n register tile) -----
// O[nl][k2][k1][o] = sum_i X[nl][k1][k2][i] * K[bin][i][o]
__global__ void k_mix(const float* __restrict__ X, const float* __restrict__ Kt,
                      const float* __restrict__ kr, const float* __restrict__ ki,
                      float* __restrict__ O, int useKt) {
    __shared__ float xl[16 * 128];       // [n][i][c]  8 KB
    __shared__ float kl[64 * 64 * 2];    // [i][o][c] 32 KB
    int lc = blockIdx.x / 2380;
    int bin = blockIdx.x % 2380;
    int k1 = bin / KH, k2 = bin % KH;
    const float* Xc = X + (size_t)lc * CHS;
    float* Oc = O + (size_t)lc * CHS;
    int t = threadIdx.x;
    for (int e = t; e < 2048; e += 256) {
        int n = e >> 7, ic = e & 127;
        xl[e] = Xc[((size_t)(n * 68 + k1) * KH + k2) * 128 + ic];
    }
    if (useKt) {
        const float* src = Kt + (size_t)bin * 8192;
        for (int e = t; e < 8192; e += 256) kl[e] = src[e];
    } else {
        for (int e = t; e < 4096; e += 256) {
            int o = e >> 6, i = e & 63;
            size_t gi = ((size_t)(o * 64 + i) * 68 + k1) * 68 + k2;
            kl[i * 128 + o * 2]     = kr[gi];
            kl[i * 128 + o * 2 + 1] = ki[gi];
        }
    }
    __syncthreads();
    int op = t & 31, g = t >> 5;         // o = 2op,2op+1 ; n = g, g+8
    float a0r=0,a0i=0,a1r=0,a1i=0,b0r=0,b0i=0,b1r=0,b1i=0;
    for (int i = 0; i < 64; ++i) {
        float4 kv = *(const float4*)(kl + i * 128 + op * 4);
        float2 c0 = *(const float2*)(xl + (g << 7) + i * 2);
        float2 c1 = *(const float2*)(xl + ((g + 8) << 7) + i * 2);
        a0r += kv.x * c0.x - kv.y * c0.y;  a0i += kv.x * c0.y + kv.y * c0.x;
        a1r += kv.z * c0.x - kv.w * c0.y;  a1i += kv.z * c0.y + kv.w * c0.x;
        b0r += kv.x * c1.x - kv.y * c1.y;  b0i += kv.x * c1.y + kv.y * c1.x;
        b1r += kv.z * c1.x - kv.w * c1.y;  b1i += kv.z * c1.y + kv.w * c1.x;
    }
    size_t base0 = ((((size_t)g       * KH + k2) * 68 + k1) * 64 + 2 * op) * 2;
    size_t base1 = ((((size_t)(g + 8) * KH + k2) * 68 + k1) * 64 + 2 * op) * 2;
    *(float4*)(Oc + base0) = make_float4(a0r, a0i, a1r, a1i);
    *(float4*)(Oc + base1) = make_float4(b0r, b0i, b1r, b1i);
}

// ---------------- stage 4: inverse col DFT (reg-blocked p sweep, LDS tw) ----
// Z[nl][p][k2][o] = sum_k1 Wi[p][k1] * O[nl][k2][k1][o]
__global__ __launch_bounds__(512) void k_inv_col(
        const float* __restrict__ O, const float* __restrict__ Wi2,
        float* __restrict__ Z) {
    __shared__ float ol[68 * 128];       // 34 KB   [k1][o][c]
    __shared__ float wih[40 * 136];      // 21.8 KB [pl][k1][c] (padded rows zero)
    int lc = blockIdx.x / 1120;
    int rem = blockIdx.x % 1120;
    int ph = rem & 1;
    int rest = rem >> 1;
    int k2 = rest % KH, nl = rest / KH;
    int t = threadIdx.x;
    const float* Oc = O + (size_t)lc * CHS;
    float* Zc = Z + (size_t)lc * CHS;
    const float4* osrc = (const float4*)(Oc + ((size_t)nl * KH + k2) * 68 * 128);
    float4* ol4 = (float4*)ol;
    for (int e = t; e < 68 * 32; e += 512) ol4[e] = osrc[e];
    const float4* wsrc4 = (const float4*)(Wi2 + (size_t)ph * 5440);
    float4* wi4 = (float4*)wih;
    for (int e = t; e < 1360; e += 512) wi4[e] = wsrc4[e];
    __syncthreads();
    int o = t & 63, g = t >> 6;          // wave-uniform g
    float ar[5], ai[5];
    #pragma unroll
    for (int j = 0; j < 5; ++j) { ar[j] = 0.f; ai[j] = 0.f; }
    const float* oo_ = ol + 2 * o;
    const float* wb = wih + g * 136;     // wave-uniform base
    #pragma unroll 4
    for (int k1 = 0; k1 < 68; ++k1) {
        float2 ov = *(const float2*)(oo_ + (k1 << 7));
        #pragma unroll
        for (int j = 0; j < 5; ++j) {
            float2 wv = *(const float2*)(wb + j * 1088 + 2 * k1);  // broadcast
            ar[j] += wv.x * ov.x - wv.y * ov.y;
            ai[j] += wv.x * ov.y + wv.y * ov.x;
        }
    }
    #pragma unroll
    for (int j = 0; j < 5; ++j) {
        int pl = g + 8 * j;
        if (pl < 34) {
            int p = ph * 34 + pl;
            *(float2*)(Zc + ((size_t)(nl * 68 + p) * KH + k2) * 128 + 2 * o)
                = make_float2(ar[j], ai[j]);
        }
    }
}

// ---------------- stage 5: inverse row DFT + overlap-add --------------------
__global__ __launch_bounds__(256) void k_fused_inv(
        const float* __restrict__ Z, const float* __restrict__ Wg,
        const float* __restrict__ bias, float* __restrict__ out, int c0) {
    __shared__ float zl[KH * 128];       // 17.9 KB [k2][o][c]
    __shared__ float wg[68 * 70];        // 19.0 KB [q][k2c]
    int lc = blockIdx.x / 1088;
    int rem = blockIdx.x % 1088;
    int nl = rem / 68, p = rem % 68;
    int b = c0 + lc;
    int tr = nl >> 2, tc = nl & 3;
    int y = 66 * tr + p;
    if (y >= 256) return;
    int t = threadIdx.x;
    const float4* zs4 = (const float4*)(Z + (size_t)lc * CHS
                                        + ((size_t)(nl * 68 + p)) * 4480);
    float4* zl4 = (float4*)zl;
    for (int e = t; e < 1120; e += 256) zl4[e] = zs4[e];
    for (int e = t; e < 4760; e += 256) wg[e] = Wg[e];
    __syncthreads();

    int o = t & 63, qg = t >> 6;         // qg in 0..3, q = qg*17 + j
    float bv = bias[o];
    const float* zr = zl + 2 * o;
    const float* wbase = wg + (qg * 17) * 70;

    float acc[17];
    #pragma unroll
    for (int j = 0; j < 17; ++j) acc[j] = 0.f;

    for (int k2 = 0; k2 < KH; ++k2) {
        float2 zv = *(const float2*)(zr + (k2 << 7));
        #pragma unroll
        for (int j = 0; j < 17; ++j) {
            float2 wv = *(const float2*)(wbase + j * 70 + 2 * k2);  // broadcast
            acc[j] += zv.x * wv.x - zv.y * wv.y;
        }
    }

    bool rowu = !((p <= 1 && tr > 0) || (p >= 66 && tr < 3));
    float* orow = out + ((size_t)(b * 256 + y)) * 256 * 64 + o;
    #pragma unroll
    for (int j = 0; j < 17; ++j) {
        int q = qg * 17 + j;
        int x = 66 * tc + q;
        if (x >= 256) continue;
        bool colu = !((q <= 1 && tc > 0) || (q >= 66 && tc < 3));
        float v = acc[j] + bv;
        if (rowu && colu) orow[(size_t)x * 64] = v;
        else              atomicAdd(orow + (size_t)x * 64, v);
    }
}

extern "C" void kernel_launch(void* const* d_in, const int* in_sizes, int n_in,
                              void* d_out, int out_size, void* d_ws, size_t ws_size,
                              hipStream_t stream) {
    const float* x    = (const float*)d_in[0];
    const float* kr   = (const float*)d_in[1];
    const float* ki   = (const float*)d_in[2];
    const float* bias = (const float*)d_in[3];
    float* out = (float*)d_out;
    float* ws  = (float*)d_ws;

    int useKt = 1;
    int CH = 8;
    while (CH > 1 && (WS_HEAD + KT_FLOATS + 2ull * CH * CHS) * 4ull > ws_size) CH >>= 1;
    if ((WS_HEAD + KT_FLOATS + 2ull * CH * CHS) * 4ull > ws_size) {
        useKt = 0;
        CH = 8;
        while (CH > 1 && (WS_HEAD + 2ull * CH * CHS) * 4ull > ws_size) CH >>= 1;
    }

    float* Wf   = ws;                          // 9216 floats (72x64 cplx, padded)
    float* Wi2  = ws + 9216;                   // 10880 floats (2x40x68 cplx, padded)
    float* Wg   = ws + 20096;                  // 4760 floats
    float* Kt   = ws + WS_HEAD;                // KT_FLOATS (if useKt)
    float* bufA = Kt + (useKt ? KT_FLOATS : 0);   // Y then O
    float* bufB = bufA + (size_t)CH * CHS;        // X then Z

    k_twiddle<<<1, 256, 0, stream>>>(ws);
    if (useKt)
        k_ktrans<<<68 * 64, 256, 0, stream>>>(kr, ki, Kt);
    k_zero_seams<<<96, 256, 0, stream>>>(out);

    for (int s = 0; s < 8; s += CH) {
        k_fwd_row<<<CH * 1024, 256, 0, stream>>>(x, Wf, bufA, s);
        k_fwd_col<<<CH * 288, 256, 0, stream>>>(bufA, Wf, bufB);
        k_mix<<<CH * 2380, 256, 0, stream>>>(bufB, Kt, kr, ki, bufA, useKt);
        k_inv_col<<<CH * 1120, 512, 0, stream>>>(bufA, Wi2, bufB);
        k_fused_inv<<<CH * 1088, 256, 0, stream>>>(bufB, Wg, bias, out, s);
    }
}

// Round 14
// 1385.675 us; speedup vs baseline: 1.0168x; 1.0168x over previous
//
#include <hip/hip_runtime.h>
#include <hip/hip_bf16.h>

// FFT-tiled conv: B=8, IMG=256, CIN=COUT=64, TILE=64, FFT=68, PAD=2.
// Frequency-domain per-tile conv via DFT-as-matmul, Hermitian half-spectrum
// (k2 in [0,35)), direct overlap-add (plain stores interior, atomics on seams,
// seam bands pre-zeroed). All fp32. Register-blocked outer-product sweeps.
//
// Layouts (per 16-tile chunk slot of CHS floats):
//   Y  [nl][k2][r][i][c]      in bufA     ((nl*35+k2)*64+r)*128
//   X  [nl][k1][k2][i][c]     in bufB     ((nl*68+k1)*35+k2)*128
//   K_t[bin][i][o][c]         78 MB, one-time (bin = k1*35+k2)
//   O  [nl][k2][k1][o][c]     in bufA     ((nl*35+k2)*68+k1)*128
//   Z  [nl][p][k2][o][c]      in bufB     ((nl*68+p)*35+k2)*128
//
// Twiddle tables (zero-padded for fixed-trip register blocking):
//   Wf  [72][64] cplx   rows 68..71 zero      (9216 floats)
//   Wi2 [2][40][68] cplx rows pl=34..39 zero  (10880 floats)
//   Wg  [68][35] cplx                          (4760 floats)

#define KH   35
#define CHS  4874240ull                       // floats per chunk slot
#define KT_FLOATS (68ull * KH * 64 * 64 * 2)  // 19,496,960
#define WS_HEAD 24856ull                      // 9216 + 10880 + 4760
#define SLP  8196                             // k2-slice stride in LDS (mod32=4)

__global__ void k_twiddle(float* ws) {
    const float TWO_PI = 6.28318530717958647692f;
    int t = threadIdx.x;
    float* Wf = ws;                       // 72 x 64 cplx
    for (int e = t; e < 72 * 64; e += 256) {
        int k = e >> 6, m = e & 63;
        float vr = 0.f, vi = 0.f;
        if (k < 68) {
            int ph = (k * (m + 2)) % 68;
            float a = TWO_PI * (float)ph / 68.0f;
            vr = cosf(a); vi = -sinf(a);
        }
        Wf[2 * e] = vr; Wf[2 * e + 1] = vi;
    }
    float* Wi2 = ws + 9216;               // 2 x 40 x 68 cplx
    for (int e = t; e < 2 * 40 * 68; e += 256) {
        int hp = e / 2720, rem2 = e % 2720;
        int pl = rem2 / 68, k = rem2 % 68;
        float vr = 0.f, vi = 0.f;
        if (pl < 34) {
            int p = hp * 34 + pl;
            int ph = (p * k) % 68;
            float a = TWO_PI * (float)ph / 68.0f;
            vr = cosf(a) / 68.0f; vi = sinf(a) / 68.0f;
        }
        Wi2[2 * e] = vr; Wi2[2 * e + 1] = vi;
    }
    float* Wg = ws + 20096;               // 68 x 35 cplx
    for (int e = t; e < 68 * KH; e += 256) {
        int q = e / KH, k2 = e % KH;
        int ph = (q * k2) % 68;
        float a = TWO_PI * (float)ph / 68.0f;
        float alpha = (k2 == 0 || k2 == 34) ? 1.0f : 2.0f;
        Wg[2 * e]     = alpha * cosf(a) / 68.0f;
        Wg[2 * e + 1] = alpha * sinf(a) / 68.0f;
    }
}

// zero only the seam bands (rows/cols 66,67,132,133,198,199 of each image):
// those are the only pixels receiving atomicAdd.
__global__ void k_zero_seams(float* out) {
    int b = blockIdx.x / 12, line = blockIdx.x % 12;
    const int seam[6] = {66, 67, 132, 133, 198, 199};
    int t = threadIdx.x;
    if (line < 6) {
        int y = seam[line];
        float4* dst = (float4*)(out + ((size_t)(b * 256 + y)) * 256 * 64);
        for (int e = t; e < 4096; e += 256) dst[e] = make_float4(0, 0, 0, 0);
    } else {
        int x = seam[line - 6];
        float4* dst = (float4*)out;
        for (int e = t; e < 4096; e += 256) {
            int y = e >> 4, f = e & 15;
            dst[(((size_t)(b * 256 + y)) * 256 + x) * 16 + f] = make_float4(0, 0, 0, 0);
        }
    }
}

// ---------- one-time kernel-spectrum transpose: K_t[bin][i][o][c] ----------
__global__ void k_ktrans(const float* __restrict__ kr, const float* __restrict__ ki,
                         float* __restrict__ Kt) {
    __shared__ float tr[64 * 37];
    __shared__ float ti[64 * 37];
    int k1 = blockIdx.x >> 6, i = blockIdx.x & 63;
    int t = threadIdx.x;
    for (int e = t; e < 64 * KH; e += 256) {
        int o = e / KH, k2 = e % KH;
        size_t src = ((size_t)(o * 64 + i) * 68 + k1) * 68 + k2;
        tr[o * 37 + k2] = kr[src];
        ti[o * 37 + k2] = ki[src];
    }
    __syncthreads();
    for (int e = t; e < KH * 64; e += 256) {
        int k2 = e >> 6, o = e & 63;
        size_t dst = ((size_t)(k1 * KH + k2)) * 8192 + (size_t)i * 128 + o * 2;
        Kt[dst]     = tr[o * 37 + k2];
        Kt[dst + 1] = ti[o * 37 + k2];
    }
}

// ---------------- stage 1: row DFT ----------------
// Y[nl][k2][r][i] = sum_c x[b, tr*64+r, tc*64+c, i] * Wf[k2][c]
__global__ void k_fwd_row(const float* __restrict__ x, const float* __restrict__ Wf,
                          float* __restrict__ Y, int c0) {
    __shared__ float xr[64 * 64];        // [c][i]
    __shared__ float wf[KH * 64 * 2];    // [k2][c]
    __shared__ float yout[KH * 128];     // [k2][i][c]
    int lc = blockIdx.x >> 10;
    int rem = blockIdx.x & 1023;
    int nl = rem >> 6, r = rem & 63;
    int n = (c0 + lc) * 16 + nl;
    int b = n >> 4, tr = (n >> 2) & 3, tc = n & 3;
    const float* src = x + (((size_t)(b * 256 + tr * 64 + r)) * 256 + tc * 64) * 64;
    int t = threadIdx.x;
    const float4* src4 = (const float4*)src;
    float4* xr4 = (float4*)xr;
    for (int e = t; e < 1024; e += 256) xr4[e] = src4[e];
    for (int e = t; e < KH * 64 * 2; e += 256) wf[e] = Wf[e];
    __syncthreads();
    int i = t & 63, kg = t >> 6;
    for (int k2 = kg; k2 < KH; k2 += 4) {
        float ar = 0.f, ai = 0.f;
        const float* w = wf + k2 * 128;
        for (int c = 0; c < 64; ++c) {
            float v = xr[(c << 6) | i];
            ar += v * w[2 * c];
            ai += v * w[2 * c + 1];
        }
        yout[(k2 << 7) + 2 * i]     = ar;
        yout[(k2 << 7) + 2 * i + 1] = ai;
    }
    __syncthreads();
    float* Yc = Y + (size_t)lc * CHS;
    const float4* ys4 = (const float4*)yout;
    for (int e = t; e < KH * 32; e += 256) {
        int k2 = e >> 5, f = e & 31;
        ((float4*)(Yc + ((size_t)(nl * KH + k2) * 64 + r) * 128))[f] = ys4[e];
    }
}

// ---------------- stage 2: column DFT (4i x 9k1 outer product, wave-g) -----
// X[nl][k1][k2][i] = sum_r Wf[k1][r] * Y[nl][k2][r][i]
// 512 thr = 8 waves. wave g = t>>6 (k1 = g+8j, WAVE-UNIFORM -> wv broadcast).
// lane: q = l&15 (i-quad 4q..4q+3), ks = l>>4 (k2 slice, 3 staged; ks=3 idle).
// Slice stride SLP=8196 floats (mod32=4) -> b128 zv reads spread all 32 banks.
__global__ __launch_bounds__(512) void k_fwd_col(
        const float* __restrict__ Y, const float* __restrict__ Wf,
        float* __restrict__ X) {
    __shared__ float ylp[3 * SLP];       // 98.4 KB [ks][r][i][c]
    __shared__ float wfs[72 * 128];      // 36.9 KB [k1][r][c] (rows 68..71 zero)
    int lc = blockIdx.x / 192;
    int rem = blockIdx.x % 192;
    int nl = rem / 12, k2g = rem % 12;   // 3 k2 per group
    const float* Yc = Y + (size_t)lc * CHS;
    float* Xc = X + (size_t)lc * CHS;
    int t = threadIdx.x;
    float4* wf4 = (float4*)wfs;
    const float4* wsrc4 = (const float4*)Wf;
    for (int e = t; e < 2304; e += 512) wf4[e] = wsrc4[e];
    float4* yl4 = (float4*)ylp;
    for (int e = t; e < 3 * 2049; e += 512) {
        int sl = e / 2049, f = e % 2049;
        int k2s = 3 * k2g + sl;
        if (f < 2048 && k2s < KH)
            yl4[sl * 2049 + f]
                = ((const float4*)(Yc + ((size_t)(nl * KH + k2s)) * 8192))[f];
    }
    __syncthreads();
    int l = t & 63, g = t >> 6;          // g wave-uniform, 0..7
    int q = l & 15, ks = l >> 4;         // 16 i-quads x 4 slices
    int k2 = 3 * k2g + ks;
    bool active = (ks < 3) && (k2 < KH);
    float ar[9][4], ai[9][4];
    #pragma unroll
    for (int j = 0; j < 9; ++j)
        #pragma unroll
        for (int u = 0; u < 4; ++u) { ar[j][u] = 0.f; ai[j][u] = 0.f; }
    if (active) {
        const float* zp = ylp + ks * SLP + 8 * q;
        const float* wb = wfs + (g << 7);    // wave-uniform base -> broadcast
        #pragma unroll 4
        for (int r = 0; r < 64; ++r) {
            float4 z01 = *(const float4*)(zp + (r << 7));
            float4 z23 = *(const float4*)(zp + (r << 7) + 4);
            #pragma unroll
            for (int j = 0; j < 9; ++j) {
                float2 wv = *(const float2*)(wb + (j << 10) + 2 * r);
                ar[j][0] += wv.x * z01.x - wv.y * z01.y;
                ai[j][0] += wv.x * z01.y + wv.y * z01.x;
                ar[j][1] += wv.x * z01.z - wv.y * z01.w;
                ai[j][1] += wv.x * z01.w + wv.y * z01.z;
                ar[j][2] += wv.x * z23.x - wv.y * z23.y;
                ai[j][2] += wv.x * z23.y + wv.y * z23.x;
                ar[j][3] += wv.x * z23.z - wv.y * z23.w;
                ai[j][3] += wv.x * z23.w + wv.y * z23.z;
            }
        }
        #pragma unroll
        for (int j = 0; j < 9; ++j) {
            int k1 = g + 8 * j;
            if (k1 < 68) {
                float* dst = Xc + ((size_t)(nl * 68 + k1) * KH + k2) * 128 + 8 * q;
                *(float4*)dst       = make_float4(ar[j][0], ai[j][0], ar[j][1], ai[j][1]);
                *(float4*)(dst + 4) = make_float4(ar[j][2], ai[j][2], ar[j][3], ai[j][3]);
            }
        }
    }
}

// ---------------- stage 3: per-bin channel mix (2o x 2n register tile) -----
// O[nl][k2][k1][o] = sum_i X[nl][k1][k2][i] * K[bin][i][o]
__global__ void k_mix(const float* __restrict__ X, const float* __restrict__ Kt,
                      const float* __restrict__ kr, const float* __restrict__ ki,
                      float* __restrict__ O, int useKt) {
    __shared__ float xl[16 * 128];       // [n][i][c]  8 KB
    __shared__ float kl[64 * 64 * 2];    // [i][o][c] 32 KB
    int lc = blockIdx.x / 2380;
    int bin = blockIdx.x % 2380;
    int k1 = bin / KH, k2 = bin % KH;
    const float* Xc = X + (size_t)lc * CHS;
    float* Oc = O + (size_t)lc * CHS;
    int t = threadIdx.x;
    for (int e = t; e < 2048; e += 256) {
        int n = e >> 7, ic = e & 127;
        xl[e] = Xc[((size_t)(n * 68 + k1) * KH + k2) * 128 + ic];
    }
    if (useKt) {
        const float* src = Kt + (size_t)bin * 8192;
        for (int e = t; e < 8192; e += 256) kl[e] = src[e];
    } else {
        for (int e = t; e < 4096; e += 256) {
            int o = e >> 6, i = e & 63;
            size_t gi = ((size_t)(o * 64 + i) * 68 + k1) * 68 + k2;
            kl[i * 128 + o * 2]     = kr[gi];
            kl[i * 128 + o * 2 + 1] = ki[gi];
        }
    }
    __syncthreads();
    int op = t & 31, g = t >> 5;         // o = 2op,2op+1 ; n = g, g+8
    float a0r=0,a0i=0,a1r=0,a1i=0,b0r=0,b0i=0,b1r=0,b1i=0;
    for (int i = 0; i < 64; ++i) {
        float4 kv = *(const float4*)(kl + i * 128 + op * 4);
        float2 c0 = *(const float2*)(xl + (g << 7) + i * 2);
        float2 c1 = *(const float2*)(xl + ((g + 8) << 7) + i * 2);
        a0r += kv.x * c0.x - kv.y * c0.y;  a0i += kv.x * c0.y + kv.y * c0.x;
        a1r += kv.z * c0.x - kv.w * c0.y;  a1i += kv.z * c0.y + kv.w * c0.x;
        b0r += kv.x * c1.x - kv.y * c1.y;  b0i += kv.x * c1.y + kv.y * c1.x;
        b1r += kv.z * c1.x - kv.w * c1.y;  b1i += kv.z * c1.y + kv.w * c1.x;
    }
    size_t base0 = ((((size_t)g       * KH + k2) * 68 + k1) * 64 + 2 * op) * 2;
    size_t base1 = ((((size_t)(g + 8) * KH + k2) * 68 + k1) * 64 + 2 * op) * 2;
    *(float4*)(Oc + base0) = make_float4(a0r, a0i, a1r, a1i);
    *(float4*)(Oc + base1) = make_float4(b0r, b0i, b1r, b1i);
}

// ---------------- stage 4: inverse col DFT (reg-blocked p sweep, LDS tw) ----
// Z[nl][p][k2][o] = sum_k1 Wi[p][k1] * O[nl][k2][k1][o]
__global__ __launch_bounds__(512) void k_inv_col(
        const float* __restrict__ O, const float* __restrict__ Wi2,
        float* __restrict__ Z) {
    __shared__ float ol[68 * 128];       // 34 KB   [k1][o][c]
    __shared__ float wih[40 * 136];      // 21.8 KB [pl][k1][c] (padded rows zero)
    int lc = blockIdx.x / 1120;
    int rem = blockIdx.x % 1120;
    int ph = rem & 1;
    int rest = rem >> 1;
    int k2 = rest % KH, nl = rest / KH;
    int t = threadIdx.x;
    const float* Oc = O + (size_t)lc * CHS;
    float* Zc = Z + (size_t)lc * CHS;
    const float4* osrc = (const float4*)(Oc + ((size_t)nl * KH + k2) * 68 * 128);
    float4* ol4 = (float4*)ol;
    for (int e = t; e < 68 * 32; e += 512) ol4[e] = osrc[e];
    const float4* wsrc4 = (const float4*)(Wi2 + (size_t)ph * 5440);
    float4* wi4 = (float4*)wih;
    for (int e = t; e < 1360; e += 512) wi4[e] = wsrc4[e];
    __syncthreads();
    int o = t & 63, g = t >> 6;          // wave-uniform g
    float ar[5], ai[5];
    #pragma unroll
    for (int j = 0; j < 5; ++j) { ar[j] = 0.f; ai[j] = 0.f; }
    const float* oo_ = ol + 2 * o;
    const float* wb = wih + g * 136;     // wave-uniform base
    #pragma unroll 4
    for (int k1 = 0; k1 < 68; ++k1) {
        float2 ov = *(const float2*)(oo_ + (k1 << 7));
        #pragma unroll
        for (int j = 0; j < 5; ++j) {
            float2 wv = *(const float2*)(wb + j * 1088 + 2 * k1);  // broadcast
            ar[j] += wv.x * ov.x - wv.y * ov.y;
            ai[j] += wv.x * ov.y + wv.y * ov.x;
        }
    }
    #pragma unroll
    for (int j = 0; j < 5; ++j) {
        int pl = g + 8 * j;
        if (pl < 34) {
            int p = ph * 34 + pl;
            *(float2*)(Zc + ((size_t)(nl * 68 + p) * KH + k2) * 128 + 2 * o)
                = make_float2(ar[j], ai[j]);
        }
    }
}

// ---------------- stage 5: inverse row DFT + overlap-add --------------------
__global__ __launch_bounds__(256) void k_fused_inv(
        const float* __restrict__ Z, const float* __restrict__ Wg,
        const float* __restrict__ bias, float* __restrict__ out, int c0) {
    __shared__ float zl[KH * 128];       // 17.9 KB [k2][o][c]
    __shared__ float wg[68 * 70];        // 19.0 KB [q][k2c]
    int lc = blockIdx.x / 1088;
    int rem = blockIdx.x % 1088;
    int nl = rem / 68, p = rem % 68;
    int b = c0 + lc;
    int tr = nl >> 2, tc = nl & 3;
    int y = 66 * tr + p;
    if (y >= 256) return;
    int t = threadIdx.x;
    const float4* zs4 = (const float4*)(Z + (size_t)lc * CHS
                                        + ((size_t)(nl * 68 + p)) * 4480);
    float4* zl4 = (float4*)zl;
    for (int e = t; e < 1120; e += 256) zl4[e] = zs4[e];
    for (int e = t; e < 4760; e += 256) wg[e] = Wg[e];
    __syncthreads();

    int o = t & 63, qg = t >> 6;         // qg in 0..3, q = qg*17 + j
    float bv = bias[o];
    const float* zr = zl + 2 * o;
    const float* wbase = wg + (qg * 17) * 70;

    float acc[17];
    #pragma unroll
    for (int j = 0; j < 17; ++j) acc[j] = 0.f;

    for (int k2 = 0; k2 < KH; ++k2) {
        float2 zv = *(const float2*)(zr + (k2 << 7));
        #pragma unroll
        for (int j = 0; j < 17; ++j) {
            float2 wv = *(const float2*)(wbase + j * 70 + 2 * k2);  // broadcast
            acc[j] += zv.x * wv.x - zv.y * wv.y;
        }
    }

    bool rowu = !((p <= 1 && tr > 0) || (p >= 66 && tr < 3));
    float* orow = out + ((size_t)(b * 256 + y)) * 256 * 64 + o;
    #pragma unroll
    for (int j = 0; j < 17; ++j) {
        int q = qg * 17 + j;
        int x = 66 * tc + q;
        if (x >= 256) continue;
        bool colu = !((q <= 1 && tc > 0) || (q >= 66 && tc < 3));
        float v = acc[j] + bv;
        if (rowu && colu) orow[(size_t)x * 64] = v;
        else              atomicAdd(orow + (size_t)x * 64, v);
    }
}

extern "C" void kernel_launch(void* const* d_in, const int* in_sizes, int n_in,
                              void* d_out, int out_size, void* d_ws, size_t ws_size,
                              hipStream_t stream) {
    const float* x    = (const float*)d_in[0];
    const float* kr   = (const float*)d_in[1];
    const float* ki   = (const float*)d_in[2];
    const float* bias = (const float*)d_in[3];
    float* out = (float*)d_out;
    float* ws  = (float*)d_ws;

    int useKt = 1;
    int CH = 8;
    while (CH > 1 && (WS_HEAD + KT_FLOATS + 2ull * CH * CHS) * 4ull > ws_size) CH >>= 1;
    if ((WS_HEAD + KT_FLOATS + 2ull * CH * CHS) * 4ull > ws_size) {
        useKt = 0;
        CH = 8;
        while (CH > 1 && (WS_HEAD + 2ull * CH * CHS) * 4ull > ws_size) CH >>= 1;
    }

    float* Wf   = ws;                          // 9216 floats (72x64 cplx, padded)
    float* Wi2  = ws + 9216;                   // 10880 floats (2x40x68 cplx, padded)
    float* Wg   = ws + 20096;                  // 4760 floats
    float* Kt   = ws + WS_HEAD;                // KT_FLOATS (if useKt)
    float* bufA = Kt + (useKt ? KT_FLOATS : 0);   // Y then O
    float* bufB = bufA + (size_t)CH * CHS;        // X then Z

    k_twiddle<<<1, 256, 0, stream>>>(ws);
    if (useKt)
        k_ktrans<<<68 * 64, 256, 0, stream>>>(kr, ki, Kt);
    k_zero_seams<<<96, 256, 0, stream>>>(out);

    for (int s = 0; s < 8; s += CH) {
        k_fwd_row<<<CH * 1024, 256, 0, stream>>>(x, Wf, bufA, s);
        k_fwd_col<<<CH * 192, 512, 0, stream>>>(bufA, Wf, bufB);
        k_mix<<<CH * 2380, 256, 0, stream>>>(bufB, Kt, kr, ki, bufA, useKt);
        k_inv_col<<<CH * 1120, 512, 0, stream>>>(bufA, Wi2, bufB);
        k_fused_inv<<<CH * 1088, 256, 0, stream>>>(bufB, Wg, bias, out, s);
    }
}

// Round 15
// 1112.678 us; speedup vs baseline: 1.2663x; 1.2454x over previous
//
#include <hip/hip_runtime.h>
#include <hip/hip_bf16.h>

// FFT-tiled conv: B=8, IMG=256, CIN=COUT=64, TILE=64, FFT=68, PAD=2.
// Frequency-domain per-tile conv via DFT-as-matmul, Hermitian half-spectrum
// (k2 in [0,35)), direct overlap-add (plain stores interior, atomics on seams,
// seam bands pre-zeroed). Stage-2 column DFT now runs on bf16 MFMA.
//
// Layouts (per 16-tile chunk slot of CHS floats):
//   Y  [nl][k2][r][i][c]      in bufA     ((nl*35+k2)*64+r)*128
//   X  [nl][k1][k2][i][c]     in bufB     ((nl*68+k1)*35+k2)*128
//   K_t[bin][i][o][c]         78 MB, one-time (bin = k1*35+k2)
//   O  [nl][k2][k1][o][c]     in bufA     ((nl*35+k2)*68+k1)*128
//   Z  [nl][p][k2][o][c]      in bufB     ((nl*68+p)*35+k2)*128
//
// Twiddle tables:
//   Wf  [72][64] cplx fp32  rows 68..71 zero   (9216 floats)
//   Wi2 [2][40][68] cplx fp32 rows pl>=34 zero (10880 floats)
//   Wg  [68][35] cplx fp32                      (4760 floats)
//   Wfb [2][80][64] bf16  rows 68..79 zero      (10240 ushorts = 5120 floats)

#define KH   35
#define CHS  4874240ull                       // floats per chunk slot
#define KT_FLOATS (68ull * KH * 64 * 64 * 2)  // 19,496,960
#define WS_HEAD 29976ull                      // 9216+10880+4760+5120

typedef float f32x4 __attribute__((ext_vector_type(4)));
typedef short s16x8 __attribute__((ext_vector_type(8)));

__device__ __forceinline__ ushort f2bf(float f) {
    __hip_bfloat16 h = __float2bfloat16(f);
    return *reinterpret_cast<ushort*>(&h);
}

__global__ void k_twiddle(float* ws) {
    const float TWO_PI = 6.28318530717958647692f;
    int t = threadIdx.x;
    float* Wf = ws;                       // 72 x 64 cplx
    for (int e = t; e < 72 * 64; e += 256) {
        int k = e >> 6, m = e & 63;
        float vr = 0.f, vi = 0.f;
        if (k < 68) {
            int ph = (k * (m + 2)) % 68;
            float a = TWO_PI * (float)ph / 68.0f;
            vr = cosf(a); vi = -sinf(a);
        }
        Wf[2 * e] = vr; Wf[2 * e + 1] = vi;
    }
    float* Wi2 = ws + 9216;               // 2 x 40 x 68 cplx
    for (int e = t; e < 2 * 40 * 68; e += 256) {
        int hp = e / 2720, rem2 = e % 2720;
        int pl = rem2 / 68, k = rem2 % 68;
        float vr = 0.f, vi = 0.f;
        if (pl < 34) {
            int p = hp * 34 + pl;
            int ph = (p * k) % 68;
            float a = TWO_PI * (float)ph / 68.0f;
            vr = cosf(a) / 68.0f; vi = sinf(a) / 68.0f;
        }
        Wi2[2 * e] = vr; Wi2[2 * e + 1] = vi;
    }
    float* Wg = ws + 20096;               // 68 x 35 cplx
    for (int e = t; e < 68 * KH; e += 256) {
        int q = e / KH, k2 = e % KH;
        int ph = (q * k2) % 68;
        float a = TWO_PI * (float)ph / 68.0f;
        float alpha = (k2 == 0 || k2 == 34) ? 1.0f : 2.0f;
        Wg[2 * e]     = alpha * cosf(a) / 68.0f;
        Wg[2 * e + 1] = alpha * sinf(a) / 68.0f;
    }
    ushort* Wfb = (ushort*)(ws + 24856);  // [2][80][64] bf16
    for (int e = t; e < 80 * 64; e += 256) {
        int k = e >> 6, r = e & 63;
        float vr = 0.f, vi = 0.f;
        if (k < 68) {
            int ph = (k * (r + 2)) % 68;
            float a = TWO_PI * (float)ph / 68.0f;
            vr = cosf(a); vi = -sinf(a);
        }
        Wfb[e]        = f2bf(vr);
        Wfb[5120 + e] = f2bf(vi);
    }
}

// zero only the seam bands (rows/cols 66,67,132,133,198,199 of each image)
__global__ void k_zero_seams(float* out) {
    int b = blockIdx.x / 12, line = blockIdx.x % 12;
    const int seam[6] = {66, 67, 132, 133, 198, 199};
    int t = threadIdx.x;
    if (line < 6) {
        int y = seam[line];
        float4* dst = (float4*)(out + ((size_t)(b * 256 + y)) * 256 * 64);
        for (int e = t; e < 4096; e += 256) dst[e] = make_float4(0, 0, 0, 0);
    } else {
        int x = seam[line - 6];
        float4* dst = (float4*)out;
        for (int e = t; e < 4096; e += 256) {
            int y = e >> 4, f = e & 15;
            dst[(((size_t)(b * 256 + y)) * 256 + x) * 16 + f] = make_float4(0, 0, 0, 0);
        }
    }
}

// ---------- one-time kernel-spectrum transpose: K_t[bin][i][o][c] ----------
__global__ void k_ktrans(const float* __restrict__ kr, const float* __restrict__ ki,
                         float* __restrict__ Kt) {
    __shared__ float tr[64 * 37];
    __shared__ float ti[64 * 37];
    int k1 = blockIdx.x >> 6, i = blockIdx.x & 63;
    int t = threadIdx.x;
    for (int e = t; e < 64 * KH; e += 256) {
        int o = e / KH, k2 = e % KH;
        size_t src = ((size_t)(o * 64 + i) * 68 + k1) * 68 + k2;
        tr[o * 37 + k2] = kr[src];
        ti[o * 37 + k2] = ki[src];
    }
    __syncthreads();
    for (int e = t; e < KH * 64; e += 256) {
        int k2 = e >> 6, o = e & 63;
        size_t dst = ((size_t)(k1 * KH + k2)) * 8192 + (size_t)i * 128 + o * 2;
        Kt[dst]     = tr[o * 37 + k2];
        Kt[dst + 1] = ti[o * 37 + k2];
    }
}

// ---------------- stage 1: row DFT ----------------
// Y[nl][k2][r][i] = sum_c x[b, tr*64+r, tc*64+c, i] * Wf[k2][c]
__global__ void k_fwd_row(const float* __restrict__ x, const float* __restrict__ Wf,
                          float* __restrict__ Y, int c0) {
    __shared__ float xr[64 * 64];        // [c][i]
    __shared__ float wf[KH * 64 * 2];    // [k2][c]
    __shared__ float yout[KH * 128];     // [k2][i][c]
    int lc = blockIdx.x >> 10;
    int rem = blockIdx.x & 1023;
    int nl = rem >> 6, r = rem & 63;
    int n = (c0 + lc) * 16 + nl;
    int b = n >> 4, tr = (n >> 2) & 3, tc = n & 3;
    const float* src = x + (((size_t)(b * 256 + tr * 64 + r)) * 256 + tc * 64) * 64;
    int t = threadIdx.x;
    const float4* src4 = (const float4*)src;
    float4* xr4 = (float4*)xr;
    for (int e = t; e < 1024; e += 256) xr4[e] = src4[e];
    for (int e = t; e < KH * 64 * 2; e += 256) wf[e] = Wf[e];
    __syncthreads();
    int i = t & 63, kg = t >> 6;
    for (int k2 = kg; k2 < KH; k2 += 4) {
        float ar = 0.f, ai = 0.f;
        const float* w = wf + k2 * 128;
        for (int c = 0; c < 64; ++c) {
            float v = xr[(c << 6) | i];
            ar += v * w[2 * c];
            ai += v * w[2 * c + 1];
        }
        yout[(k2 << 7) + 2 * i]     = ar;
        yout[(k2 << 7) + 2 * i + 1] = ai;
    }
    __syncthreads();
    float* Yc = Y + (size_t)lc * CHS;
    const float4* ys4 = (const float4*)yout;
    for (int e = t; e < KH * 32; e += 256) {
        int k2 = e >> 5, f = e & 31;
        ((float4*)(Yc + ((size_t)(nl * KH + k2) * 64 + r) * 128))[f] = ys4[e];
    }
}

// ---------------- stage 2: column DFT — bf16 MFMA ----------------
// X[nl][k1][k2][i] = sum_r Wf[k1][r] * Y[nl][k2][r][i]
// Per block (nl,k2): 4 real GEMMs M=80(k1,pad) x N=64(i) x K=64(r) via
// mfma_f32_16x16x32_bf16. A = Wfb (LDS, [k1][r] bf16), B = Y^T (LDS, [i][r]
// bf16, converted+transposed during staging). 16B blocks XOR-swizzled by
// (row&7) for alignment + bank spread. 8 waves x 20 output tiles.
// Frag layout: A row=lane%16, k=(lane>>4)*8+e; B col=lane%16, same k;
// D col=lane&15 (i), row=(lane>>4)*4+reg (k1)  [m89-verified].
__global__ __launch_bounds__(512) void k_fwd_col(
        const float* __restrict__ Y, const ushort* __restrict__ Wfb,
        float* __restrict__ X) {
    __shared__ __align__(16) ushort sAr[80 * 64];
    __shared__ __align__(16) ushort sAi[80 * 64];
    __shared__ __align__(16) ushort sBr[64 * 64];
    __shared__ __align__(16) ushort sBi[64 * 64];
    int lc = blockIdx.x / 560;
    int rem = blockIdx.x % 560;
    int nl = rem / KH, k2 = rem % KH;
    const float* Yg = Y + (size_t)lc * CHS + ((size_t)(nl * KH + k2)) * 8192;
    float* Xc = X + (size_t)lc * CHS;
    int t = threadIdx.x;
    // stage A: Wfb planes, swizzled 16B blocks
    for (int e = t; e < 5120; e += 512) {
        int m = e >> 6, r = e & 63;
        int sw = (m << 6) + ((((r >> 3) ^ (m & 7))) << 3) + (r & 7);
        sAr[sw] = Wfb[e];
        sAi[sw] = Wfb[5120 + e];
    }
    // stage B: Y fp32 [r][i] -> bf16 planes [i][r], swizzled
    for (int e = t; e < 4096; e += 512) {
        int i = e & 63, r = e >> 6;
        float2 v = *(const float2*)(Yg + (r << 7) + 2 * i);
        int sw = (i << 6) + ((((r >> 3) ^ (i & 7))) << 3) + (r & 7);
        sBr[sw] = f2bf(v.x);
        sBi[sw] = f2bf(v.y);
    }
    __syncthreads();
    int lane = t & 63, w = t >> 6;
    int lm = lane & 15, kg = lane >> 4;
    int ba0 = ((kg ^ (lm & 7)) << 3);
    int ba1 = (((kg + 4) ^ (lm & 7)) << 3);
    for (int tid = w; tid < 20; tid += 8) {
        int mt = tid >> 2, nt = tid & 3;
        int am = mt * 16 + lm, bn = nt * 16 + lm;
        s16x8 ar0 = *(const s16x8*)(sAr + (am << 6) + ba0);
        s16x8 ar1 = *(const s16x8*)(sAr + (am << 6) + ba1);
        s16x8 ai0 = *(const s16x8*)(sAi + (am << 6) + ba0);
        s16x8 ai1 = *(const s16x8*)(sAi + (am << 6) + ba1);
        s16x8 br0 = *(const s16x8*)(sBr + (bn << 6) + ba0);
        s16x8 br1 = *(const s16x8*)(sBr + (bn << 6) + ba1);
        s16x8 bi0 = *(const s16x8*)(sBi + (bn << 6) + ba0);
        s16x8 bi1 = *(const s16x8*)(sBi + (bn << 6) + ba1);
        f32x4 rr = {0.f, 0.f, 0.f, 0.f}, ii = rr, ri = rr, ir = rr;
        rr = __builtin_amdgcn_mfma_f32_16x16x32_bf16(ar0, br0, rr, 0, 0, 0);
        rr = __builtin_amdgcn_mfma_f32_16x16x32_bf16(ar1, br1, rr, 0, 0, 0);
        ii = __builtin_amdgcn_mfma_f32_16x16x32_bf16(ai0, bi0, ii, 0, 0, 0);
        ii = __builtin_amdgcn_mfma_f32_16x16x32_bf16(ai1, bi1, ii, 0, 0, 0);
        ri = __builtin_amdgcn_mfma_f32_16x16x32_bf16(ar0, bi0, ri, 0, 0, 0);
        ri = __builtin_amdgcn_mfma_f32_16x16x32_bf16(ar1, bi1, ri, 0, 0, 0);
        ir = __builtin_amdgcn_mfma_f32_16x16x32_bf16(ai0, br0, ir, 0, 0, 0);
        ir = __builtin_amdgcn_mfma_f32_16x16x32_bf16(ai1, br1, ir, 0, 0, 0);
        #pragma unroll
        for (int g2 = 0; g2 < 4; ++g2) {
            int k1 = mt * 16 + kg * 4 + g2;
            if (k1 < 68) {
                float2 res = make_float2(rr[g2] - ii[g2], ri[g2] + ir[g2]);
                *(float2*)(Xc + ((size_t)(nl * 68 + k1) * KH + k2) * 128
                           + 2 * (nt * 16 + lm)) = res;
            }
        }
    }
}

// ---------------- stage 3: per-bin channel mix (2o x 2n register tile) -----
// O[nl][k2][k1][o] = sum_i X[nl][k1][k2][i] * K[bin][i][o]
__global__ void k_mix(const float* __restrict__ X, const float* __restrict__ Kt,
                      const float* __restrict__ kr, const float* __restrict__ ki,
                      float* __restrict__ O, int useKt) {
    __shared__ float xl[16 * 128];       // [n][i][c]  8 KB
    __shared__ float kl[64 * 64 * 2];    // [i][o][c] 32 KB
    int lc = blockIdx.x / 2380;
    int bin = blockIdx.x % 2380;
    int k1 = bin / KH, k2 = bin % KH;
    const float* Xc = X + (size_t)lc * CHS;
    float* Oc = O + (size_t)lc * CHS;
    int t = threadIdx.x;
    for (int e = t; e < 2048; e += 256) {
        int n = e >> 7, ic = e & 127;
        xl[e] = Xc[((size_t)(n * 68 + k1) * KH + k2) * 128 + ic];
    }
    if (useKt) {
        const float* src = Kt + (size_t)bin * 8192;
        for (int e = t; e < 8192; e += 256) kl[e] = src[e];
    } else {
        for (int e = t; e < 4096; e += 256) {
            int o = e >> 6, i = e & 63;
            size_t gi = ((size_t)(o * 64 + i) * 68 + k1) * 68 + k2;
            kl[i * 128 + o * 2]     = kr[gi];
            kl[i * 128 + o * 2 + 1] = ki[gi];
        }
    }
    __syncthreads();
    int op = t & 31, g = t >> 5;         // o = 2op,2op+1 ; n = g, g+8
    float a0r=0,a0i=0,a1r=0,a1i=0,b0r=0,b0i=0,b1r=0,b1i=0;
    for (int i = 0; i < 64; ++i) {
        float4 kv = *(const float4*)(kl + i * 128 + op * 4);
        float2 c0 = *(const float2*)(xl + (g << 7) + i * 2);
        float2 c1 = *(const float2*)(xl + ((g + 8) << 7) + i * 2);
        a0r += kv.x * c0.x - kv.y * c0.y;  a0i += kv.x * c0.y + kv.y * c0.x;
        a1r += kv.z * c0.x - kv.w * c0.y;  a1i += kv.z * c0.y + kv.w * c0.x;
        b0r += kv.x * c1.x - kv.y * c1.y;  b0i += kv.x * c1.y + kv.y * c1.x;
        b1r += kv.z * c1.x - kv.w * c1.y;  b1i += kv.z * c1.y + kv.w * c1.x;
    }
    size_t base0 = ((((size_t)g       * KH + k2) * 68 + k1) * 64 + 2 * op) * 2;
    size_t base1 = ((((size_t)(g + 8) * KH + k2) * 68 + k1) * 64 + 2 * op) * 2;
    *(float4*)(Oc + base0) = make_float4(a0r, a0i, a1r, a1i);
    *(float4*)(Oc + base1) = make_float4(b0r, b0i, b1r, b1i);
}

// ---------------- stage 4: inverse col DFT (reg-blocked p sweep, LDS tw) ----
// Z[nl][p][k2][o] = sum_k1 Wi[p][k1] * O[nl][k2][k1][o]
__global__ __launch_bounds__(512) void k_inv_col(
        const float* __restrict__ O, const float* __restrict__ Wi2,
        float* __restrict__ Z) {
    __shared__ float ol[68 * 128];       // 34 KB   [k1][o][c]
    __shared__ float wih[40 * 136];      // 21.8 KB [pl][k1][c] (padded rows zero)
    int lc = blockIdx.x / 1120;
    int rem = blockIdx.x % 1120;
    int ph = rem & 1;
    int rest = rem >> 1;
    int k2 = rest % KH, nl = rest / KH;
    int t = threadIdx.x;
    const float* Oc = O + (size_t)lc * CHS;
    float* Zc = Z + (size_t)lc * CHS;
    const float4* osrc = (const float4*)(Oc + ((size_t)nl * KH + k2) * 68 * 128);
    float4* ol4 = (float4*)ol;
    for (int e = t; e < 68 * 32; e += 512) ol4[e] = osrc[e];
    const float4* wsrc4 = (const float4*)(Wi2 + (size_t)ph * 5440);
    float4* wi4 = (float4*)wih;
    for (int e = t; e < 1360; e += 512) wi4[e] = wsrc4[e];
    __syncthreads();
    int o = t & 63, g = t >> 6;          // wave-uniform g
    float ar[5], ai[5];
    #pragma unroll
    for (int j = 0; j < 5; ++j) { ar[j] = 0.f; ai[j] = 0.f; }
    const float* oo_ = ol + 2 * o;
    const float* wb = wih + g * 136;     // wave-uniform base
    #pragma unroll 4
    for (int k1 = 0; k1 < 68; ++k1) {
        float2 ov = *(const float2*)(oo_ + (k1 << 7));
        #pragma unroll
        for (int j = 0; j < 5; ++j) {
            float2 wv = *(const float2*)(wb + j * 1088 + 2 * k1);  // broadcast
            ar[j] += wv.x * ov.x - wv.y * ov.y;
            ai[j] += wv.x * ov.y + wv.y * ov.x;
        }
    }
    #pragma unroll
    for (int j = 0; j < 5; ++j) {
        int pl = g + 8 * j;
        if (pl < 34) {
            int p = ph * 34 + pl;
            *(float2*)(Zc + ((size_t)(nl * 68 + p) * KH + k2) * 128 + 2 * o)
                = make_float2(ar[j], ai[j]);
        }
    }
}

// ---------------- stage 5: inverse row DFT + overlap-add --------------------
__global__ __launch_bounds__(256) void k_fused_inv(
        const float* __restrict__ Z, const float* __restrict__ Wg,
        const float* __restrict__ bias, float* __restrict__ out, int c0) {
    __shared__ float zl[KH * 128];       // 17.9 KB [k2][o][c]
    __shared__ float wg[68 * 70];        // 19.0 KB [q][k2c]
    int lc = blockIdx.x / 1088;
    int rem = blockIdx.x % 1088;
    int nl = rem / 68, p = rem % 68;
    int b = c0 + lc;
    int tr = nl >> 2, tc = nl & 3;
    int y = 66 * tr + p;
    if (y >= 256) return;
    int t = threadIdx.x;
    const float4* zs4 = (const float4*)(Z + (size_t)lc * CHS
                                        + ((size_t)(nl * 68 + p)) * 4480);
    float4* zl4 = (float4*)zl;
    for (int e = t; e < 1120; e += 256) zl4[e] = zs4[e];
    for (int e = t; e < 4760; e += 256) wg[e] = Wg[e];
    __syncthreads();

    int o = t & 63, qg = t >> 6;         // qg in 0..3, q = qg*17 + j
    float bv = bias[o];
    const float* zr = zl + 2 * o;
    const float* wbase = wg + (qg * 17) * 70;

    float acc[17];
    #pragma unroll
    for (int j = 0; j < 17; ++j) acc[j] = 0.f;

    for (int k2 = 0; k2 < KH; ++k2) {
        float2 zv = *(const float2*)(zr + (k2 << 7));
        #pragma unroll
        for (int j = 0; j < 17; ++j) {
            float2 wv = *(const float2*)(wbase + j * 70 + 2 * k2);  // broadcast
            acc[j] += zv.x * wv.x - zv.y * wv.y;
        }
    }

    bool rowu = !((p <= 1 && tr > 0) || (p >= 66 && tr < 3));
    float* orow = out + ((size_t)(b * 256 + y)) * 256 * 64 + o;
    #pragma unroll
    for (int j = 0; j < 17; ++j) {
        int q = qg * 17 + j;
        int x = 66 * tc + q;
        if (x >= 256) continue;
        bool colu = !((q <= 1 && tc > 0) || (q >= 66 && tc < 3));
        float v = acc[j] + bv;
        if (rowu && colu) orow[(size_t)x * 64] = v;
        else              atomicAdd(orow + (size_t)x * 64, v);
    }
}

extern "C" void kernel_launch(void* const* d_in, const int* in_sizes, int n_in,
                              void* d_out, int out_size, void* d_ws, size_t ws_size,
                              hipStream_t stream) {
    const float* x    = (const float*)d_in[0];
    const float* kr   = (const float*)d_in[1];
    const float* ki   = (const float*)d_in[2];
    const float* bias = (const float*)d_in[3];
    float* out = (float*)d_out;
    float* ws  = (float*)d_ws;

    int useKt = 1;
    int CH = 8;
    while (CH > 1 && (WS_HEAD + KT_FLOATS + 2ull * CH * CHS) * 4ull > ws_size) CH >>= 1;
    if ((WS_HEAD + KT_FLOATS + 2ull * CH * CHS) * 4ull > ws_size) {
        useKt = 0;
        CH = 8;
        while (CH > 1 && (WS_HEAD + 2ull * CH * CHS) * 4ull > ws_size) CH >>= 1;
    }

    float*  Wf   = ws;                         // 9216 floats
    float*  Wi2  = ws + 9216;                  // 10880 floats
    float*  Wg   = ws + 20096;                 // 4760 floats
    ushort* Wfb  = (ushort*)(ws + 24856);      // 10240 ushorts (bf16 twiddles)
    float*  Kt   = ws + WS_HEAD;               // KT_FLOATS (if useKt)
    float*  bufA = Kt + (useKt ? KT_FLOATS : 0);  // Y then O
    float*  bufB = bufA + (size_t)CH * CHS;       // X then Z

    k_twiddle<<<1, 256, 0, stream>>>(ws);
    if (useKt)
        k_ktrans<<<68 * 64, 256, 0, stream>>>(kr, ki, Kt);
    k_zero_seams<<<96, 256, 0, stream>>>(out);

    for (int s = 0; s < 8; s += CH) {
        k_fwd_row<<<CH * 1024, 256, 0, stream>>>(x, Wf, bufA, s);
        k_fwd_col<<<CH * 560, 512, 0, stream>>>(bufA, Wfb, bufB);
        k_mix<<<CH * 2380, 256, 0, stream>>>(bufB, Kt, kr, ki, bufA, useKt);
        k_inv_col<<<CH * 1120, 512, 0, stream>>>(bufA, Wi2, bufB);
        k_fused_inv<<<CH * 1088, 256, 0, stream>>>(bufB, Wg, bias, out, s);
    }
}

// Round 16
// 869.472 us; speedup vs baseline: 1.6206x; 1.2797x over previous
//
#include <hip/hip_runtime.h>
#include <hip/hip_bf16.h>

// FFT-tiled conv: B=8, IMG=256, CIN=COUT=64, TILE=64, FFT=68, PAD=2.
// Frequency-domain per-tile conv via DFT-as-matmul, Hermitian half-spectrum
// (k2 in [0,35)), direct overlap-add (plain stores interior, atomics on seams,
// seam bands pre-zeroed). Stages 2,3,4 run on bf16 MFMA.
//
// Layouts (per 16-tile chunk slot of CHS floats):
//   Y  [nl][k2][r][i][c]      in bufA     ((nl*35+k2)*64+r)*128
//   X  [nl][k1][k2][i][c]     in bufB     ((nl*68+k1)*35+k2)*128
//   Ktb[bin][2][o][i] bf16 pre-swizzled   39 MB, one-time (bin = k1*35+k2)
//   O  [nl][k2][k1][o][c]     in bufA     ((nl*35+k2)*68+k1)*128
//   Z  [nl][p][k2][o][c]      in bufB     ((nl*68+p)*35+k2)*128
//
// Twiddle tables:
//   Wf  [72][64] cplx fp32  rows 68..71 zero      (9216 floats)
//   Wg  [68][35] cplx fp32                         (4760 floats)
//   Wfb [2][80][64] bf16 rows>=68 zero             (5120 floats)
//   Wib [2][80][136] bf16 pre-swizzled, zero-pad   (10880 floats)

#define KH   35
#define CHS  4874240ull                       // floats per chunk slot
#define KTB_FLOATS 9748480ull                 // 2380*8192 ushorts / 2
#define KT_FLOATS  19496960ull                // fp32 scratch Kt (in bufB)
#define WS_HEAD 29976ull                      // 9216+4760+5120+10880

typedef float f32x4 __attribute__((ext_vector_type(4)));
typedef short s16x8 __attribute__((ext_vector_type(8)));

__device__ __forceinline__ ushort f2bf(float f) {
    __hip_bfloat16 h = __float2bfloat16(f);
    return *reinterpret_cast<ushort*>(&h);
}

__global__ void k_twiddle(float* ws) {
    const float TWO_PI = 6.28318530717958647692f;
    int t = threadIdx.x;
    float* Wf = ws;                       // 72 x 64 cplx fp32
    for (int e = t; e < 72 * 64; e += 256) {
        int k = e >> 6, m = e & 63;
        float vr = 0.f, vi = 0.f;
        if (k < 68) {
            int ph = (k * (m + 2)) % 68;
            float a = TWO_PI * (float)ph / 68.0f;
            vr = cosf(a); vi = -sinf(a);
        }
        Wf[2 * e] = vr; Wf[2 * e + 1] = vi;
    }
    float* Wg = ws + 9216;                // 68 x 35 cplx fp32
    for (int e = t; e < 68 * KH; e += 256) {
        int q = e / KH, k2 = e % KH;
        int ph = (q * k2) % 68;
        float a = TWO_PI * (float)ph / 68.0f;
        float alpha = (k2 == 0 || k2 == 34) ? 1.0f : 2.0f;
        Wg[2 * e]     = alpha * cosf(a) / 68.0f;
        Wg[2 * e + 1] = alpha * sinf(a) / 68.0f;
    }
    ushort* Wfb = (ushort*)(ws + 13976);  // [2][80][64] bf16 (fwd col twiddles)
    for (int e = t; e < 80 * 64; e += 256) {
        int k = e >> 6, r = e & 63;
        float vr = 0.f, vi = 0.f;
        if (k < 68) {
            int ph = (k * (r + 2)) % 68;
            float a = TWO_PI * (float)ph / 68.0f;
            vr = cosf(a); vi = -sinf(a);
        }
        Wfb[e]        = f2bf(vr);
        Wfb[5120 + e] = f2bf(vi);
    }
    ushort* Wib = (ushort*)(ws + 19096);  // [2][80][136] bf16 pre-swizzled
    for (int e = t; e < 80 * 96; e += 256) {
        int p = e / 96, k = e % 96;
        float vr = 0.f, vi = 0.f;
        if (p < 68 && k < 68) {
            int ph = (p * k) % 68;
            float a = TWO_PI * (float)ph / 68.0f;
            vr = cosf(a) / 68.0f; vi = sinf(a) / 68.0f;
        }
        int dst = p * 136 + (((k >> 3) ^ (p & 7)) << 3) + (k & 7);
        Wib[dst]         = f2bf(vr);
        Wib[10880 + dst] = f2bf(vi);
    }
}

// zero only the seam bands (rows/cols 66,67,132,133,198,199 of each image)
__global__ void k_zero_seams(float* out) {
    int b = blockIdx.x / 12, line = blockIdx.x % 12;
    const int seam[6] = {66, 67, 132, 133, 198, 199};
    int t = threadIdx.x;
    if (line < 6) {
        int y = seam[line];
        float4* dst = (float4*)(out + ((size_t)(b * 256 + y)) * 256 * 64);
        for (int e = t; e < 4096; e += 256) dst[e] = make_float4(0, 0, 0, 0);
    } else {
        int x = seam[line - 6];
        float4* dst = (float4*)out;
        for (int e = t; e < 4096; e += 256) {
            int y = e >> 4, f = e & 15;
            dst[(((size_t)(b * 256 + y)) * 256 + x) * 16 + f] = make_float4(0, 0, 0, 0);
        }
    }
}

// ---------- one-time: kernel spectrum -> fp32 Kt[bin][i][o][c] (scratch) ----
__global__ void k_ktrans(const float* __restrict__ kr, const float* __restrict__ ki,
                         float* __restrict__ Kt) {
    __shared__ float tr[64 * 37];
    __shared__ float ti[64 * 37];
    int k1 = blockIdx.x >> 6, i = blockIdx.x & 63;
    int t = threadIdx.x;
    for (int e = t; e < 64 * KH; e += 256) {
        int o = e / KH, k2 = e % KH;
        size_t src = ((size_t)(o * 64 + i) * 68 + k1) * 68 + k2;
        tr[o * 37 + k2] = kr[src];
        ti[o * 37 + k2] = ki[src];
    }
    __syncthreads();
    for (int e = t; e < KH * 64; e += 256) {
        int k2 = e >> 6, o = e & 63;
        size_t dst = ((size_t)(k1 * KH + k2)) * 8192 + (size_t)i * 128 + o * 2;
        Kt[dst]     = tr[o * 37 + k2];
        Kt[dst + 1] = ti[o * 37 + k2];
    }
}

// ---------- one-time: Kt fp32 -> Ktb bf16 [bin][plane][o][i_swz] ------------
__global__ void k_kconv(const float* __restrict__ Kt, ushort* __restrict__ Ktb) {
    __shared__ float kl[64 * 130];       // [i][o*c] padded
    int bin = blockIdx.x;
    int t = threadIdx.x;
    const float4* src = (const float4*)(Kt + (size_t)bin * 8192);
    for (int e = t; e < 2048; e += 256) {
        float4 v = src[e];
        int i = e >> 5, oc = (e & 31) << 2;
        kl[i * 130 + oc]     = v.x;
        kl[i * 130 + oc + 1] = v.y;
        kl[i * 130 + oc + 2] = v.z;
        kl[i * 130 + oc + 3] = v.w;
    }
    __syncthreads();
    ushort* dst = Ktb + (size_t)bin * 8192;
    for (int e = t; e < 4096; e += 256) {
        int o = e >> 6, i = e & 63;
        int sw = (o << 6) + (((i >> 3) ^ (o & 7)) << 3) + (i & 7);
        dst[sw]        = f2bf(kl[i * 130 + 2 * o]);
        dst[4096 + sw] = f2bf(kl[i * 130 + 2 * o + 1]);
    }
}

// ---------------- stage 1: row DFT ----------------
// Y[nl][k2][r][i] = sum_c x[b, tr*64+r, tc*64+c, i] * Wf[k2][c]
__global__ void k_fwd_row(const float* __restrict__ x, const float* __restrict__ Wf,
                          float* __restrict__ Y, int c0) {
    __shared__ float xr[64 * 64];        // [c][i]
    __shared__ float wf[KH * 64 * 2];    // [k2][c]
    __shared__ float yout[KH * 128];     // [k2][i][c]
    int lc = blockIdx.x >> 10;
    int rem = blockIdx.x & 1023;
    int nl = rem >> 6, r = rem & 63;
    int n = (c0 + lc) * 16 + nl;
    int b = n >> 4, tr = (n >> 2) & 3, tc = n & 3;
    const float* src = x + (((size_t)(b * 256 + tr * 64 + r)) * 256 + tc * 64) * 64;
    int t = threadIdx.x;
    const float4* src4 = (const float4*)src;
    float4* xr4 = (float4*)xr;
    for (int e = t; e < 1024; e += 256) xr4[e] = src4[e];
    for (int e = t; e < KH * 64 * 2; e += 256) wf[e] = Wf[e];
    __syncthreads();
    int i = t & 63, kg = t >> 6;
    for (int k2 = kg; k2 < KH; k2 += 4) {
        float ar = 0.f, ai = 0.f;
        const float* w = wf + k2 * 128;
        for (int c = 0; c < 64; ++c) {
            float v = xr[(c << 6) | i];
            ar += v * w[2 * c];
            ai += v * w[2 * c + 1];
        }
        yout[(k2 << 7) + 2 * i]     = ar;
        yout[(k2 << 7) + 2 * i + 1] = ai;
    }
    __syncthreads();
    float* Yc = Y + (size_t)lc * CHS;
    const float4* ys4 = (const float4*)yout;
    for (int e = t; e < KH * 32; e += 256) {
        int k2 = e >> 5, f = e & 31;
        ((float4*)(Yc + ((size_t)(nl * KH + k2) * 64 + r) * 128))[f] = ys4[e];
    }
}

// ---------------- stage 2: column DFT — bf16 MFMA ----------------
// X[nl][k1][k2][i] = sum_r Wf[k1][r] * Y[nl][k2][r][i]
__global__ __launch_bounds__(512) void k_fwd_col(
        const float* __restrict__ Y, const ushort* __restrict__ Wfb,
        float* __restrict__ X) {
    __shared__ __align__(16) ushort sAr[80 * 64];
    __shared__ __align__(16) ushort sAi[80 * 64];
    __shared__ __align__(16) ushort sBr[64 * 64];
    __shared__ __align__(16) ushort sBi[64 * 64];
    int lc = blockIdx.x / 560;
    int rem = blockIdx.x % 560;
    int nl = rem / KH, k2 = rem % KH;
    const float* Yg = Y + (size_t)lc * CHS + ((size_t)(nl * KH + k2)) * 8192;
    float* Xc = X + (size_t)lc * CHS;
    int t = threadIdx.x;
    for (int e = t; e < 5120; e += 512) {
        int m = e >> 6, r = e & 63;
        int sw = (m << 6) + ((((r >> 3) ^ (m & 7))) << 3) + (r & 7);
        sAr[sw] = Wfb[e];
        sAi[sw] = Wfb[5120 + e];
    }
    for (int e = t; e < 4096; e += 512) {
        int i = e & 63, r = e >> 6;
        float2 v = *(const float2*)(Yg + (r << 7) + 2 * i);
        int sw = (i << 6) + ((((r >> 3) ^ (i & 7))) << 3) + (r & 7);
        sBr[sw] = f2bf(v.x);
        sBi[sw] = f2bf(v.y);
    }
    __syncthreads();
    int lane = t & 63, w = t >> 6;
    int lm = lane & 15, kg = lane >> 4;
    int ba0 = ((kg ^ (lm & 7)) << 3);
    int ba1 = (((kg + 4) ^ (lm & 7)) << 3);
    for (int tid = w; tid < 20; tid += 8) {
        int mt = tid >> 2, nt = tid & 3;
        int am = mt * 16 + lm, bn = nt * 16 + lm;
        s16x8 ar0 = *(const s16x8*)(sAr + (am << 6) + ba0);
        s16x8 ar1 = *(const s16x8*)(sAr + (am << 6) + ba1);
        s16x8 ai0 = *(const s16x8*)(sAi + (am << 6) + ba0);
        s16x8 ai1 = *(const s16x8*)(sAi + (am << 6) + ba1);
        s16x8 br0 = *(const s16x8*)(sBr + (bn << 6) + ba0);
        s16x8 br1 = *(const s16x8*)(sBr + (bn << 6) + ba1);
        s16x8 bi0 = *(const s16x8*)(sBi + (bn << 6) + ba0);
        s16x8 bi1 = *(const s16x8*)(sBi + (bn << 6) + ba1);
        f32x4 rr = {0.f, 0.f, 0.f, 0.f}, ii = rr, ri = rr, ir = rr;
        rr = __builtin_amdgcn_mfma_f32_16x16x32_bf16(ar0, br0, rr, 0, 0, 0);
        rr = __builtin_amdgcn_mfma_f32_16x16x32_bf16(ar1, br1, rr, 0, 0, 0);
        ii = __builtin_amdgcn_mfma_f32_16x16x32_bf16(ai0, bi0, ii, 0, 0, 0);
        ii = __builtin_amdgcn_mfma_f32_16x16x32_bf16(ai1, bi1, ii, 0, 0, 0);
        ri = __builtin_amdgcn_mfma_f32_16x16x32_bf16(ar0, bi0, ri, 0, 0, 0);
        ri = __builtin_amdgcn_mfma_f32_16x16x32_bf16(ar1, bi1, ri, 0, 0, 0);
        ir = __builtin_amdgcn_mfma_f32_16x16x32_bf16(ai0, br0, ir, 0, 0, 0);
        ir = __builtin_amdgcn_mfma_f32_16x16x32_bf16(ai1, br1, ir, 0, 0, 0);
        #pragma unroll
        for (int g2 = 0; g2 < 4; ++g2) {
            int k1 = mt * 16 + kg * 4 + g2;
            if (k1 < 68) {
                float2 res = make_float2(rr[g2] - ii[g2], ri[g2] + ir[g2]);
                *(float2*)(Xc + ((size_t)(nl * 68 + k1) * KH + k2) * 128
                           + 2 * (nt * 16 + lm)) = res;
            }
        }
    }
}

// ---------------- stage 3: channel mix — bf16 MFMA ----------------
// O[nl][k2][k1][o] = sum_i X[nl][k1][k2][i] * K[bin][i][o]
// A = X [n(16)][i] bf16 swizzled; B = Ktb [o][i] (pre-swizzled global copy).
__global__ __launch_bounds__(256) void k_mix(
        const float* __restrict__ X, const ushort* __restrict__ Ktb,
        float* __restrict__ O) {
    __shared__ __align__(16) ushort sAr[16 * 64];
    __shared__ __align__(16) ushort sAi[16 * 64];
    __shared__ __align__(16) ushort sB[2 * 64 * 64];
    int lc = blockIdx.x / 2380;
    int bin = blockIdx.x % 2380;
    int k1 = bin / KH, k2 = bin % KH;
    const float* Xc = X + (size_t)lc * CHS;
    float* Oc = O + (size_t)lc * CHS;
    int t = threadIdx.x;
    for (int e = t; e < 1024; e += 256) {
        int n = e >> 6, i = e & 63;
        float2 v = *(const float2*)(Xc + ((size_t)(n * 68 + k1) * KH + k2) * 128 + 2 * i);
        int sw = (n << 6) + (((i >> 3) ^ (n & 7)) << 3) + (i & 7);
        sAr[sw] = f2bf(v.x);
        sAi[sw] = f2bf(v.y);
    }
    const uint4* ksrc = (const uint4*)(Ktb + (size_t)bin * 8192);
    for (int e = t; e < 1024; e += 256) ((uint4*)sB)[e] = ksrc[e];
    __syncthreads();
    const ushort* sBr = sB;
    const ushort* sBi = sB + 4096;
    int lane = t & 63, w = t >> 6;       // w = o-tile
    int lm = lane & 15, kg = lane >> 4;
    f32x4 rr = {0.f, 0.f, 0.f, 0.f}, ii = rr, ri = rr, ir = rr;
    #pragma unroll
    for (int st = 0; st < 2; ++st) {
        int blk = kg + st * 4;
        int ao = (lm << 6) + ((blk ^ (lm & 7)) << 3);
        int bo = ((w * 16 + lm) << 6) + ((blk ^ (lm & 7)) << 3);
        s16x8 axr = *(const s16x8*)(sAr + ao);
        s16x8 axi = *(const s16x8*)(sAi + ao);
        s16x8 bxr = *(const s16x8*)(sBr + bo);
        s16x8 bxi = *(const s16x8*)(sBi + bo);
        rr = __builtin_amdgcn_mfma_f32_16x16x32_bf16(axr, bxr, rr, 0, 0, 0);
        ii = __builtin_amdgcn_mfma_f32_16x16x32_bf16(axi, bxi, ii, 0, 0, 0);
        ri = __builtin_amdgcn_mfma_f32_16x16x32_bf16(axr, bxi, ri, 0, 0, 0);
        ir = __builtin_amdgcn_mfma_f32_16x16x32_bf16(axi, bxr, ir, 0, 0, 0);
    }
    #pragma unroll
    for (int g2 = 0; g2 < 4; ++g2) {
        int n = kg * 4 + g2;
        int o = w * 16 + lm;
        *(float2*)(Oc + (((size_t)n * KH + k2) * 68 + k1) * 128 + 2 * o)
            = make_float2(rr[g2] - ii[g2], ri[g2] + ir[g2]);
    }
}

// ---------------- stage 4: inverse column DFT — bf16 MFMA ----------------
// Z[nl][p][k2][o] = sum_k1 Wi[p][k1] * O[nl][k2][k1][o]
// A = Wib [p(80)][k1(96 pad, stride 136)] pre-swizzled; B = O^T [o][k1] bf16.
__global__ __launch_bounds__(512) void k_inv_col(
        const float* __restrict__ O, const ushort* __restrict__ Wib,
        float* __restrict__ Z) {
    __shared__ __align__(16) ushort sAr[80 * 136];
    __shared__ __align__(16) ushort sAi[80 * 136];
    __shared__ __align__(16) ushort sBr[64 * 136];
    __shared__ __align__(16) ushort sBi[64 * 136];
    int lc = blockIdx.x / 560;
    int rem = blockIdx.x % 560;
    int nl = rem / KH, k2 = rem % KH;
    int t = threadIdx.x;
    const float* Ob = O + (size_t)lc * CHS + ((size_t)nl * KH + k2) * 68 * 128;
    float* Zc = Z + (size_t)lc * CHS;
    const uint4* wsrc = (const uint4*)Wib;
    for (int e = t; e < 1360; e += 512) ((uint4*)sAr)[e] = wsrc[e];
    for (int e = t; e < 1360; e += 512) ((uint4*)sAi)[e] = wsrc[1360 + e];
    uint4 zz = {0, 0, 0, 0};
    for (int e = t; e < 1088; e += 512) { ((uint4*)sBr)[e] = zz; ((uint4*)sBi)[e] = zz; }
    __syncthreads();
    for (int e = t; e < 4352; e += 512) {
        int k1 = e >> 6, o = e & 63;
        float2 v = *(const float2*)(Ob + (size_t)k1 * 128 + 2 * o);
        int sw = o * 136 + (((k1 >> 3) ^ (o & 7)) << 3) + (k1 & 7);
        sBr[sw] = f2bf(v.x);
        sBi[sw] = f2bf(v.y);
    }
    __syncthreads();
    int lane = t & 63, w = t >> 6;
    int lm = lane & 15, kg = lane >> 4;
    for (int tid = w; tid < 20; tid += 8) {
        int mt = tid >> 2, nt = tid & 3;
        int am = mt * 16 + lm, bn = nt * 16 + lm;
        f32x4 rr = {0.f, 0.f, 0.f, 0.f}, ii = rr, ri = rr, ir = rr;
        #pragma unroll
        for (int st = 0; st < 3; ++st) {
            int blk = kg + st * 4;
            int off = ((blk ^ (lm & 7)) << 3);
            s16x8 axr = *(const s16x8*)(sAr + am * 136 + off);
            s16x8 axi = *(const s16x8*)(sAi + am * 136 + off);
            s16x8 bxr = *(const s16x8*)(sBr + bn * 136 + off);
            s16x8 bxi = *(const s16x8*)(sBi + bn * 136 + off);
            rr = __builtin_amdgcn_mfma_f32_16x16x32_bf16(axr, bxr, rr, 0, 0, 0);
            ii = __builtin_amdgcn_mfma_f32_16x16x32_bf16(axi, bxi, ii, 0, 0, 0);
            ri = __builtin_amdgcn_mfma_f32_16x16x32_bf16(axr, bxi, ri, 0, 0, 0);
            ir = __builtin_amdgcn_mfma_f32_16x16x32_bf16(axi, bxr, ir, 0, 0, 0);
        }
        #pragma unroll
        for (int g2 = 0; g2 < 4; ++g2) {
            int p = mt * 16 + kg * 4 + g2;
            if (p < 68) {
                *(float2*)(Zc + (((size_t)(nl * 68 + p)) * KH + k2) * 128
                           + 2 * (nt * 16 + lm))
                    = make_float2(rr[g2] - ii[g2], ri[g2] + ir[g2]);
            }
        }
    }
}

// ---------------- stage 5: inverse row DFT + overlap-add --------------------
__global__ __launch_bounds__(256) void k_fused_inv(
        const float* __restrict__ Z, const float* __restrict__ Wg,
        const float* __restrict__ bias, float* __restrict__ out, int c0) {
    __shared__ float zl[KH * 128];       // 17.9 KB [k2][o][c]
    __shared__ float wg[68 * 70];        // 19.0 KB [q][k2c]
    int lc = blockIdx.x / 1088;
    int rem = blockIdx.x % 1088;
    int nl = rem / 68, p = rem % 68;
    int b = c0 + lc;
    int tr = nl >> 2, tc = nl & 3;
    int y = 66 * tr + p;
    if (y >= 256) return;
    int t = threadIdx.x;
    const float4* zs4 = (const float4*)(Z + (size_t)lc * CHS
                                        + ((size_t)(nl * 68 + p)) * 4480);
    float4* zl4 = (float4*)zl;
    for (int e = t; e < 1120; e += 256) zl4[e] = zs4[e];
    for (int e = t; e < 4760; e += 256) wg[e] = Wg[e];
    __syncthreads();

    int o = t & 63, qg = t >> 6;         // qg in 0..3, q = qg*17 + j
    float bv = bias[o];
    const float* zr = zl + 2 * o;
    const float* wbase = wg + (qg * 17) * 70;

    float acc[17];
    #pragma unroll
    for (int j = 0; j < 17; ++j) acc[j] = 0.f;

    for (int k2 = 0; k2 < KH; ++k2) {
        float2 zv = *(const float2*)(zr + (k2 << 7));
        #pragma unroll
        for (int j = 0; j < 17; ++j) {
            float2 wv = *(const float2*)(wbase + j * 70 + 2 * k2);  // broadcast
            acc[j] += zv.x * wv.x - zv.y * wv.y;
        }
    }

    bool rowu = !((p <= 1 && tr > 0) || (p >= 66 && tr < 3));
    float* orow = out + ((size_t)(b * 256 + y)) * 256 * 64 + o;
    #pragma unroll
    for (int j = 0; j < 17; ++j) {
        int q = qg * 17 + j;
        int x = 66 * tc + q;
        if (x >= 256) continue;
        bool colu = !((q <= 1 && tc > 0) || (q >= 66 && tc < 3));
        float v = acc[j] + bv;
        if (rowu && colu) orow[(size_t)x * 64] = v;
        else              atomicAdd(orow + (size_t)x * 64, v);
    }
}

extern "C" void kernel_launch(void* const* d_in, const int* in_sizes, int n_in,
                              void* d_out, int out_size, void* d_ws, size_t ws_size,
                              hipStream_t stream) {
    const float* x    = (const float*)d_in[0];
    const float* kr   = (const float*)d_in[1];
    const float* ki   = (const float*)d_in[2];
    const float* bias = (const float*)d_in[3];
    float* out = (float*)d_out;
    float* ws  = (float*)d_ws;

    int CH = 8;
    while (CH > 4 && (WS_HEAD + KTB_FLOATS + 2ull * CH * CHS) * 4ull > ws_size)
        CH >>= 1;

    float*  Wf   = ws;                         // 9216 floats
    float*  Wg   = ws + 9216;                  // 4760 floats
    ushort* Wfb  = (ushort*)(ws + 13976);      // 10240 ushorts
    ushort* Wib  = (ushort*)(ws + 19096);      // 21760 ushorts
    ushort* Ktb  = (ushort*)(ws + WS_HEAD);    // 2380*8192 ushorts
    float*  bufA = ws + WS_HEAD + KTB_FLOATS;  // Y then O
    float*  bufB = bufA + (size_t)CH * CHS;    // X then Z (also Kt scratch)

    k_twiddle<<<1, 256, 0, stream>>>(ws);
    k_ktrans<<<68 * 64, 256, 0, stream>>>(kr, ki, bufB);   // fp32 Kt scratch
    k_kconv<<<2380, 256, 0, stream>>>(bufB, Ktb);          // -> bf16 pre-swizzled
    k_zero_seams<<<96, 256, 0, stream>>>(out);

    for (int s = 0; s < 8; s += CH) {
        k_fwd_row<<<CH * 1024, 256, 0, stream>>>(x, Wf, bufA, s);
        k_fwd_col<<<CH * 560, 512, 0, stream>>>(bufA, Wfb, bufB);
        k_mix<<<CH * 2380, 256, 0, stream>>>(bufB, Ktb, bufA);
        k_inv_col<<<CH * 560, 512, 0, stream>>>(bufA, Wib, bufB);
        k_fused_inv<<<CH * 1088, 256, 0, stream>>>(bufB, Wg, bias, out, s);
    }
}

// Round 17
// 670.473 us; speedup vs baseline: 2.1015x; 1.2968x over previous
//
#include <hip/hip_runtime.h>
#include <hip/hip_bf16.h>

// FFT-tiled conv: B=8, IMG=256, CIN=COUT=64, TILE=64, FFT=68, PAD=2.
// Frequency-domain per-tile conv via DFT-as-matmul, Hermitian half-spectrum
// (k2 in [0,35)), direct overlap-add (plain stores interior, atomics on seams,
// seam bands pre-zeroed). Stages 1,2,3,4 run on bf16 MFMA.
//
// Layouts (per 16-tile chunk slot of CHS floats):
//   Y  [nl][k2][r][i][c]      in bufA     ((nl*35+k2)*64+r)*128
//   X  [nl][k1][k2][i][c]     in bufB     ((nl*68+k1)*35+k2)*128
//   Ktb[bin][2][o][i] bf16 pre-swizzled   39 MB, one-time (bin = k1*35+k2)
//   O  [nl][k2][k1][o][c]     in bufA     ((nl*35+k2)*68+k1)*128
//   Z  [nl][p][k2][o][c]      in bufB     ((nl*68+p)*35+k2)*128
//
// Twiddle tables:
//   Wf  [72][64] cplx fp32  rows 68..71 zero      (9216 floats)
//   Wg  [68][35] cplx fp32                         (4760 floats)
//   Wfb [2][80][64] bf16 rows>=68 zero             (5120 floats)
//   Wib [2][80][136] bf16 pre-swizzled, zero-pad   (10880 floats)

#define KH   35
#define CHS  4874240ull                       // floats per chunk slot
#define KTB_FLOATS 9748480ull                 // 2380*8192 ushorts / 2
#define WS_HEAD 29976ull                      // 9216+4760+5120+10880

typedef float f32x4 __attribute__((ext_vector_type(4)));
typedef short s16x8 __attribute__((ext_vector_type(8)));

__device__ __forceinline__ ushort f2bf(float f) {
    __hip_bfloat16 h = __float2bfloat16(f);
    return *reinterpret_cast<ushort*>(&h);
}

__global__ void k_twiddle(float* ws) {
    const float TWO_PI = 6.28318530717958647692f;
    int t = threadIdx.x;
    float* Wf = ws;                       // 72 x 64 cplx fp32
    for (int e = t; e < 72 * 64; e += 256) {
        int k = e >> 6, m = e & 63;
        float vr = 0.f, vi = 0.f;
        if (k < 68) {
            int ph = (k * (m + 2)) % 68;
            float a = TWO_PI * (float)ph / 68.0f;
            vr = cosf(a); vi = -sinf(a);
        }
        Wf[2 * e] = vr; Wf[2 * e + 1] = vi;
    }
    float* Wg = ws + 9216;                // 68 x 35 cplx fp32
    for (int e = t; e < 68 * KH; e += 256) {
        int q = e / KH, k2 = e % KH;
        int ph = (q * k2) % 68;
        float a = TWO_PI * (float)ph / 68.0f;
        float alpha = (k2 == 0 || k2 == 34) ? 1.0f : 2.0f;
        Wg[2 * e]     = alpha * cosf(a) / 68.0f;
        Wg[2 * e + 1] = alpha * sinf(a) / 68.0f;
    }
    ushort* Wfb = (ushort*)(ws + 13976);  // [2][80][64] bf16
    for (int e = t; e < 80 * 64; e += 256) {
        int k = e >> 6, r = e & 63;
        float vr = 0.f, vi = 0.f;
        if (k < 68) {
            int ph = (k * (r + 2)) % 68;
            float a = TWO_PI * (float)ph / 68.0f;
            vr = cosf(a); vi = -sinf(a);
        }
        Wfb[e]        = f2bf(vr);
        Wfb[5120 + e] = f2bf(vi);
    }
    ushort* Wib = (ushort*)(ws + 19096);  // [2][80][136] bf16 pre-swizzled
    for (int e = t; e < 80 * 96; e += 256) {
        int p = e / 96, k = e % 96;
        float vr = 0.f, vi = 0.f;
        if (p < 68 && k < 68) {
            int ph = (p * k) % 68;
            float a = TWO_PI * (float)ph / 68.0f;
            vr = cosf(a) / 68.0f; vi = sinf(a) / 68.0f;
        }
        int dst = p * 136 + (((k >> 3) ^ (p & 7)) << 3) + (k & 7);
        Wib[dst]         = f2bf(vr);
        Wib[10880 + dst] = f2bf(vi);
    }
}

// zero only the seam bands (rows/cols 66,67,132,133,198,199 of each image)
__global__ void k_zero_seams(float* out) {
    int b = blockIdx.x / 12, line = blockIdx.x % 12;
    const int seam[6] = {66, 67, 132, 133, 198, 199};
    int t = threadIdx.x;
    if (line < 6) {
        int y = seam[line];
        float4* dst = (float4*)(out + ((size_t)(b * 256 + y)) * 256 * 64);
        for (int e = t; e < 4096; e += 256) dst[e] = make_float4(0, 0, 0, 0);
    } else {
        int x = seam[line - 6];
        float4* dst = (float4*)out;
        for (int e = t; e < 4096; e += 256) {
            int y = e >> 4, f = e & 15;
            dst[(((size_t)(b * 256 + y)) * 256 + x) * 16 + f] = make_float4(0, 0, 0, 0);
        }
    }
}

// ---------- one-time: kernel spectrum -> fp32 Kt[bin][i][o][c] (scratch) ----
__global__ void k_ktrans(const float* __restrict__ kr, const float* __restrict__ ki,
                         float* __restrict__ Kt) {
    __shared__ float tr[64 * 37];
    __shared__ float ti[64 * 37];
    int k1 = blockIdx.x >> 6, i = blockIdx.x & 63;
    int t = threadIdx.x;
    for (int e = t; e < 64 * KH; e += 256) {
        int o = e / KH, k2 = e % KH;
        size_t src = ((size_t)(o * 64 + i) * 68 + k1) * 68 + k2;
        tr[o * 37 + k2] = kr[src];
        ti[o * 37 + k2] = ki[src];
    }
    __syncthreads();
    for (int e = t; e < KH * 64; e += 256) {
        int k2 = e >> 6, o = e & 63;
        size_t dst = ((size_t)(k1 * KH + k2)) * 8192 + (size_t)i * 128 + o * 2;
        Kt[dst]     = tr[o * 37 + k2];
        Kt[dst + 1] = ti[o * 37 + k2];
    }
}

// ---------- one-time: Kt fp32 -> Ktb bf16 [bin][plane][o][i_swz] ------------
__global__ void k_kconv(const float* __restrict__ Kt, ushort* __restrict__ Ktb) {
    __shared__ float kl[64 * 130];
    int bin = blockIdx.x;
    int t = threadIdx.x;
    const float4* src = (const float4*)(Kt + (size_t)bin * 8192);
    for (int e = t; e < 2048; e += 256) {
        float4 v = src[e];
        int i = e >> 5, oc = (e & 31) << 2;
        kl[i * 130 + oc]     = v.x;
        kl[i * 130 + oc + 1] = v.y;
        kl[i * 130 + oc + 2] = v.z;
        kl[i * 130 + oc + 3] = v.w;
    }
    __syncthreads();
    ushort* dst = Ktb + (size_t)bin * 8192;
    for (int e = t; e < 4096; e += 256) {
        int o = e >> 6, i = e & 63;
        int sw = (o << 6) + (((i >> 3) ^ (o & 7)) << 3) + (i & 7);
        dst[sw]        = f2bf(kl[i * 130 + 2 * o]);
        dst[4096 + sw] = f2bf(kl[i * 130 + 2 * o + 1]);
    }
}

// ---------------- stage 1: row DFT — bf16 MFMA ----------------
// Y[nl][k2][r][i] = sum_c x[b, tr*64+r, tc*64+c, i] * Wf[k2][c]
// Block = (nl, r-quad). Per r: M=48(k2 pad)xN=64(i)xK=64(c) real GEMM, A=Wfb
// planes (twiddle(k,(c+2)) — same table as stage 2), B = x^T [i][c] bf16.
__global__ __launch_bounds__(512) void k_fwd_row(
        const float* __restrict__ x, const ushort* __restrict__ Wfb,
        float* __restrict__ Y, int c0) {
    __shared__ __align__(16) ushort sAr[48 * 64];
    __shared__ __align__(16) ushort sAi[48 * 64];
    __shared__ __align__(16) ushort sB[4 * 64 * 64];   // [rr][i][c] swizzled
    int gid = blockIdx.x;
    int lc = gid >> 8;
    int rem = gid & 255;
    int nl = rem >> 4, rq = rem & 15;
    int n = (c0 + lc) * 16 + nl;
    int b = n >> 4, tr = (n >> 2) & 3, tc = n & 3;
    int t = threadIdx.x;
    // stage A: Wfb rows 0..47 (rows >=35 masked at store), swizzled
    for (int e = t; e < 3072; e += 512) {
        int m = e >> 6, c = e & 63;
        int sw = (m << 6) + (((c >> 3) ^ (m & 7)) << 3) + (c & 7);
        sAr[sw] = Wfb[e];
        sAi[sw] = Wfb[5120 + e];
    }
    // stage B: 4 x-rows fp32 [c][i] -> bf16 [i][c] planes, swizzled
    for (int e = t; e < 4096; e += 512) {
        int rr = e >> 10, f = e & 1023;
        int c = f >> 4, i0 = (f & 15) << 2;
        int y = tr * 64 + rq * 4 + rr;
        const float4* src = (const float4*)(x + ((size_t)(b * 256 + y) * 256
                                                 + tc * 64) * 64 + (c << 6) + i0);
        float4 v = *src;
        float vv[4] = {v.x, v.y, v.z, v.w};
        #pragma unroll
        for (int u = 0; u < 4; ++u) {
            int i = i0 + u;
            sB[(rr << 12) + (i << 6) + (((c >> 3) ^ (i & 7)) << 3) + (c & 7)]
                = f2bf(vv[u]);
        }
    }
    __syncthreads();
    float* Yc = Y + (size_t)lc * CHS;
    int lane = t & 63, w = t >> 6;
    int lm = lane & 15, kg = lane >> 4;
    int ba0 = ((kg ^ (lm & 7)) << 3);
    int ba1 = (((kg + 4) ^ (lm & 7)) << 3);
    for (int tid = w; tid < 48; tid += 8) {
        int rr = tid / 12, rem2 = tid % 12;
        int mt = rem2 >> 2, nt = rem2 & 3;
        int am = mt * 16 + lm, bn = nt * 16 + lm;
        s16x8 a0r = *(const s16x8*)(sAr + (am << 6) + ba0);
        s16x8 a1r = *(const s16x8*)(sAr + (am << 6) + ba1);
        s16x8 a0i = *(const s16x8*)(sAi + (am << 6) + ba0);
        s16x8 a1i = *(const s16x8*)(sAi + (am << 6) + ba1);
        s16x8 b0 = *(const s16x8*)(sB + (rr << 12) + (bn << 6) + ba0);
        s16x8 b1 = *(const s16x8*)(sB + (rr << 12) + (bn << 6) + ba1);
        f32x4 yr = {0.f, 0.f, 0.f, 0.f}, yi = yr;
        yr = __builtin_amdgcn_mfma_f32_16x16x32_bf16(a0r, b0, yr, 0, 0, 0);
        yr = __builtin_amdgcn_mfma_f32_16x16x32_bf16(a1r, b1, yr, 0, 0, 0);
        yi = __builtin_amdgcn_mfma_f32_16x16x32_bf16(a0i, b0, yi, 0, 0, 0);
        yi = __builtin_amdgcn_mfma_f32_16x16x32_bf16(a1i, b1, yi, 0, 0, 0);
        int r = rq * 4 + rr;
        #pragma unroll
        for (int g2 = 0; g2 < 4; ++g2) {
            int k2 = mt * 16 + kg * 4 + g2;
            if (k2 < KH) {
                *(float2*)(Yc + ((size_t)(nl * KH + k2) * 64 + r) * 128
                           + 2 * (nt * 16 + lm))
                    = make_float2(yr[g2], yi[g2]);
            }
        }
    }
}

// ---------------- stage 2: column DFT — bf16 MFMA ----------------
// X[nl][k1][k2][i] = sum_r Wf[k1][r] * Y[nl][k2][r][i]
__global__ __launch_bounds__(512) void k_fwd_col(
        const float* __restrict__ Y, const ushort* __restrict__ Wfb,
        float* __restrict__ X) {
    __shared__ __align__(16) ushort sAr[80 * 64];
    __shared__ __align__(16) ushort sAi[80 * 64];
    __shared__ __align__(16) ushort sBr[64 * 64];
    __shared__ __align__(16) ushort sBi[64 * 64];
    int lc = blockIdx.x / 560;
    int rem = blockIdx.x % 560;
    int nl = rem / KH, k2 = rem % KH;
    const float* Yg = Y + (size_t)lc * CHS + ((size_t)(nl * KH + k2)) * 8192;
    float* Xc = X + (size_t)lc * CHS;
    int t = threadIdx.x;
    for (int e = t; e < 5120; e += 512) {
        int m = e >> 6, r = e & 63;
        int sw = (m << 6) + ((((r >> 3) ^ (m & 7))) << 3) + (r & 7);
        sAr[sw] = Wfb[e];
        sAi[sw] = Wfb[5120 + e];
    }
    for (int e = t; e < 4096; e += 512) {
        int i = e & 63, r = e >> 6;
        float2 v = *(const float2*)(Yg + (r << 7) + 2 * i);
        int sw = (i << 6) + ((((r >> 3) ^ (i & 7))) << 3) + (r & 7);
        sBr[sw] = f2bf(v.x);
        sBi[sw] = f2bf(v.y);
    }
    __syncthreads();
    int lane = t & 63, w = t >> 6;
    int lm = lane & 15, kg = lane >> 4;
    int ba0 = ((kg ^ (lm & 7)) << 3);
    int ba1 = (((kg + 4) ^ (lm & 7)) << 3);
    for (int tid = w; tid < 20; tid += 8) {
        int mt = tid >> 2, nt = tid & 3;
        int am = mt * 16 + lm, bn = nt * 16 + lm;
        s16x8 ar0 = *(const s16x8*)(sAr + (am << 6) + ba0);
        s16x8 ar1 = *(const s16x8*)(sAr + (am << 6) + ba1);
        s16x8 ai0 = *(const s16x8*)(sAi + (am << 6) + ba0);
        s16x8 ai1 = *(const s16x8*)(sAi + (am << 6) + ba1);
        s16x8 br0 = *(const s16x8*)(sBr + (bn << 6) + ba0);
        s16x8 br1 = *(const s16x8*)(sBr + (bn << 6) + ba1);
        s16x8 bi0 = *(const s16x8*)(sBi + (bn << 6) + ba0);
        s16x8 bi1 = *(const s16x8*)(sBi + (bn << 6) + ba1);
        f32x4 rr = {0.f, 0.f, 0.f, 0.f}, ii = rr, ri = rr, ir = rr;
        rr = __builtin_amdgcn_mfma_f32_16x16x32_bf16(ar0, br0, rr, 0, 0, 0);
        rr = __builtin_amdgcn_mfma_f32_16x16x32_bf16(ar1, br1, rr, 0, 0, 0);
        ii = __builtin_amdgcn_mfma_f32_16x16x32_bf16(ai0, bi0, ii, 0, 0, 0);
        ii = __builtin_amdgcn_mfma_f32_16x16x32_bf16(ai1, bi1, ii, 0, 0, 0);
        ri = __builtin_amdgcn_mfma_f32_16x16x32_bf16(ar0, bi0, ri, 0, 0, 0);
        ri = __builtin_amdgcn_mfma_f32_16x16x32_bf16(ar1, bi1, ri, 0, 0, 0);
        ir = __builtin_amdgcn_mfma_f32_16x16x32_bf16(ai0, br0, ir, 0, 0, 0);
        ir = __builtin_amdgcn_mfma_f32_16x16x32_bf16(ai1, br1, ir, 0, 0, 0);
        #pragma unroll
        for (int g2 = 0; g2 < 4; ++g2) {
            int k1 = mt * 16 + kg * 4 + g2;
            if (k1 < 68) {
                float2 res = make_float2(rr[g2] - ii[g2], ri[g2] + ir[g2]);
                *(float2*)(Xc + ((size_t)(nl * 68 + k1) * KH + k2) * 128
                           + 2 * (nt * 16 + lm)) = res;
            }
        }
    }
}

// ---------------- stage 3: channel mix — bf16 MFMA ----------------
// O[nl][k2][k1][o] = sum_i X[nl][k1][k2][i] * K[bin][i][o]
__global__ __launch_bounds__(256) void k_mix(
        const float* __restrict__ X, const ushort* __restrict__ Ktb,
        float* __restrict__ O) {
    __shared__ __align__(16) ushort sAr[16 * 64];
    __shared__ __align__(16) ushort sAi[16 * 64];
    __shared__ __align__(16) ushort sB[2 * 64 * 64];
    int lc = blockIdx.x / 2380;
    int bin = blockIdx.x % 2380;
    int k1 = bin / KH, k2 = bin % KH;
    const float* Xc = X + (size_t)lc * CHS;
    float* Oc = O + (size_t)lc * CHS;
    int t = threadIdx.x;
    for (int e = t; e < 1024; e += 256) {
        int n = e >> 6, i = e & 63;
        float2 v = *(const float2*)(Xc + ((size_t)(n * 68 + k1) * KH + k2) * 128 + 2 * i);
        int sw = (n << 6) + (((i >> 3) ^ (n & 7)) << 3) + (i & 7);
        sAr[sw] = f2bf(v.x);
        sAi[sw] = f2bf(v.y);
    }
    const uint4* ksrc = (const uint4*)(Ktb + (size_t)bin * 8192);
    for (int e = t; e < 1024; e += 256) ((uint4*)sB)[e] = ksrc[e];
    __syncthreads();
    const ushort* sBr = sB;
    const ushort* sBi = sB + 4096;
    int lane = t & 63, w = t >> 6;
    int lm = lane & 15, kg = lane >> 4;
    f32x4 rr = {0.f, 0.f, 0.f, 0.f}, ii = rr, ri = rr, ir = rr;
    #pragma unroll
    for (int st = 0; st < 2; ++st) {
        int blk = kg + st * 4;
        int ao = (lm << 6) + ((blk ^ (lm & 7)) << 3);
        int bo = ((w * 16 + lm) << 6) + ((blk ^ (lm & 7)) << 3);
        s16x8 axr = *(const s16x8*)(sAr + ao);
        s16x8 axi = *(const s16x8*)(sAi + ao);
        s16x8 bxr = *(const s16x8*)(sBr + bo);
        s16x8 bxi = *(const s16x8*)(sBi + bo);
        rr = __builtin_amdgcn_mfma_f32_16x16x32_bf16(axr, bxr, rr, 0, 0, 0);
        ii = __builtin_amdgcn_mfma_f32_16x16x32_bf16(axi, bxi, ii, 0, 0, 0);
        ri = __builtin_amdgcn_mfma_f32_16x16x32_bf16(axr, bxi, ri, 0, 0, 0);
        ir = __builtin_amdgcn_mfma_f32_16x16x32_bf16(axi, bxr, ir, 0, 0, 0);
    }
    #pragma unroll
    for (int g2 = 0; g2 < 4; ++g2) {
        int n = kg * 4 + g2;
        int o = w * 16 + lm;
        *(float2*)(Oc + (((size_t)n * KH + k2) * 68 + k1) * 128 + 2 * o)
            = make_float2(rr[g2] - ii[g2], ri[g2] + ir[g2]);
    }
}

// ---------------- stage 4: inverse column DFT — bf16 MFMA ----------------
// Z[nl][p][k2][o] = sum_k1 Wi[p][k1] * O[nl][k2][k1][o]
__global__ __launch_bounds__(512) void k_inv_col(
        const float* __restrict__ O, const ushort* __restrict__ Wib,
        float* __restrict__ Z) {
    __shared__ __align__(16) ushort sAr[80 * 136];
    __shared__ __align__(16) ushort sAi[80 * 136];
    __shared__ __align__(16) ushort sBr[64 * 136];
    __shared__ __align__(16) ushort sBi[64 * 136];
    int lc = blockIdx.x / 560;
    int rem = blockIdx.x % 560;
    int nl = rem / KH, k2 = rem % KH;
    int t = threadIdx.x;
    const float* Ob = O + (size_t)lc * CHS + ((size_t)nl * KH + k2) * 68 * 128;
    float* Zc = Z + (size_t)lc * CHS;
    const uint4* wsrc = (const uint4*)Wib;
    for (int e = t; e < 1360; e += 512) ((uint4*)sAr)[e] = wsrc[e];
    for (int e = t; e < 1360; e += 512) ((uint4*)sAi)[e] = wsrc[1360 + e];
    uint4 zz = {0, 0, 0, 0};
    for (int e = t; e < 1088; e += 512) { ((uint4*)sBr)[e] = zz; ((uint4*)sBi)[e] = zz; }
    __syncthreads();
    for (int e = t; e < 4352; e += 512) {
        int k1 = e >> 6, o = e & 63;
        float2 v = *(const float2*)(Ob + (size_t)k1 * 128 + 2 * o);
        int sw = o * 136 + (((k1 >> 3) ^ (o & 7)) << 3) + (k1 & 7);
        sBr[sw] = f2bf(v.x);
        sBi[sw] = f2bf(v.y);
    }
    __syncthreads();
    int lane = t & 63, w = t >> 6;
    int lm = lane & 15, kg = lane >> 4;
    for (int tid = w; tid < 20; tid += 8) {
        int mt = tid >> 2, nt = tid & 3;
        int am = mt * 16 + lm, bn = nt * 16 + lm;
        f32x4 rr = {0.f, 0.f, 0.f, 0.f}, ii = rr, ri = rr, ir = rr;
        #pragma unroll
        for (int st = 0; st < 3; ++st) {
            int blk = kg + st * 4;
            int off = ((blk ^ (lm & 7)) << 3);
            s16x8 axr = *(const s16x8*)(sAr + am * 136 + off);
            s16x8 axi = *(const s16x8*)(sAi + am * 136 + off);
            s16x8 bxr = *(const s16x8*)(sBr + bn * 136 + off);
            s16x8 bxi = *(const s16x8*)(sBi + bn * 136 + off);
            rr = __builtin_amdgcn_mfma_f32_16x16x32_bf16(axr, bxr, rr, 0, 0, 0);
            ii = __builtin_amdgcn_mfma_f32_16x16x32_bf16(axi, bxi, ii, 0, 0, 0);
            ri = __builtin_amdgcn_mfma_f32_16x16x32_bf16(axr, bxi, ri, 0, 0, 0);
            ir = __builtin_amdgcn_mfma_f32_16x16x32_bf16(axi, bxr, ir, 0, 0, 0);
        }
        #pragma unroll
        for (int g2 = 0; g2 < 4; ++g2) {
            int p = mt * 16 + kg * 4 + g2;
            if (p < 68) {
                *(float2*)(Zc + (((size_t)(nl * 68 + p)) * KH + k2) * 128
                           + 2 * (nt * 16 + lm))
                    = make_float2(rr[g2] - ii[g2], ri[g2] + ir[g2]);
            }
        }
    }
}

// ---------------- stage 5: inverse row DFT + overlap-add --------------------
__global__ __launch_bounds__(256) void k_fused_inv(
        const float* __restrict__ Z, const float* __restrict__ Wg,
        const float* __restrict__ bias, float* __restrict__ out, int c0) {
    __shared__ float zl[KH * 128];       // 17.9 KB [k2][o][c]
    __shared__ float wg[68 * 70];        // 19.0 KB [q][k2c]
    int lc = blockIdx.x / 1088;
    int rem = blockIdx.x % 1088;
    int nl = rem / 68, p = rem % 68;
    int b = c0 + lc;
    int tr = nl >> 2, tc = nl & 3;
    int y = 66 * tr + p;
    if (y >= 256) return;
    int t = threadIdx.x;
    const float4* zs4 = (const float4*)(Z + (size_t)lc * CHS
                                        + ((size_t)(nl * 68 + p)) * 4480);
    float4* zl4 = (float4*)zl;
    for (int e = t; e < 1120; e += 256) zl4[e] = zs4[e];
    for (int e = t; e < 4760; e += 256) wg[e] = Wg[e];
    __syncthreads();

    int o = t & 63, qg = t >> 6;
    float bv = bias[o];
    const float* zr = zl + 2 * o;
    const float* wbase = wg + (qg * 17) * 70;

    float acc[17];
    #pragma unroll
    for (int j = 0; j < 17; ++j) acc[j] = 0.f;

    for (int k2 = 0; k2 < KH; ++k2) {
        float2 zv = *(const float2*)(zr + (k2 << 7));
        #pragma unroll
        for (int j = 0; j < 17; ++j) {
            float2 wv = *(const float2*)(wbase + j * 70 + 2 * k2);  // broadcast
            acc[j] += zv.x * wv.x - zv.y * wv.y;
        }
    }

    bool rowu = !((p <= 1 && tr > 0) || (p >= 66 && tr < 3));
    float* orow = out + ((size_t)(b * 256 + y)) * 256 * 64 + o;
    #pragma unroll
    for (int j = 0; j < 17; ++j) {
        int q = qg * 17 + j;
        int x = 66 * tc + q;
        if (x >= 256) continue;
        bool colu = !((q <= 1 && tc > 0) || (q >= 66 && tc < 3));
        float v = acc[j] + bv;
        if (rowu && colu) orow[(size_t)x * 64] = v;
        else              atomicAdd(orow + (size_t)x * 64, v);
    }
}

extern "C" void kernel_launch(void* const* d_in, const int* in_sizes, int n_in,
                              void* d_out, int out_size, void* d_ws, size_t ws_size,
                              hipStream_t stream) {
    const float* x    = (const float*)d_in[0];
    const float* kr   = (const float*)d_in[1];
    const float* ki   = (const float*)d_in[2];
    const float* bias = (const float*)d_in[3];
    float* out = (float*)d_out;
    float* ws  = (float*)d_ws;

    int CH = 8;
    while (CH > 4 && (WS_HEAD + KTB_FLOATS + 2ull * CH * CHS) * 4ull > ws_size)
        CH >>= 1;

    float*  Wf   = ws;                         // 9216 floats
    float*  Wg   = ws + 9216;                  // 4760 floats
    ushort* Wfb  = (ushort*)(ws + 13976);      // 10240 ushorts
    ushort* Wib  = (ushort*)(ws + 19096);      // 21760 ushorts
    ushort* Ktb  = (ushort*)(ws + WS_HEAD);    // 2380*8192 ushorts
    float*  bufA = ws + WS_HEAD + KTB_FLOATS;  // Y then O
    float*  bufB = bufA + (size_t)CH * CHS;    // X then Z (also Kt scratch)

    k_twiddle<<<1, 256, 0, stream>>>(ws);
    k_ktrans<<<68 * 64, 256, 0, stream>>>(kr, ki, bufB);   // fp32 Kt scratch
    k_kconv<<<2380, 256, 0, stream>>>(bufB, Ktb);          // -> bf16 pre-swizzled
    k_zero_seams<<<96, 256, 0, stream>>>(out);

    for (int s = 0; s < 8; s += CH) {
        k_fwd_row<<<CH * 256, 512, 0, stream>>>(x, Wfb, bufA, s);
        k_fwd_col<<<CH * 560, 512, 0, stream>>>(bufA, Wfb, bufB);
        k_mix<<<CH * 2380, 256, 0, stream>>>(bufB, Ktb, bufA);
        k_inv_col<<<CH * 560, 512, 0, stream>>>(bufA, Wib, bufB);
        k_fused_inv<<<CH * 1088, 256, 0, stream>>>(bufB, Wg, bias, out, s);
    }
}

// Round 18
// 600.079 us; speedup vs baseline: 2.3481x; 1.1173x over previous
//
#include <hip/hip_runtime.h>
#include <hip/hip_bf16.h>

// FFT-tiled conv: B=8, IMG=256, CIN=COUT=64, TILE=64, FFT=68, PAD=2.
// Frequency-domain per-tile conv via DFT-as-matmul, Hermitian half-spectrum
// (k2 in [0,35)), direct overlap-add (plain stores interior, atomics on seams,
// seam bands pre-zeroed). ALL five stages run on bf16 MFMA.
//
// Layouts (per 16-tile chunk slot of CHS floats):
//   Y  [nl][k2][r][i][c]      in bufA     ((nl*35+k2)*64+r)*128
//   X  [nl][k1][k2][i][c]     in bufB     ((nl*68+k1)*35+k2)*128
//   Ktb[bin][2][o][i] bf16 pre-swizzled   39 MB, one-time (bin = k1*35+k2)
//   O  [nl][k2][k1][o][c]     in bufA     ((nl*35+k2)*68+k1)*128
//   Z  [nl][p][k2][o][c]      in bufB     ((nl*68+p)*35+k2)*128
//
// Twiddle tables:
//   Wf  [72][64] cplx fp32 (legacy, unused)        (9216 floats)
//   Wg  [68][35] cplx fp32 (legacy, unused)         (4760 floats)
//   Wfb [2][80][64] bf16 rows>=68 zero              (5120 floats)
//   Wib [2][80][136] bf16 pre-swizzled, zero-pad    (10880 floats)
//   Wgb [80][136] bf16 pre-swizzled, K=[Wgr|-Wgi]   (5440 floats)

#define KH   35
#define CHS  4874240ull                       // floats per chunk slot
#define KTB_FLOATS 9748480ull                 // 2380*8192 ushorts / 2
#define WS_HEAD 35416ull                      // 9216+4760+5120+10880+5440

typedef float f32x4 __attribute__((ext_vector_type(4)));
typedef short s16x8 __attribute__((ext_vector_type(8)));

__device__ __forceinline__ ushort f2bf(float f) {
    __hip_bfloat16 h = __float2bfloat16(f);
    return *reinterpret_cast<ushort*>(&h);
}

__global__ void k_twiddle(float* ws) {
    const float TWO_PI = 6.28318530717958647692f;
    int t = threadIdx.x;
    float* Wf = ws;                       // 72 x 64 cplx fp32 (legacy)
    for (int e = t; e < 72 * 64; e += 256) {
        int k = e >> 6, m = e & 63;
        float vr = 0.f, vi = 0.f;
        if (k < 68) {
            int ph = (k * (m + 2)) % 68;
            float a = TWO_PI * (float)ph / 68.0f;
            vr = cosf(a); vi = -sinf(a);
        }
        Wf[2 * e] = vr; Wf[2 * e + 1] = vi;
    }
    float* Wg = ws + 9216;                // 68 x 35 cplx fp32 (legacy)
    for (int e = t; e < 68 * KH; e += 256) {
        int q = e / KH, k2 = e % KH;
        int ph = (q * k2) % 68;
        float a = TWO_PI * (float)ph / 68.0f;
        float alpha = (k2 == 0 || k2 == 34) ? 1.0f : 2.0f;
        Wg[2 * e]     = alpha * cosf(a) / 68.0f;
        Wg[2 * e + 1] = alpha * sinf(a) / 68.0f;
    }
    ushort* Wfb = (ushort*)(ws + 13976);  // [2][80][64] bf16
    for (int e = t; e < 80 * 64; e += 256) {
        int k = e >> 6, r = e & 63;
        float vr = 0.f, vi = 0.f;
        if (k < 68) {
            int ph = (k * (r + 2)) % 68;
            float a = TWO_PI * (float)ph / 68.0f;
            vr = cosf(a); vi = -sinf(a);
        }
        Wfb[e]        = f2bf(vr);
        Wfb[5120 + e] = f2bf(vi);
    }
    ushort* Wib = (ushort*)(ws + 19096);  // [2][80][136] bf16 pre-swizzled
    for (int e = t; e < 80 * 96; e += 256) {
        int p = e / 96, k = e % 96;
        float vr = 0.f, vi = 0.f;
        if (p < 68 && k < 68) {
            int ph = (p * k) % 68;
            float a = TWO_PI * (float)ph / 68.0f;
            vr = cosf(a) / 68.0f; vi = sinf(a) / 68.0f;
        }
        int dst = p * 136 + (((k >> 3) ^ (p & 7)) << 3) + (k & 7);
        Wib[dst]         = f2bf(vr);
        Wib[10880 + dst] = f2bf(vi);
    }
    // Wgb: A-table for stage 5. K axis = [Wgr(35) | -Wgi(35) | 0-pad to 96].
    ushort* Wgb = (ushort*)(ws + 29976);  // [80][136] bf16 pre-swizzled
    for (int e = t; e < 80 * 96; e += 256) {
        int q = e / 96, k = e % 96;
        float v = 0.f;
        if (q < 68 && k < 70) {
            int k2 = (k < KH) ? k : (k - KH);
            int ph = (q * k2) % 68;
            float a = TWO_PI * (float)ph / 68.0f;
            float alpha = (k2 == 0 || k2 == 34) ? 1.0f : 2.0f;
            v = (k < KH) ? (alpha * cosf(a) / 68.0f)
                         : (-alpha * sinf(a) / 68.0f);
        }
        int dst = q * 136 + (((k >> 3) ^ (q & 7)) << 3) + (k & 7);
        Wgb[dst] = f2bf(v);
    }
}

// zero only the seam bands (rows/cols 66,67,132,133,198,199 of each image)
__global__ void k_zero_seams(float* out) {
    int b = blockIdx.x / 12, line = blockIdx.x % 12;
    const int seam[6] = {66, 67, 132, 133, 198, 199};
    int t = threadIdx.x;
    if (line < 6) {
        int y = seam[line];
        float4* dst = (float4*)(out + ((size_t)(b * 256 + y)) * 256 * 64);
        for (int e = t; e < 4096; e += 256) dst[e] = make_float4(0, 0, 0, 0);
    } else {
        int x = seam[line - 6];
        float4* dst = (float4*)out;
        for (int e = t; e < 4096; e += 256) {
            int y = e >> 4, f = e & 15;
            dst[(((size_t)(b * 256 + y)) * 256 + x) * 16 + f] = make_float4(0, 0, 0, 0);
        }
    }
}

// ---------- one-time: kernel spectrum -> fp32 Kt[bin][i][o][c] (scratch) ----
__global__ void k_ktrans(const float* __restrict__ kr, const float* __restrict__ ki,
                         float* __restrict__ Kt) {
    __shared__ float tr[64 * 37];
    __shared__ float ti[64 * 37];
    int k1 = blockIdx.x >> 6, i = blockIdx.x & 63;
    int t = threadIdx.x;
    for (int e = t; e < 64 * KH; e += 256) {
        int o = e / KH, k2 = e % KH;
        size_t src = ((size_t)(o * 64 + i) * 68 + k1) * 68 + k2;
        tr[o * 37 + k2] = kr[src];
        ti[o * 37 + k2] = ki[src];
    }
    __syncthreads();
    for (int e = t; e < KH * 64; e += 256) {
        int k2 = e >> 6, o = e & 63;
        size_t dst = ((size_t)(k1 * KH + k2)) * 8192 + (size_t)i * 128 + o * 2;
        Kt[dst]     = tr[o * 37 + k2];
        Kt[dst + 1] = ti[o * 37 + k2];
    }
}

// ---------- one-time: Kt fp32 -> Ktb bf16 [bin][plane][o][i_swz] ------------
__global__ void k_kconv(const float* __restrict__ Kt, ushort* __restrict__ Ktb) {
    __shared__ float kl[64 * 130];
    int bin = blockIdx.x;
    int t = threadIdx.x;
    const float4* src = (const float4*)(Kt + (size_t)bin * 8192);
    for (int e = t; e < 2048; e += 256) {
        float4 v = src[e];
        int i = e >> 5, oc = (e & 31) << 2;
        kl[i * 130 + oc]     = v.x;
        kl[i * 130 + oc + 1] = v.y;
        kl[i * 130 + oc + 2] = v.z;
        kl[i * 130 + oc + 3] = v.w;
    }
    __syncthreads();
    ushort* dst = Ktb + (size_t)bin * 8192;
    for (int e = t; e < 4096; e += 256) {
        int o = e >> 6, i = e & 63;
        int sw = (o << 6) + (((i >> 3) ^ (o & 7)) << 3) + (i & 7);
        dst[sw]        = f2bf(kl[i * 130 + 2 * o]);
        dst[4096 + sw] = f2bf(kl[i * 130 + 2 * o + 1]);
    }
}

// ---------------- stage 1: row DFT — bf16 MFMA ----------------
// Y[nl][k2][r][i] = sum_c x[b, tr*64+r, tc*64+c, i] * Wf[k2][c]
__global__ __launch_bounds__(512) void k_fwd_row(
        const float* __restrict__ x, const ushort* __restrict__ Wfb,
        float* __restrict__ Y, int c0) {
    __shared__ __align__(16) ushort sAr[48 * 64];
    __shared__ __align__(16) ushort sAi[48 * 64];
    __shared__ __align__(16) ushort sB[4 * 64 * 64];   // [rr][i][c] swizzled
    int gid = blockIdx.x;
    int lc = gid >> 8;
    int rem = gid & 255;
    int nl = rem >> 4, rq = rem & 15;
    int n = (c0 + lc) * 16 + nl;
    int b = n >> 4, tr = (n >> 2) & 3, tc = n & 3;
    int t = threadIdx.x;
    for (int e = t; e < 3072; e += 512) {
        int m = e >> 6, c = e & 63;
        int sw = (m << 6) + (((c >> 3) ^ (m & 7)) << 3) + (c & 7);
        sAr[sw] = Wfb[e];
        sAi[sw] = Wfb[5120 + e];
    }
    for (int e = t; e < 4096; e += 512) {
        int rr = e >> 10, f = e & 1023;
        int c = f >> 4, i0 = (f & 15) << 2;
        int y = tr * 64 + rq * 4 + rr;
        const float4* src = (const float4*)(x + ((size_t)(b * 256 + y) * 256
                                                 + tc * 64) * 64 + (c << 6) + i0);
        float4 v = *src;
        float vv[4] = {v.x, v.y, v.z, v.w};
        #pragma unroll
        for (int u = 0; u < 4; ++u) {
            int i = i0 + u;
            sB[(rr << 12) + (i << 6) + (((c >> 3) ^ (i & 7)) << 3) + (c & 7)]
                = f2bf(vv[u]);
        }
    }
    __syncthreads();
    float* Yc = Y + (size_t)lc * CHS;
    int lane = t & 63, w = t >> 6;
    int lm = lane & 15, kg = lane >> 4;
    int ba0 = ((kg ^ (lm & 7)) << 3);
    int ba1 = (((kg + 4) ^ (lm & 7)) << 3);
    for (int tid = w; tid < 48; tid += 8) {
        int rr = tid / 12, rem2 = tid % 12;
        int mt = rem2 >> 2, nt = rem2 & 3;
        int am = mt * 16 + lm, bn = nt * 16 + lm;
        s16x8 a0r = *(const s16x8*)(sAr + (am << 6) + ba0);
        s16x8 a1r = *(const s16x8*)(sAr + (am << 6) + ba1);
        s16x8 a0i = *(const s16x8*)(sAi + (am << 6) + ba0);
        s16x8 a1i = *(const s16x8*)(sAi + (am << 6) + ba1);
        s16x8 b0 = *(const s16x8*)(sB + (rr << 12) + (bn << 6) + ba0);
        s16x8 b1 = *(const s16x8*)(sB + (rr << 12) + (bn << 6) + ba1);
        f32x4 yr = {0.f, 0.f, 0.f, 0.f}, yi = yr;
        yr = __builtin_amdgcn_mfma_f32_16x16x32_bf16(a0r, b0, yr, 0, 0, 0);
        yr = __builtin_amdgcn_mfma_f32_16x16x32_bf16(a1r, b1, yr, 0, 0, 0);
        yi = __builtin_amdgcn_mfma_f32_16x16x32_bf16(a0i, b0, yi, 0, 0, 0);
        yi = __builtin_amdgcn_mfma_f32_16x16x32_bf16(a1i, b1, yi, 0, 0, 0);
        int r = rq * 4 + rr;
        #pragma unroll
        for (int g2 = 0; g2 < 4; ++g2) {
            int k2 = mt * 16 + kg * 4 + g2;
            if (k2 < KH) {
                *(float2*)(Yc + ((size_t)(nl * KH + k2) * 64 + r) * 128
                           + 2 * (nt * 16 + lm))
                    = make_float2(yr[g2], yi[g2]);
            }
        }
    }
}

// ---------------- stage 2: column DFT — bf16 MFMA ----------------
// X[nl][k1][k2][i] = sum_r Wf[k1][r] * Y[nl][k2][r][i]
__global__ __launch_bounds__(512) void k_fwd_col(
        const float* __restrict__ Y, const ushort* __restrict__ Wfb,
        float* __restrict__ X) {
    __shared__ __align__(16) ushort sAr[80 * 64];
    __shared__ __align__(16) ushort sAi[80 * 64];
    __shared__ __align__(16) ushort sBr[64 * 64];
    __shared__ __align__(16) ushort sBi[64 * 64];
    int lc = blockIdx.x / 560;
    int rem = blockIdx.x % 560;
    int nl = rem / KH, k2 = rem % KH;
    const float* Yg = Y + (size_t)lc * CHS + ((size_t)(nl * KH + k2)) * 8192;
    float* Xc = X + (size_t)lc * CHS;
    int t = threadIdx.x;
    for (int e = t; e < 5120; e += 512) {
        int m = e >> 6, r = e & 63;
        int sw = (m << 6) + ((((r >> 3) ^ (m & 7))) << 3) + (r & 7);
        sAr[sw] = Wfb[e];
        sAi[sw] = Wfb[5120 + e];
    }
    for (int e = t; e < 4096; e += 512) {
        int i = e & 63, r = e >> 6;
        float2 v = *(const float2*)(Yg + (r << 7) + 2 * i);
        int sw = (i << 6) + ((((r >> 3) ^ (i & 7))) << 3) + (r & 7);
        sBr[sw] = f2bf(v.x);
        sBi[sw] = f2bf(v.y);
    }
    __syncthreads();
    int lane = t & 63, w = t >> 6;
    int lm = lane & 15, kg = lane >> 4;
    int ba0 = ((kg ^ (lm & 7)) << 3);
    int ba1 = (((kg + 4) ^ (lm & 7)) << 3);
    for (int tid = w; tid < 20; tid += 8) {
        int mt = tid >> 2, nt = tid & 3;
        int am = mt * 16 + lm, bn = nt * 16 + lm;
        s16x8 ar0 = *(const s16x8*)(sAr + (am << 6) + ba0);
        s16x8 ar1 = *(const s16x8*)(sAr + (am << 6) + ba1);
        s16x8 ai0 = *(const s16x8*)(sAi + (am << 6) + ba0);
        s16x8 ai1 = *(const s16x8*)(sAi + (am << 6) + ba1);
        s16x8 br0 = *(const s16x8*)(sBr + (bn << 6) + ba0);
        s16x8 br1 = *(const s16x8*)(sBr + (bn << 6) + ba1);
        s16x8 bi0 = *(const s16x8*)(sBi + (bn << 6) + ba0);
        s16x8 bi1 = *(const s16x8*)(sBi + (bn << 6) + ba1);
        f32x4 rr = {0.f, 0.f, 0.f, 0.f}, ii = rr, ri = rr, ir = rr;
        rr = __builtin_amdgcn_mfma_f32_16x16x32_bf16(ar0, br0, rr, 0, 0, 0);
        rr = __builtin_amdgcn_mfma_f32_16x16x32_bf16(ar1, br1, rr, 0, 0, 0);
        ii = __builtin_amdgcn_mfma_f32_16x16x32_bf16(ai0, bi0, ii, 0, 0, 0);
        ii = __builtin_amdgcn_mfma_f32_16x16x32_bf16(ai1, bi1, ii, 0, 0, 0);
        ri = __builtin_amdgcn_mfma_f32_16x16x32_bf16(ar0, bi0, ri, 0, 0, 0);
        ri = __builtin_amdgcn_mfma_f32_16x16x32_bf16(ar1, bi1, ri, 0, 0, 0);
        ir = __builtin_amdgcn_mfma_f32_16x16x32_bf16(ai0, br0, ir, 0, 0, 0);
        ir = __builtin_amdgcn_mfma_f32_16x16x32_bf16(ai1, br1, ir, 0, 0, 0);
        #pragma unroll
        for (int g2 = 0; g2 < 4; ++g2) {
            int k1 = mt * 16 + kg * 4 + g2;
            if (k1 < 68) {
                float2 res = make_float2(rr[g2] - ii[g2], ri[g2] + ir[g2]);
                *(float2*)(Xc + ((size_t)(nl * 68 + k1) * KH + k2) * 128
                           + 2 * (nt * 16 + lm)) = res;
            }
        }
    }
}

// ---------------- stage 3: channel mix — bf16 MFMA ----------------
// O[nl][k2][k1][o] = sum_i X[nl][k1][k2][i] * K[bin][i][o]
__global__ __launch_bounds__(256) void k_mix(
        const float* __restrict__ X, const ushort* __restrict__ Ktb,
        float* __restrict__ O) {
    __shared__ __align__(16) ushort sAr[16 * 64];
    __shared__ __align__(16) ushort sAi[16 * 64];
    __shared__ __align__(16) ushort sB[2 * 64 * 64];
    int lc = blockIdx.x / 2380;
    int bin = blockIdx.x % 2380;
    int k1 = bin / KH, k2 = bin % KH;
    const float* Xc = X + (size_t)lc * CHS;
    float* Oc = O + (size_t)lc * CHS;
    int t = threadIdx.x;
    for (int e = t; e < 1024; e += 256) {
        int n = e >> 6, i = e & 63;
        float2 v = *(const float2*)(Xc + ((size_t)(n * 68 + k1) * KH + k2) * 128 + 2 * i);
        int sw = (n << 6) + (((i >> 3) ^ (n & 7)) << 3) + (i & 7);
        sAr[sw] = f2bf(v.x);
        sAi[sw] = f2bf(v.y);
    }
    const uint4* ksrc = (const uint4*)(Ktb + (size_t)bin * 8192);
    for (int e = t; e < 1024; e += 256) ((uint4*)sB)[e] = ksrc[e];
    __syncthreads();
    const ushort* sBr = sB;
    const ushort* sBi = sB + 4096;
    int lane = t & 63, w = t >> 6;
    int lm = lane & 15, kg = lane >> 4;
    f32x4 rr = {0.f, 0.f, 0.f, 0.f}, ii = rr, ri = rr, ir = rr;
    #pragma unroll
    for (int st = 0; st < 2; ++st) {
        int blk = kg + st * 4;
        int ao = (lm << 6) + ((blk ^ (lm & 7)) << 3);
        int bo = ((w * 16 + lm) << 6) + ((blk ^ (lm & 7)) << 3);
        s16x8 axr = *(const s16x8*)(sAr + ao);
        s16x8 axi = *(const s16x8*)(sAi + ao);
        s16x8 bxr = *(const s16x8*)(sBr + bo);
        s16x8 bxi = *(const s16x8*)(sBi + bo);
        rr = __builtin_amdgcn_mfma_f32_16x16x32_bf16(axr, bxr, rr, 0, 0, 0);
        ii = __builtin_amdgcn_mfma_f32_16x16x32_bf16(axi, bxi, ii, 0, 0, 0);
        ri = __builtin_amdgcn_mfma_f32_16x16x32_bf16(axr, bxi, ri, 0, 0, 0);
        ir = __builtin_amdgcn_mfma_f32_16x16x32_bf16(axi, bxr, ir, 0, 0, 0);
    }
    #pragma unroll
    for (int g2 = 0; g2 < 4; ++g2) {
        int n = kg * 4 + g2;
        int o = w * 16 + lm;
        *(float2*)(Oc + (((size_t)n * KH + k2) * 68 + k1) * 128 + 2 * o)
            = make_float2(rr[g2] - ii[g2], ri[g2] + ir[g2]);
    }
}

// ---------------- stage 4: inverse column DFT — bf16 MFMA ----------------
// Z[nl][p][k2][o] = sum_k1 Wi[p][k1] * O[nl][k2][k1][o]
__global__ __launch_bounds__(512) void k_inv_col(
        const float* __restrict__ O, const ushort* __restrict__ Wib,
        float* __restrict__ Z) {
    __shared__ __align__(16) ushort sAr[80 * 136];
    __shared__ __align__(16) ushort sAi[80 * 136];
    __shared__ __align__(16) ushort sBr[64 * 136];
    __shared__ __align__(16) ushort sBi[64 * 136];
    int lc = blockIdx.x / 560;
    int rem = blockIdx.x % 560;
    int nl = rem / KH, k2 = rem % KH;
    int t = threadIdx.x;
    const float* Ob = O + (size_t)lc * CHS + ((size_t)nl * KH + k2) * 68 * 128;
    float* Zc = Z + (size_t)lc * CHS;
    const uint4* wsrc = (const uint4*)Wib;
    for (int e = t; e < 1360; e += 512) ((uint4*)sAr)[e] = wsrc[e];
    for (int e = t; e < 1360; e += 512) ((uint4*)sAi)[e] = wsrc[1360 + e];
    uint4 zz = {0, 0, 0, 0};
    for (int e = t; e < 1088; e += 512) { ((uint4*)sBr)[e] = zz; ((uint4*)sBi)[e] = zz; }
    __syncthreads();
    for (int e = t; e < 4352; e += 512) {
        int k1 = e >> 6, o = e & 63;
        float2 v = *(const float2*)(Ob + (size_t)k1 * 128 + 2 * o);
        int sw = o * 136 + (((k1 >> 3) ^ (o & 7)) << 3) + (k1 & 7);
        sBr[sw] = f2bf(v.x);
        sBi[sw] = f2bf(v.y);
    }
    __syncthreads();
    int lane = t & 63, w = t >> 6;
    int lm = lane & 15, kg = lane >> 4;
    for (int tid = w; tid < 20; tid += 8) {
        int mt = tid >> 2, nt = tid & 3;
        int am = mt * 16 + lm, bn = nt * 16 + lm;
        f32x4 rr = {0.f, 0.f, 0.f, 0.f}, ii = rr, ri = rr, ir = rr;
        #pragma unroll
        for (int st = 0; st < 3; ++st) {
            int blk = kg + st * 4;
            int off = ((blk ^ (lm & 7)) << 3);
            s16x8 axr = *(const s16x8*)(sAr + am * 136 + off);
            s16x8 axi = *(const s16x8*)(sAi + am * 136 + off);
            s16x8 bxr = *(const s16x8*)(sBr + bn * 136 + off);
            s16x8 bxi = *(const s16x8*)(sBi + bn * 136 + off);
            rr = __builtin_amdgcn_mfma_f32_16x16x32_bf16(axr, bxr, rr, 0, 0, 0);
            ii = __builtin_amdgcn_mfma_f32_16x16x32_bf16(axi, bxi, ii, 0, 0, 0);
            ri = __builtin_amdgcn_mfma_f32_16x16x32_bf16(axr, bxi, ri, 0, 0, 0);
            ir = __builtin_amdgcn_mfma_f32_16x16x32_bf16(axi, bxr, ir, 0, 0, 0);
        }
        #pragma unroll
        for (int g2 = 0; g2 < 4; ++g2) {
            int p = mt * 16 + kg * 4 + g2;
            if (p < 68) {
                *(float2*)(Zc + (((size_t)(nl * 68 + p)) * KH + k2) * 128
                           + 2 * (nt * 16 + lm))
                    = make_float2(rr[g2] - ii[g2], ri[g2] + ir[g2]);
            }
        }
    }
}

// ---------------- stage 5: inverse row DFT + overlap-add — bf16 MFMA --------
// out[b, 66tr+p, 66tc+q, o] (+)= bias[o] + S[q][o],
// S = A*B: A = Wgb[q][k] = [Wgr | -Wgi] (K=70 pad 96), B = [Zr; Zi][k][o].
__global__ __launch_bounds__(512) void k_fused_inv(
        const float* __restrict__ Z, const ushort* __restrict__ Wgb,
        const float* __restrict__ bias, float* __restrict__ out, int c0) {
    __shared__ __align__(16) ushort sWg[80 * 136];   // 21.3 KB
    __shared__ __align__(16) ushort sBq[64 * 136];   // 17 KB
    int lc = blockIdx.x / 1088;
    int rem = blockIdx.x % 1088;
    int nl = rem / 68, p = rem % 68;
    int b = c0 + lc;
    int tr = nl >> 2, tc = nl & 3;
    int y = 66 * tr + p;
    if (y >= 256) return;
    int t = threadIdx.x;
    const float* Zb = Z + (size_t)lc * CHS + ((size_t)(nl * 68 + p)) * 4480;
    const uint4* wsrc = (const uint4*)Wgb;
    for (int e = t; e < 1360; e += 512) ((uint4*)sWg)[e] = wsrc[e];
    uint4 zz = {0, 0, 0, 0};
    for (int e = t; e < 1088; e += 512) ((uint4*)sBq)[e] = zz;
    __syncthreads();
    // B: k<35 -> Zr[k][o]; 35<=k<70 -> Zi[k-35][o]; one float2 feeds both.
    for (int e = t; e < KH * 64; e += 512) {
        int k2 = e >> 6, o = e & 63;
        float2 v = *(const float2*)(Zb + (k2 << 7) + 2 * o);
        int kb = k2 + KH;
        sBq[o * 136 + (((k2 >> 3) ^ (o & 7)) << 3) + (k2 & 7)] = f2bf(v.x);
        sBq[o * 136 + (((kb >> 3) ^ (o & 7)) << 3) + (kb & 7)] = f2bf(v.y);
    }
    __syncthreads();
    int lane = t & 63, w = t >> 6;
    int lm = lane & 15, kg = lane >> 4;
    bool rowu = !((p <= 1 && tr > 0) || (p >= 66 && tr < 3));
    float* orow = out + ((size_t)(b * 256 + y)) * 256 * 64;
    for (int tid = w; tid < 20; tid += 8) {
        int mt = tid >> 2, nt = tid & 3;
        int am = mt * 16 + lm, bn = nt * 16 + lm;
        f32x4 acc = {0.f, 0.f, 0.f, 0.f};
        #pragma unroll
        for (int st = 0; st < 3; ++st) {
            int blk = kg + st * 4;
            int off = ((blk ^ (lm & 7)) << 3);
            s16x8 av = *(const s16x8*)(sWg + am * 136 + off);
            s16x8 bv = *(const s16x8*)(sBq + bn * 136 + off);
            acc = __builtin_amdgcn_mfma_f32_16x16x32_bf16(av, bv, acc, 0, 0, 0);
        }
        int o = nt * 16 + lm;
        float bv = bias[o];
        #pragma unroll
        for (int g2 = 0; g2 < 4; ++g2) {
            int q = mt * 16 + kg * 4 + g2;
            if (q >= 68) continue;
            int xx = 66 * tc + q;
            if (xx >= 256) continue;
            bool colu = !((q <= 1 && tc > 0) || (q >= 66 && tc < 3));
            float v = acc[g2] + bv;
            float* addr = orow + (size_t)xx * 64 + o;
            if (rowu && colu) *addr = v;
            else              atomicAdd(addr, v);
        }
    }
}

extern "C" void kernel_launch(void* const* d_in, const int* in_sizes, int n_in,
                              void* d_out, int out_size, void* d_ws, size_t ws_size,
                              hipStream_t stream) {
    const float* x    = (const float*)d_in[0];
    const float* kr   = (const float*)d_in[1];
    const float* ki   = (const float*)d_in[2];
    const float* bias = (const float*)d_in[3];
    float* out = (float*)d_out;
    float* ws  = (float*)d_ws;

    int CH = 8;
    while (CH > 4 && (WS_HEAD + KTB_FLOATS + 2ull * CH * CHS) * 4ull > ws_size)
        CH >>= 1;

    ushort* Wfb  = (ushort*)(ws + 13976);      // 10240 ushorts
    ushort* Wib  = (ushort*)(ws + 19096);      // 21760 ushorts
    ushort* Wgb  = (ushort*)(ws + 29976);      // 10880 ushorts
    ushort* Ktb  = (ushort*)(ws + WS_HEAD);    // 2380*8192 ushorts
    float*  bufA = ws + WS_HEAD + KTB_FLOATS;  // Y then O
    float*  bufB = bufA + (size_t)CH * CHS;    // X then Z (also Kt scratch)

    k_twiddle<<<1, 256, 0, stream>>>(ws);
    k_ktrans<<<68 * 64, 256, 0, stream>>>(kr, ki, bufB);   // fp32 Kt scratch
    k_kconv<<<2380, 256, 0, stream>>>(bufB, Ktb);          // -> bf16 pre-swizzled
    k_zero_seams<<<96, 256, 0, stream>>>(out);

    for (int s = 0; s < 8; s += CH) {
        k_fwd_row<<<CH * 256, 512, 0, stream>>>(x, Wfb, bufA, s);
        k_fwd_col<<<CH * 560, 512, 0, stream>>>(bufA, Wfb, bufB);
        k_mix<<<CH * 2380, 256, 0, stream>>>(bufB, Ktb, bufA);
        k_inv_col<<<CH * 560, 512, 0, stream>>>(bufA, Wib, bufB);
        k_fused_inv<<<CH * 1088, 512, 0, stream>>>(bufB, Wgb, bias, out, s);
    }
}

// Round 19
// 578.620 us; speedup vs baseline: 2.4351x; 1.0371x over previous
//
#include <hip/hip_runtime.h>
#include <hip/hip_bf16.h>

// FFT-tiled conv: B=8, IMG=256, CIN=COUT=64, TILE=64, FFT=68, PAD=2.
// Frequency-domain per-tile conv via DFT-as-matmul, Hermitian half-spectrum
// (k2 in [0,35)), direct overlap-add (plain stores interior, atomics on seams,
// seam bands pre-zeroed). ALL five stages run on bf16 MFMA.
// All MFMA LDS tiles use 128-ushort rows (64 dw = 0 mod 32 banks) + XOR-block
// swizzle -> uniform bank distribution on fragment reads.
//
// Layouts (per 16-tile chunk slot of CHS floats):
//   Y  [nl][k2][r][i][c]      in bufA     ((nl*35+k2)*64+r)*128
//   X  [nl][k1][k2][i][c]     in bufB     ((nl*68+k1)*35+k2)*128
//   Ktb[bin][2][o][i] bf16 pre-swizzled   39 MB, one-time (bin = k1*35+k2)
//   O  [nl][k2][k1][o][c]     in bufA     ((nl*35+k2)*68+k1)*128
//   Z  [nl][p][k2][o][c]      in bufB     ((nl*68+p)*35+k2)*128
//
// Twiddle tables:
//   Wf  [72][64] cplx fp32 (legacy, unused)        (9216 floats)
//   Wg  [68][35] cplx fp32 (legacy, unused)         (4760 floats)
//   Wfb [2][80][64] bf16 rows>=68 zero              (5120 floats)
//   Wib [2][80][128] bf16 pre-swizzled, zero-pad    (10240 floats)
//   Wgb [80][128] bf16 pre-swizzled, K=[Wgr|-Wgi]   (5120 floats)

#define KH   35
#define CHS  4874240ull                       // floats per chunk slot
#define KTB_FLOATS 9748480ull                 // 2380*8192 ushorts / 2
#define WS_HEAD 34456ull                      // 9216+4760+5120+10240+5120

typedef float f32x4 __attribute__((ext_vector_type(4)));
typedef short s16x8 __attribute__((ext_vector_type(8)));

__device__ __forceinline__ ushort f2bf(float f) {
    __hip_bfloat16 h = __float2bfloat16(f);
    return *reinterpret_cast<ushort*>(&h);
}

__global__ void k_twiddle(float* ws) {
    const float TWO_PI = 6.28318530717958647692f;
    int t = threadIdx.x;
    float* Wf = ws;                       // legacy
    for (int e = t; e < 72 * 64; e += 256) {
        int k = e >> 6, m = e & 63;
        float vr = 0.f, vi = 0.f;
        if (k < 68) {
            int ph = (k * (m + 2)) % 68;
            float a = TWO_PI * (float)ph / 68.0f;
            vr = cosf(a); vi = -sinf(a);
        }
        Wf[2 * e] = vr; Wf[2 * e + 1] = vi;
    }
    float* Wg = ws + 9216;                // legacy
    for (int e = t; e < 68 * KH; e += 256) {
        int q = e / KH, k2 = e % KH;
        int ph = (q * k2) % 68;
        float a = TWO_PI * (float)ph / 68.0f;
        float alpha = (k2 == 0 || k2 == 34) ? 1.0f : 2.0f;
        Wg[2 * e]     = alpha * cosf(a) / 68.0f;
        Wg[2 * e + 1] = alpha * sinf(a) / 68.0f;
    }
    ushort* Wfb = (ushort*)(ws + 13976);  // [2][80][64] bf16
    for (int e = t; e < 80 * 64; e += 256) {
        int k = e >> 6, r = e & 63;
        float vr = 0.f, vi = 0.f;
        if (k < 68) {
            int ph = (k * (r + 2)) % 68;
            float a = TWO_PI * (float)ph / 68.0f;
            vr = cosf(a); vi = -sinf(a);
        }
        Wfb[e]        = f2bf(vr);
        Wfb[5120 + e] = f2bf(vi);
    }
    ushort* Wib = (ushort*)(ws + 19096);  // [2][80][128] bf16 pre-swizzled
    for (int e = t; e < 80 * 96; e += 256) {
        int p = e / 96, k = e % 96;
        float vr = 0.f, vi = 0.f;
        if (p < 68 && k < 68) {
            int ph = (p * k) % 68;
            float a = TWO_PI * (float)ph / 68.0f;
            vr = cosf(a) / 68.0f; vi = sinf(a) / 68.0f;
        }
        int dst = p * 128 + (((k >> 3) ^ (p & 7)) << 3) + (k & 7);
        Wib[dst]         = f2bf(vr);
        Wib[10240 + dst] = f2bf(vi);
    }
    // Wgb: A-table for stage 5. K axis = [Wgr(35) | -Wgi(35) | 0-pad to 96].
    ushort* Wgb = (ushort*)(ws + 29336);  // [80][128] bf16 pre-swizzled
    for (int e = t; e < 80 * 96; e += 256) {
        int q = e / 96, k = e % 96;
        float v = 0.f;
        if (q < 68 && k < 70) {
            int k2 = (k < KH) ? k : (k - KH);
            int ph = (q * k2) % 68;
            float a = TWO_PI * (float)ph / 68.0f;
            float alpha = (k2 == 0 || k2 == 34) ? 1.0f : 2.0f;
            v = (k < KH) ? (alpha * cosf(a) / 68.0f)
                         : (-alpha * sinf(a) / 68.0f);
        }
        int dst = q * 128 + (((k >> 3) ^ (q & 7)) << 3) + (k & 7);
        Wgb[dst] = f2bf(v);
    }
}

// zero only the seam bands (rows/cols 66,67,132,133,198,199 of each image)
__global__ void k_zero_seams(float* out) {
    int b = blockIdx.x / 12, line = blockIdx.x % 12;
    const int seam[6] = {66, 67, 132, 133, 198, 199};
    int t = threadIdx.x;
    if (line < 6) {
        int y = seam[line];
        float4* dst = (float4*)(out + ((size_t)(b * 256 + y)) * 256 * 64);
        for (int e = t; e < 4096; e += 256) dst[e] = make_float4(0, 0, 0, 0);
    } else {
        int x = seam[line - 6];
        float4* dst = (float4*)out;
        for (int e = t; e < 4096; e += 256) {
            int y = e >> 4, f = e & 15;
            dst[(((size_t)(b * 256 + y)) * 256 + x) * 16 + f] = make_float4(0, 0, 0, 0);
        }
    }
}

// ---------- one-time: kernel spectrum -> fp32 Kt[bin][i][o][c] (scratch) ----
__global__ void k_ktrans(const float* __restrict__ kr, const float* __restrict__ ki,
                         float* __restrict__ Kt) {
    __shared__ float tr[64 * 37];
    __shared__ float ti[64 * 37];
    int k1 = blockIdx.x >> 6, i = blockIdx.x & 63;
    int t = threadIdx.x;
    for (int e = t; e < 64 * KH; e += 256) {
        int o = e / KH, k2 = e % KH;
        size_t src = ((size_t)(o * 64 + i) * 68 + k1) * 68 + k2;
        tr[o * 37 + k2] = kr[src];
        ti[o * 37 + k2] = ki[src];
    }
    __syncthreads();
    for (int e = t; e < KH * 64; e += 256) {
        int k2 = e >> 6, o = e & 63;
        size_t dst = ((size_t)(k1 * KH + k2)) * 8192 + (size_t)i * 128 + o * 2;
        Kt[dst]     = tr[o * 37 + k2];
        Kt[dst + 1] = ti[o * 37 + k2];
    }
}

// ---------- one-time: Kt fp32 -> Ktb bf16 [bin][plane][o][i_swz] ------------
__global__ void k_kconv(const float* __restrict__ Kt, ushort* __restrict__ Ktb) {
    __shared__ float kl[64 * 130];
    int bin = blockIdx.x;
    int t = threadIdx.x;
    const float4* src = (const float4*)(Kt + (size_t)bin * 8192);
    for (int e = t; e < 2048; e += 256) {
        float4 v = src[e];
        int i = e >> 5, oc = (e & 31) << 2;
        kl[i * 130 + oc]     = v.x;
        kl[i * 130 + oc + 1] = v.y;
        kl[i * 130 + oc + 2] = v.z;
        kl[i * 130 + oc + 3] = v.w;
    }
    __syncthreads();
    ushort* dst = Ktb + (size_t)bin * 8192;
    for (int e = t; e < 4096; e += 256) {
        int o = e >> 6, i = e & 63;
        int sw = (o << 6) + (((i >> 3) ^ (o & 7)) << 3) + (i & 7);
        dst[sw]        = f2bf(kl[i * 130 + 2 * o]);
        dst[4096 + sw] = f2bf(kl[i * 130 + 2 * o + 1]);
    }
}

// ---------------- stage 1: row DFT — bf16 MFMA ----------------
// Y[nl][k2][r][i] = sum_c x[b, tr*64+r, tc*64+c, i] * Wf[k2][c]
__global__ __launch_bounds__(512) void k_fwd_row(
        const float* __restrict__ x, const ushort* __restrict__ Wfb,
        float* __restrict__ Y, int c0) {
    __shared__ __align__(16) ushort sAr[48 * 64];
    __shared__ __align__(16) ushort sAi[48 * 64];
    __shared__ __align__(16) ushort sB[4 * 64 * 64];   // [rr][i][c] swizzled
    int gid = blockIdx.x;
    int lc = gid >> 8;
    int rem = gid & 255;
    int nl = rem >> 4, rq = rem & 15;
    int n = (c0 + lc) * 16 + nl;
    int b = n >> 4, tr = (n >> 2) & 3, tc = n & 3;
    int t = threadIdx.x;
    for (int e = t; e < 3072; e += 512) {
        int m = e >> 6, c = e & 63;
        int sw = (m << 6) + (((c >> 3) ^ (m & 7)) << 3) + (c & 7);
        sAr[sw] = Wfb[e];
        sAi[sw] = Wfb[5120 + e];
    }
    for (int e = t; e < 4096; e += 512) {
        int rr = e >> 10, f = e & 1023;
        int c = f >> 4, i0 = (f & 15) << 2;
        int y = tr * 64 + rq * 4 + rr;
        const float4* src = (const float4*)(x + ((size_t)(b * 256 + y) * 256
                                                 + tc * 64) * 64 + (c << 6) + i0);
        float4 v = *src;
        float vv[4] = {v.x, v.y, v.z, v.w};
        #pragma unroll
        for (int u = 0; u < 4; ++u) {
            int i = i0 + u;
            sB[(rr << 12) + (i << 6) + (((c >> 3) ^ (i & 7)) << 3) + (c & 7)]
                = f2bf(vv[u]);
        }
    }
    __syncthreads();
    float* Yc = Y + (size_t)lc * CHS;
    int lane = t & 63, w = t >> 6;
    int lm = lane & 15, kg = lane >> 4;
    int ba0 = ((kg ^ (lm & 7)) << 3);
    int ba1 = (((kg + 4) ^ (lm & 7)) << 3);
    for (int tid = w; tid < 48; tid += 8) {
        int rr = tid / 12, rem2 = tid % 12;
        int mt = rem2 >> 2, nt = rem2 & 3;
        int am = mt * 16 + lm, bn = nt * 16 + lm;
        s16x8 a0r = *(const s16x8*)(sAr + (am << 6) + ba0);
        s16x8 a1r = *(const s16x8*)(sAr + (am << 6) + ba1);
        s16x8 a0i = *(const s16x8*)(sAi + (am << 6) + ba0);
        s16x8 a1i = *(const s16x8*)(sAi + (am << 6) + ba1);
        s16x8 b0 = *(const s16x8*)(sB + (rr << 12) + (bn << 6) + ba0);
        s16x8 b1 = *(const s16x8*)(sB + (rr << 12) + (bn << 6) + ba1);
        f32x4 yr = {0.f, 0.f, 0.f, 0.f}, yi = yr;
        yr = __builtin_amdgcn_mfma_f32_16x16x32_bf16(a0r, b0, yr, 0, 0, 0);
        yr = __builtin_amdgcn_mfma_f32_16x16x32_bf16(a1r, b1, yr, 0, 0, 0);
        yi = __builtin_amdgcn_mfma_f32_16x16x32_bf16(a0i, b0, yi, 0, 0, 0);
        yi = __builtin_amdgcn_mfma_f32_16x16x32_bf16(a1i, b1, yi, 0, 0, 0);
        int r = rq * 4 + rr;
        #pragma unroll
        for (int g2 = 0; g2 < 4; ++g2) {
            int k2 = mt * 16 + kg * 4 + g2;
            if (k2 < KH) {
                *(float2*)(Yc + ((size_t)(nl * KH + k2) * 64 + r) * 128
                           + 2 * (nt * 16 + lm))
                    = make_float2(yr[g2], yi[g2]);
            }
        }
    }
}

// ---------------- stage 2: column DFT — bf16 MFMA ----------------
// X[nl][k1][k2][i] = sum_r Wf[k1][r] * Y[nl][k2][r][i]
__global__ __launch_bounds__(512) void k_fwd_col(
        const float* __restrict__ Y, const ushort* __restrict__ Wfb,
        float* __restrict__ X) {
    __shared__ __align__(16) ushort sAr[80 * 64];
    __shared__ __align__(16) ushort sAi[80 * 64];
    __shared__ __align__(16) ushort sBr[64 * 64];
    __shared__ __align__(16) ushort sBi[64 * 64];
    int lc = blockIdx.x / 560;
    int rem = blockIdx.x % 560;
    int nl = rem / KH, k2 = rem % KH;
    const float* Yg = Y + (size_t)lc * CHS + ((size_t)(nl * KH + k2)) * 8192;
    float* Xc = X + (size_t)lc * CHS;
    int t = threadIdx.x;
    for (int e = t; e < 5120; e += 512) {
        int m = e >> 6, r = e & 63;
        int sw = (m << 6) + ((((r >> 3) ^ (m & 7))) << 3) + (r & 7);
        sAr[sw] = Wfb[e];
        sAi[sw] = Wfb[5120 + e];
    }
    for (int e = t; e < 4096; e += 512) {
        int i = e & 63, r = e >> 6;
        float2 v = *(const float2*)(Yg + (r << 7) + 2 * i);
        int sw = (i << 6) + ((((r >> 3) ^ (i & 7))) << 3) + (r & 7);
        sBr[sw] = f2bf(v.x);
        sBi[sw] = f2bf(v.y);
    }
    __syncthreads();
    int lane = t & 63, w = t >> 6;
    int lm = lane & 15, kg = lane >> 4;
    int ba0 = ((kg ^ (lm & 7)) << 3);
    int ba1 = (((kg + 4) ^ (lm & 7)) << 3);
    for (int tid = w; tid < 20; tid += 8) {
        int mt = tid >> 2, nt = tid & 3;
        int am = mt * 16 + lm, bn = nt * 16 + lm;
        s16x8 ar0 = *(const s16x8*)(sAr + (am << 6) + ba0);
        s16x8 ar1 = *(const s16x8*)(sAr + (am << 6) + ba1);
        s16x8 ai0 = *(const s16x8*)(sAi + (am << 6) + ba0);
        s16x8 ai1 = *(const s16x8*)(sAi + (am << 6) + ba1);
        s16x8 br0 = *(const s16x8*)(sBr + (bn << 6) + ba0);
        s16x8 br1 = *(const s16x8*)(sBr + (bn << 6) + ba1);
        s16x8 bi0 = *(const s16x8*)(sBi + (bn << 6) + ba0);
        s16x8 bi1 = *(const s16x8*)(sBi + (bn << 6) + ba1);
        f32x4 rr = {0.f, 0.f, 0.f, 0.f}, ii = rr, ri = rr, ir = rr;
        rr = __builtin_amdgcn_mfma_f32_16x16x32_bf16(ar0, br0, rr, 0, 0, 0);
        rr = __builtin_amdgcn_mfma_f32_16x16x32_bf16(ar1, br1, rr, 0, 0, 0);
        ii = __builtin_amdgcn_mfma_f32_16x16x32_bf16(ai0, bi0, ii, 0, 0, 0);
        ii = __builtin_amdgcn_mfma_f32_16x16x32_bf16(ai1, bi1, ii, 0, 0, 0);
        ri = __builtin_amdgcn_mfma_f32_16x16x32_bf16(ar0, bi0, ri, 0, 0, 0);
        ri = __builtin_amdgcn_mfma_f32_16x16x32_bf16(ar1, bi1, ri, 0, 0, 0);
        ir = __builtin_amdgcn_mfma_f32_16x16x32_bf16(ai0, br0, ir, 0, 0, 0);
        ir = __builtin_amdgcn_mfma_f32_16x16x32_bf16(ai1, br1, ir, 0, 0, 0);
        #pragma unroll
        for (int g2 = 0; g2 < 4; ++g2) {
            int k1 = mt * 16 + kg * 4 + g2;
            if (k1 < 68) {
                float2 res = make_float2(rr[g2] - ii[g2], ri[g2] + ir[g2]);
                *(float2*)(Xc + ((size_t)(nl * 68 + k1) * KH + k2) * 128
                           + 2 * (nt * 16 + lm)) = res;
            }
        }
    }
}

// ---------------- stage 3: channel mix — bf16 MFMA ----------------
// O[nl][k2][k1][o] = sum_i X[nl][k1][k2][i] * K[bin][i][o]
__global__ __launch_bounds__(256) void k_mix(
        const float* __restrict__ X, const ushort* __restrict__ Ktb,
        float* __restrict__ O) {
    __shared__ __align__(16) ushort sAr[16 * 64];
    __shared__ __align__(16) ushort sAi[16 * 64];
    __shared__ __align__(16) ushort sB[2 * 64 * 64];
    int lc = blockIdx.x / 2380;
    int bin = blockIdx.x % 2380;
    int k1 = bin / KH, k2 = bin % KH;
    const float* Xc = X + (size_t)lc * CHS;
    float* Oc = O + (size_t)lc * CHS;
    int t = threadIdx.x;
    for (int e = t; e < 1024; e += 256) {
        int n = e >> 6, i = e & 63;
        float2 v = *(const float2*)(Xc + ((size_t)(n * 68 + k1) * KH + k2) * 128 + 2 * i);
        int sw = (n << 6) + (((i >> 3) ^ (n & 7)) << 3) + (i & 7);
        sAr[sw] = f2bf(v.x);
        sAi[sw] = f2bf(v.y);
    }
    const uint4* ksrc = (const uint4*)(Ktb + (size_t)bin * 8192);
    for (int e = t; e < 1024; e += 256) ((uint4*)sB)[e] = ksrc[e];
    __syncthreads();
    const ushort* sBr = sB;
    const ushort* sBi = sB + 4096;
    int lane = t & 63, w = t >> 6;
    int lm = lane & 15, kg = lane >> 4;
    f32x4 rr = {0.f, 0.f, 0.f, 0.f}, ii = rr, ri = rr, ir = rr;
    #pragma unroll
    for (int st = 0; st < 2; ++st) {
        int blk = kg + st * 4;
        int ao = (lm << 6) + ((blk ^ (lm & 7)) << 3);
        int bo = ((w * 16 + lm) << 6) + ((blk ^ (lm & 7)) << 3);
        s16x8 axr = *(const s16x8*)(sAr + ao);
        s16x8 axi = *(const s16x8*)(sAi + ao);
        s16x8 bxr = *(const s16x8*)(sBr + bo);
        s16x8 bxi = *(const s16x8*)(sBi + bo);
        rr = __builtin_amdgcn_mfma_f32_16x16x32_bf16(axr, bxr, rr, 0, 0, 0);
        ii = __builtin_amdgcn_mfma_f32_16x16x32_bf16(axi, bxi, ii, 0, 0, 0);
        ri = __builtin_amdgcn_mfma_f32_16x16x32_bf16(axr, bxi, ri, 0, 0, 0);
        ir = __builtin_amdgcn_mfma_f32_16x16x32_bf16(axi, bxr, ir, 0, 0, 0);
    }
    #pragma unroll
    for (int g2 = 0; g2 < 4; ++g2) {
        int n = kg * 4 + g2;
        int o = w * 16 + lm;
        *(float2*)(Oc + (((size_t)n * KH + k2) * 68 + k1) * 128 + 2 * o)
            = make_float2(rr[g2] - ii[g2], ri[g2] + ir[g2]);
    }
}

// ---------------- stage 4: inverse column DFT — bf16 MFMA ----------------
// Z[nl][p][k2][o] = sum_k1 Wi[p][k1] * O[nl][k2][k1][o]
// 128-ushort rows (bank-uniform), K=96 in blocks 0..11, XOR-block swizzle.
__global__ __launch_bounds__(512) void k_inv_col(
        const float* __restrict__ O, const ushort* __restrict__ Wib,
        float* __restrict__ Z) {
    __shared__ __align__(16) ushort sAr[80 * 128];
    __shared__ __align__(16) ushort sAi[80 * 128];
    __shared__ __align__(16) ushort sBr[64 * 128];
    __shared__ __align__(16) ushort sBi[64 * 128];
    int lc = blockIdx.x / 560;
    int rem = blockIdx.x % 560;
    int nl = rem / KH, k2 = rem % KH;
    int t = threadIdx.x;
    const float* Ob = O + (size_t)lc * CHS + ((size_t)nl * KH + k2) * 68 * 128;
    float* Zc = Z + (size_t)lc * CHS;
    const uint4* wsrc = (const uint4*)Wib;
    for (int e = t; e < 1280; e += 512) ((uint4*)sAr)[e] = wsrc[e];
    for (int e = t; e < 1280; e += 512) ((uint4*)sAi)[e] = wsrc[1280 + e];
    uint4 zz = {0, 0, 0, 0};
    for (int e = t; e < 1024; e += 512) { ((uint4*)sBr)[e] = zz; ((uint4*)sBi)[e] = zz; }
    __syncthreads();
    for (int e = t; e < 4352; e += 512) {
        int k1 = e >> 6, o = e & 63;
        float2 v = *(const float2*)(Ob + (size_t)k1 * 128 + 2 * o);
        int sw = o * 128 + (((k1 >> 3) ^ (o & 7)) << 3) + (k1 & 7);
        sBr[sw] = f2bf(v.x);
        sBi[sw] = f2bf(v.y);
    }
    __syncthreads();
    int lane = t & 63, w = t >> 6;
    int lm = lane & 15, kg = lane >> 4;
    for (int tid = w; tid < 20; tid += 8) {
        int mt = tid >> 2, nt = tid & 3;
        int am = mt * 16 + lm, bn = nt * 16 + lm;
        f32x4 rr = {0.f, 0.f, 0.f, 0.f}, ii = rr, ri = rr, ir = rr;
        #pragma unroll
        for (int st = 0; st < 3; ++st) {
            int blk = kg + st * 4;
            int off = ((blk ^ (lm & 7)) << 3);
            s16x8 axr = *(const s16x8*)(sAr + am * 128 + off);
            s16x8 axi = *(const s16x8*)(sAi + am * 128 + off);
            s16x8 bxr = *(const s16x8*)(sBr + bn * 128 + off);
            s16x8 bxi = *(const s16x8*)(sBi + bn * 128 + off);
            rr = __builtin_amdgcn_mfma_f32_16x16x32_bf16(axr, bxr, rr, 0, 0, 0);
            ii = __builtin_amdgcn_mfma_f32_16x16x32_bf16(axi, bxi, ii, 0, 0, 0);
            ri = __builtin_amdgcn_mfma_f32_16x16x32_bf16(axr, bxi, ri, 0, 0, 0);
            ir = __builtin_amdgcn_mfma_f32_16x16x32_bf16(axi, bxr, ir, 0, 0, 0);
        }
        #pragma unroll
        for (int g2 = 0; g2 < 4; ++g2) {
            int p = mt * 16 + kg * 4 + g2;
            if (p < 68) {
                *(float2*)(Zc + (((size_t)(nl * 68 + p)) * KH + k2) * 128
                           + 2 * (nt * 16 + lm))
                    = make_float2(rr[g2] - ii[g2], ri[g2] + ir[g2]);
            }
        }
    }
}

// ---------------- stage 5: inverse row DFT + overlap-add — bf16 MFMA --------
// out[b, 66tr+p, 66tc+q, o] (+)= bias[o] + S[q][o],
// S = A*B: A = Wgb[q][k] = [Wgr | -Wgi] (K=70 pad 96), B = [Zr; Zi][k][o].
__global__ __launch_bounds__(512) void k_fused_inv(
        const float* __restrict__ Z, const ushort* __restrict__ Wgb,
        const float* __restrict__ bias, float* __restrict__ out, int c0) {
    __shared__ __align__(16) ushort sWg[80 * 128];   // 20 KB
    __shared__ __align__(16) ushort sBq[64 * 128];   // 16 KB
    int lc = blockIdx.x / 1088;
    int rem = blockIdx.x % 1088;
    int nl = rem / 68, p = rem % 68;
    int b = c0 + lc;
    int tr = nl >> 2, tc = nl & 3;
    int y = 66 * tr + p;
    if (y >= 256) return;
    int t = threadIdx.x;
    const float* Zb = Z + (size_t)lc * CHS + ((size_t)(nl * 68 + p)) * 4480;
    const uint4* wsrc = (const uint4*)Wgb;
    for (int e = t; e < 1280; e += 512) ((uint4*)sWg)[e] = wsrc[e];
    uint4 zz = {0, 0, 0, 0};
    for (int e = t; e < 1024; e += 512) ((uint4*)sBq)[e] = zz;
    __syncthreads();
    for (int e = t; e < KH * 64; e += 512) {
        int k2 = e >> 6, o = e & 63;
        float2 v = *(const float2*)(Zb + (k2 << 7) + 2 * o);
        int kb = k2 + KH;
        sBq[o * 128 + (((k2 >> 3) ^ (o & 7)) << 3) + (k2 & 7)] = f2bf(v.x);
        sBq[o * 128 + (((kb >> 3) ^ (o & 7)) << 3) + (kb & 7)] = f2bf(v.y);
    }
    __syncthreads();
    int lane = t & 63, w = t >> 6;
    int lm = lane & 15, kg = lane >> 4;
    bool rowu = !((p <= 1 && tr > 0) || (p >= 66 && tr < 3));
    float* orow = out + ((size_t)(b * 256 + y)) * 256 * 64;
    for (int tid = w; tid < 20; tid += 8) {
        int mt = tid >> 2, nt = tid & 3;
        int am = mt * 16 + lm, bn = nt * 16 + lm;
        f32x4 acc = {0.f, 0.f, 0.f, 0.f};
        #pragma unroll
        for (int st = 0; st < 3; ++st) {
            int blk = kg + st * 4;
            int off = ((blk ^ (lm & 7)) << 3);
            s16x8 av = *(const s16x8*)(sWg + am * 128 + off);
            s16x8 bv = *(const s16x8*)(sBq + bn * 128 + off);
            acc = __builtin_amdgcn_mfma_f32_16x16x32_bf16(av, bv, acc, 0, 0, 0);
        }
        int o = nt * 16 + lm;
        float bv = bias[o];
        #pragma unroll
        for (int g2 = 0; g2 < 4; ++g2) {
            int q = mt * 16 + kg * 4 + g2;
            if (q >= 68) continue;
            int xx = 66 * tc + q;
            if (xx >= 256) continue;
            bool colu = !((q <= 1 && tc > 0) || (q >= 66 && tc < 3));
            float v = acc[g2] + bv;
            float* addr = orow + (size_t)xx * 64 + o;
            if (rowu && colu) *addr = v;
            else              atomicAdd(addr, v);
        }
    }
}

extern "C" void kernel_launch(void* const* d_in, const int* in_sizes, int n_in,
                              void* d_out, int out_size, void* d_ws, size_t ws_size,
                              hipStream_t stream) {
    const float* x    = (const float*)d_in[0];
    const float* kr   = (const float*)d_in[1];
    const float* ki   = (const float*)d_in[2];
    const float* bias = (const float*)d_in[3];
    float* out = (float*)d_out;
    float* ws  = (float*)d_ws;

    int CH = 8;
    while (CH > 4 && (WS_HEAD + KTB_FLOATS + 2ull * CH * CHS) * 4ull > ws_size)
        CH >>= 1;

    ushort* Wfb  = (ushort*)(ws + 13976);      // 10240 ushorts
    ushort* Wib  = (ushort*)(ws + 19096);      // 20480 ushorts
    ushort* Wgb  = (ushort*)(ws + 29336);      // 10240 ushorts
    ushort* Ktb  = (ushort*)(ws + WS_HEAD);    // 2380*8192 ushorts
    float*  bufA = ws + WS_HEAD + KTB_FLOATS;  // Y then O
    float*  bufB = bufA + (size_t)CH * CHS;    // X then Z (also Kt scratch)

    k_twiddle<<<1, 256, 0, stream>>>(ws);
    k_ktrans<<<68 * 64, 256, 0, stream>>>(kr, ki, bufB);   // fp32 Kt scratch
    k_kconv<<<2380, 256, 0, stream>>>(bufB, Ktb);          // -> bf16 pre-swizzled
    k_zero_seams<<<96, 256, 0, stream>>>(out);

    for (int s = 0; s < 8; s += CH) {
        k_fwd_row<<<CH * 256, 512, 0, stream>>>(x, Wfb, bufA, s);
        k_fwd_col<<<CH * 560, 512, 0, stream>>>(bufA, Wfb, bufB);
        k_mix<<<CH * 2380, 256, 0, stream>>>(bufB, Ktb, bufA);
        k_inv_col<<<CH * 560, 512, 0, stream>>>(bufA, Wib, bufB);
        k_fused_inv<<<CH * 1088, 512, 0, stream>>>(bufB, Wgb, bias, out, s);
    }
}

// Round 20
// 414.875 us; speedup vs baseline: 3.3963x; 1.3947x over previous
//
#include <hip/hip_runtime.h>
#include <hip/hip_bf16.h>

// FFT-tiled conv: B=8, IMG=256, CIN=COUT=64, TILE=64, FFT=68, PAD=2.
// Frequency-domain per-tile conv via DFT-as-matmul, Hermitian half-spectrum
// (k2 in [0,35)), direct overlap-add (plain stores interior, atomics on seams,
// seam bands pre-zeroed). ALL five stages run on bf16 MFMA.
// ALL intermediates (Y,X,O,Z) stored as packed bf16 complex (uint re|im<<16).
//
// Layouts (per 16-tile chunk slot of CHS uints, oversized):
//   Y  [nl][k2][r][i]    uint   ((nl*35+k2)*64+r)*64 + i
//   X  [nl][k1][k2][i]   uint   ((nl*68+k1)*35+k2)*64 + i
//   O  [nl][k2][k1][o]   uint   ((nl*35+k2)*68+k1)*64 + o
//   Z  [nl][p][k2][o]    uint   ((nl*68+p)*35+k2)*64 + o
//   Ktb[bin][2][o][i] bf16 pre-swizzled, 39 MB one-time (bin = k1*35+k2)
//
// Twiddle tables:
//   Wfb [2][80][64] bf16 rows>=68 zero              (5120 floats)
//   Wib [2][80][128] bf16 pre-swizzled, zero-pad    (10240 floats)
//   Wgb [80][128] bf16 pre-swizzled, K=[Wgr|-Wgi]   (5120 floats)

#define KH   35
#define CHS  4874240ull                       // elements per chunk slot
#define KTB_FLOATS 9748480ull
#define WS_HEAD 34456ull                      // legacy head layout kept

typedef float f32x4 __attribute__((ext_vector_type(4)));
typedef short s16x8 __attribute__((ext_vector_type(8)));

__device__ __forceinline__ ushort f2bf(float f) {
    __hip_bfloat16 h = __float2bfloat16(f);
    return *reinterpret_cast<ushort*>(&h);
}
__device__ __forceinline__ uint pkbf(float re, float im) {
    return (uint)f2bf(re) | ((uint)f2bf(im) << 16);
}

__global__ void k_twiddle(float* ws) {
    const float TWO_PI = 6.28318530717958647692f;
    int t = threadIdx.x;
    ushort* Wfb = (ushort*)(ws + 13976);  // [2][80][64] bf16
    for (int e = t; e < 80 * 64; e += 256) {
        int k = e >> 6, r = e & 63;
        float vr = 0.f, vi = 0.f;
        if (k < 68) {
            int ph = (k * (r + 2)) % 68;
            float a = TWO_PI * (float)ph / 68.0f;
            vr = cosf(a); vi = -sinf(a);
        }
        Wfb[e]        = f2bf(vr);
        Wfb[5120 + e] = f2bf(vi);
    }
    ushort* Wib = (ushort*)(ws + 19096);  // [2][80][128] bf16 pre-swizzled
    for (int e = t; e < 80 * 96; e += 256) {
        int p = e / 96, k = e % 96;
        float vr = 0.f, vi = 0.f;
        if (p < 68 && k < 68) {
            int ph = (p * k) % 68;
            float a = TWO_PI * (float)ph / 68.0f;
            vr = cosf(a) / 68.0f; vi = sinf(a) / 68.0f;
        }
        int dst = p * 128 + (((k >> 3) ^ (p & 7)) << 3) + (k & 7);
        Wib[dst]         = f2bf(vr);
        Wib[10240 + dst] = f2bf(vi);
    }
    ushort* Wgb = (ushort*)(ws + 29336);  // [80][128] bf16 pre-swizzled
    for (int e = t; e < 80 * 96; e += 256) {
        int q = e / 96, k = e % 96;
        float v = 0.f;
        if (q < 68 && k < 70) {
            int k2 = (k < KH) ? k : (k - KH);
            int ph = (q * k2) % 68;
            float a = TWO_PI * (float)ph / 68.0f;
            float alpha = (k2 == 0 || k2 == 34) ? 1.0f : 2.0f;
            v = (k < KH) ? (alpha * cosf(a) / 68.0f)
                         : (-alpha * sinf(a) / 68.0f);
        }
        int dst = q * 128 + (((k >> 3) ^ (q & 7)) << 3) + (k & 7);
        Wgb[dst] = f2bf(v);
    }
}

// zero only the seam bands (rows/cols 66,67,132,133,198,199 of each image)
__global__ void k_zero_seams(float* out) {
    int b = blockIdx.x / 12, line = blockIdx.x % 12;
    const int seam[6] = {66, 67, 132, 133, 198, 199};
    int t = threadIdx.x;
    if (line < 6) {
        int y = seam[line];
        float4* dst = (float4*)(out + ((size_t)(b * 256 + y)) * 256 * 64);
        for (int e = t; e < 4096; e += 256) dst[e] = make_float4(0, 0, 0, 0);
    } else {
        int x = seam[line - 6];
        float4* dst = (float4*)out;
        for (int e = t; e < 4096; e += 256) {
            int y = e >> 4, f = e & 15;
            dst[(((size_t)(b * 256 + y)) * 256 + x) * 16 + f] = make_float4(0, 0, 0, 0);
        }
    }
}

// ---------- one-time: kernel spectrum -> fp32 Kt[bin][i][o][c] (scratch) ----
__global__ void k_ktrans(const float* __restrict__ kr, const float* __restrict__ ki,
                         float* __restrict__ Kt) {
    __shared__ float tr[64 * 37];
    __shared__ float ti[64 * 37];
    int k1 = blockIdx.x >> 6, i = blockIdx.x & 63;
    int t = threadIdx.x;
    for (int e = t; e < 64 * KH; e += 256) {
        int o = e / KH, k2 = e % KH;
        size_t src = ((size_t)(o * 64 + i) * 68 + k1) * 68 + k2;
        tr[o * 37 + k2] = kr[src];
        ti[o * 37 + k2] = ki[src];
    }
    __syncthreads();
    for (int e = t; e < KH * 64; e += 256) {
        int k2 = e >> 6, o = e & 63;
        size_t dst = ((size_t)(k1 * KH + k2)) * 8192 + (size_t)i * 128 + o * 2;
        Kt[dst]     = tr[o * 37 + k2];
        Kt[dst + 1] = ti[o * 37 + k2];
    }
}

// ---------- one-time: Kt fp32 -> Ktb bf16 [bin][plane][o][i_swz] ------------
__global__ void k_kconv(const float* __restrict__ Kt, ushort* __restrict__ Ktb) {
    __shared__ float kl[64 * 130];
    int bin = blockIdx.x;
    int t = threadIdx.x;
    const float4* src = (const float4*)(Kt + (size_t)bin * 8192);
    for (int e = t; e < 2048; e += 256) {
        float4 v = src[e];
        int i = e >> 5, oc = (e & 31) << 2;
        kl[i * 130 + oc]     = v.x;
        kl[i * 130 + oc + 1] = v.y;
        kl[i * 130 + oc + 2] = v.z;
        kl[i * 130 + oc + 3] = v.w;
    }
    __syncthreads();
    ushort* dst = Ktb + (size_t)bin * 8192;
    for (int e = t; e < 4096; e += 256) {
        int o = e >> 6, i = e & 63;
        int sw = (o << 6) + (((i >> 3) ^ (o & 7)) << 3) + (i & 7);
        dst[sw]        = f2bf(kl[i * 130 + 2 * o]);
        dst[4096 + sw] = f2bf(kl[i * 130 + 2 * o + 1]);
    }
}

// ---------------- stage 1: row DFT — bf16 MFMA ----------------
// Y[nl][k2][r][i] = sum_c x[b, tr*64+r, tc*64+c, i] * Wf[k2][c]
__global__ __launch_bounds__(512) void k_fwd_row(
        const float* __restrict__ x, const ushort* __restrict__ Wfb,
        uint* __restrict__ Y, int c0) {
    __shared__ __align__(16) ushort sAr[48 * 64];
    __shared__ __align__(16) ushort sAi[48 * 64];
    __shared__ __align__(16) ushort sB[4 * 64 * 64];
    int gid = blockIdx.x;
    int lc = gid >> 8;
    int rem = gid & 255;
    int nl = rem >> 4, rq = rem & 15;
    int n = (c0 + lc) * 16 + nl;
    int b = n >> 4, tr = (n >> 2) & 3, tc = n & 3;
    int t = threadIdx.x;
    for (int e = t; e < 3072; e += 512) {
        int m = e >> 6, c = e & 63;
        int sw = (m << 6) + (((c >> 3) ^ (m & 7)) << 3) + (c & 7);
        sAr[sw] = Wfb[e];
        sAi[sw] = Wfb[5120 + e];
    }
    for (int e = t; e < 4096; e += 512) {
        int rr = e >> 10, f = e & 1023;
        int c = f >> 4, i0 = (f & 15) << 2;
        int y = tr * 64 + rq * 4 + rr;
        const float4* src = (const float4*)(x + ((size_t)(b * 256 + y) * 256
                                                 + tc * 64) * 64 + (c << 6) + i0);
        float4 v = *src;
        float vv[4] = {v.x, v.y, v.z, v.w};
        #pragma unroll
        for (int u = 0; u < 4; ++u) {
            int i = i0 + u;
            sB[(rr << 12) + (i << 6) + (((c >> 3) ^ (i & 7)) << 3) + (c & 7)]
                = f2bf(vv[u]);
        }
    }
    __syncthreads();
    uint* Yc = Y + (size_t)lc * CHS;
    int lane = t & 63, w = t >> 6;
    int lm = lane & 15, kg = lane >> 4;
    int ba0 = ((kg ^ (lm & 7)) << 3);
    int ba1 = (((kg + 4) ^ (lm & 7)) << 3);
    for (int tid = w; tid < 48; tid += 8) {
        int rr = tid / 12, rem2 = tid % 12;
        int mt = rem2 >> 2, nt = rem2 & 3;
        int am = mt * 16 + lm, bn = nt * 16 + lm;
        s16x8 a0r = *(const s16x8*)(sAr + (am << 6) + ba0);
        s16x8 a1r = *(const s16x8*)(sAr + (am << 6) + ba1);
        s16x8 a0i = *(const s16x8*)(sAi + (am << 6) + ba0);
        s16x8 a1i = *(const s16x8*)(sAi + (am << 6) + ba1);
        s16x8 b0 = *(const s16x8*)(sB + (rr << 12) + (bn << 6) + ba0);
        s16x8 b1 = *(const s16x8*)(sB + (rr << 12) + (bn << 6) + ba1);
        f32x4 yr = {0.f, 0.f, 0.f, 0.f}, yi = yr;
        yr = __builtin_amdgcn_mfma_f32_16x16x32_bf16(a0r, b0, yr, 0, 0, 0);
        yr = __builtin_amdgcn_mfma_f32_16x16x32_bf16(a1r, b1, yr, 0, 0, 0);
        yi = __builtin_amdgcn_mfma_f32_16x16x32_bf16(a0i, b0, yi, 0, 0, 0);
        yi = __builtin_amdgcn_mfma_f32_16x16x32_bf16(a1i, b1, yi, 0, 0, 0);
        int r = rq * 4 + rr;
        #pragma unroll
        for (int g2 = 0; g2 < 4; ++g2) {
            int k2 = mt * 16 + kg * 4 + g2;
            if (k2 < KH)
                Yc[((size_t)(nl * KH + k2) * 64 + r) * 64 + nt * 16 + lm]
                    = pkbf(yr[g2], yi[g2]);
        }
    }
}

// ---------------- stage 2: column DFT — bf16 MFMA ----------------
// X[nl][k1][k2][i] = sum_r Wf[k1][r] * Y[nl][k2][r][i]
__global__ __launch_bounds__(512) void k_fwd_col(
        const uint* __restrict__ Y, const ushort* __restrict__ Wfb,
        uint* __restrict__ X) {
    __shared__ __align__(16) ushort sAr[80 * 64];
    __shared__ __align__(16) ushort sAi[80 * 64];
    __shared__ __align__(16) ushort sBr[64 * 64];
    __shared__ __align__(16) ushort sBi[64 * 64];
    int lc = blockIdx.x / 560;
    int rem = blockIdx.x % 560;
    int nl = rem / KH, k2 = rem % KH;
    const uint* Yg = Y + (size_t)lc * CHS + ((size_t)(nl * KH + k2)) * 4096;
    uint* Xc = X + (size_t)lc * CHS;
    int t = threadIdx.x;
    for (int e = t; e < 5120; e += 512) {
        int m = e >> 6, r = e & 63;
        int sw = (m << 6) + ((((r >> 3) ^ (m & 7))) << 3) + (r & 7);
        sAr[sw] = Wfb[e];
        sAi[sw] = Wfb[5120 + e];
    }
    for (int e = t; e < 4096; e += 512) {
        int i = e & 63, r = e >> 6;
        uint v = Yg[e];
        int sw = (i << 6) + ((((r >> 3) ^ (i & 7))) << 3) + (r & 7);
        sBr[sw] = (ushort)(v & 0xffff);
        sBi[sw] = (ushort)(v >> 16);
    }
    __syncthreads();
    int lane = t & 63, w = t >> 6;
    int lm = lane & 15, kg = lane >> 4;
    int ba0 = ((kg ^ (lm & 7)) << 3);
    int ba1 = (((kg + 4) ^ (lm & 7)) << 3);
    for (int tid = w; tid < 20; tid += 8) {
        int mt = tid >> 2, nt = tid & 3;
        int am = mt * 16 + lm, bn = nt * 16 + lm;
        s16x8 ar0 = *(const s16x8*)(sAr + (am << 6) + ba0);
        s16x8 ar1 = *(const s16x8*)(sAr + (am << 6) + ba1);
        s16x8 ai0 = *(const s16x8*)(sAi + (am << 6) + ba0);
        s16x8 ai1 = *(const s16x8*)(sAi + (am << 6) + ba1);
        s16x8 br0 = *(const s16x8*)(sBr + (bn << 6) + ba0);
        s16x8 br1 = *(const s16x8*)(sBr + (bn << 6) + ba1);
        s16x8 bi0 = *(const s16x8*)(sBi + (bn << 6) + ba0);
        s16x8 bi1 = *(const s16x8*)(sBi + (bn << 6) + ba1);
        f32x4 rr = {0.f, 0.f, 0.f, 0.f}, ii = rr, ri = rr, ir = rr;
        rr = __builtin_amdgcn_mfma_f32_16x16x32_bf16(ar0, br0, rr, 0, 0, 0);
        rr = __builtin_amdgcn_mfma_f32_16x16x32_bf16(ar1, br1, rr, 0, 0, 0);
        ii = __builtin_amdgcn_mfma_f32_16x16x32_bf16(ai0, bi0, ii, 0, 0, 0);
        ii = __builtin_amdgcn_mfma_f32_16x16x32_bf16(ai1, bi1, ii, 0, 0, 0);
        ri = __builtin_amdgcn_mfma_f32_16x16x32_bf16(ar0, bi0, ri, 0, 0, 0);
        ri = __builtin_amdgcn_mfma_f32_16x16x32_bf16(ar1, bi1, ri, 0, 0, 0);
        ir = __builtin_amdgcn_mfma_f32_16x16x32_bf16(ai0, br0, ir, 0, 0, 0);
        ir = __builtin_amdgcn_mfma_f32_16x16x32_bf16(ai1, br1, ir, 0, 0, 0);
        #pragma unroll
        for (int g2 = 0; g2 < 4; ++g2) {
            int k1 = mt * 16 + kg * 4 + g2;
            if (k1 < 68)
                Xc[((size_t)(nl * 68 + k1) * KH + k2) * 64 + nt * 16 + lm]
                    = pkbf(rr[g2] - ii[g2], ri[g2] + ir[g2]);
        }
    }
}

// ---------------- stage 3: channel mix — bf16 MFMA ----------------
// O[nl][k2][k1][o] = sum_i X[nl][k1][k2][i] * K[bin][i][o]
__global__ __launch_bounds__(256) void k_mix(
        const uint* __restrict__ X, const ushort* __restrict__ Ktb,
        uint* __restrict__ O) {
    __shared__ __align__(16) ushort sAr[16 * 64];
    __shared__ __align__(16) ushort sAi[16 * 64];
    __shared__ __align__(16) ushort sB[2 * 64 * 64];
    int lc = blockIdx.x / 2380;
    int bin = blockIdx.x % 2380;
    int k1 = bin / KH, k2 = bin % KH;
    const uint* Xc = X + (size_t)lc * CHS;
    uint* Oc = O + (size_t)lc * CHS;
    int t = threadIdx.x;
    for (int e = t; e < 1024; e += 256) {
        int n = e >> 6, i = e & 63;
        uint v = Xc[((size_t)(n * 68 + k1) * KH + k2) * 64 + i];
        int sw = (n << 6) + (((i >> 3) ^ (n & 7)) << 3) + (i & 7);
        sAr[sw] = (ushort)(v & 0xffff);
        sAi[sw] = (ushort)(v >> 16);
    }
    const uint4* ksrc = (const uint4*)(Ktb + (size_t)bin * 8192);
    for (int e = t; e < 1024; e += 256) ((uint4*)sB)[e] = ksrc[e];
    __syncthreads();
    const ushort* sBr = sB;
    const ushort* sBi = sB + 4096;
    int lane = t & 63, w = t >> 6;
    int lm = lane & 15, kg = lane >> 4;
    f32x4 rr = {0.f, 0.f, 0.f, 0.f}, ii = rr, ri = rr, ir = rr;
    #pragma unroll
    for (int st = 0; st < 2; ++st) {
        int blk = kg + st * 4;
        int ao = (lm << 6) + ((blk ^ (lm & 7)) << 3);
        int bo = ((w * 16 + lm) << 6) + ((blk ^ (lm & 7)) << 3);
        s16x8 axr = *(const s16x8*)(sAr + ao);
        s16x8 axi = *(const s16x8*)(sAi + ao);
        s16x8 bxr = *(const s16x8*)(sBr + bo);
        s16x8 bxi = *(const s16x8*)(sBi + bo);
        rr = __builtin_amdgcn_mfma_f32_16x16x32_bf16(axr, bxr, rr, 0, 0, 0);
        ii = __builtin_amdgcn_mfma_f32_16x16x32_bf16(axi, bxi, ii, 0, 0, 0);
        ri = __builtin_amdgcn_mfma_f32_16x16x32_bf16(axr, bxi, ri, 0, 0, 0);
        ir = __builtin_amdgcn_mfma_f32_16x16x32_bf16(axi, bxr, ir, 0, 0, 0);
    }
    #pragma unroll
    for (int g2 = 0; g2 < 4; ++g2) {
        int n = kg * 4 + g2;
        int o = w * 16 + lm;
        Oc[(((size_t)n * KH + k2) * 68 + k1) * 64 + o]
            = pkbf(rr[g2] - ii[g2], ri[g2] + ir[g2]);
    }
}

// ---------------- stage 4: inverse column DFT — bf16 MFMA ----------------
// Z[nl][p][k2][o] = sum_k1 Wi[p][k1] * O[nl][k2][k1][o]
__global__ __launch_bounds__(512) void k_inv_col(
        const uint* __restrict__ O, const ushort* __restrict__ Wib,
        uint* __restrict__ Z) {
    __shared__ __align__(16) ushort sAr[80 * 128];
    __shared__ __align__(16) ushort sAi[80 * 128];
    __shared__ __align__(16) ushort sBr[64 * 128];
    __shared__ __align__(16) ushort sBi[64 * 128];
    int lc = blockIdx.x / 560;
    int rem = blockIdx.x % 560;
    int nl = rem / KH, k2 = rem % KH;
    int t = threadIdx.x;
    const uint* Ob = O + (size_t)lc * CHS + ((size_t)nl * KH + k2) * 68 * 64;
    uint* Zc = Z + (size_t)lc * CHS;
    const uint4* wsrc = (const uint4*)Wib;
    for (int e = t; e < 1280; e += 512) ((uint4*)sAr)[e] = wsrc[e];
    for (int e = t; e < 1280; e += 512) ((uint4*)sAi)[e] = wsrc[1280 + e];
    uint4 zz = {0, 0, 0, 0};
    for (int e = t; e < 1024; e += 512) { ((uint4*)sBr)[e] = zz; ((uint4*)sBi)[e] = zz; }
    __syncthreads();
    for (int e = t; e < 4352; e += 512) {
        int k1 = e >> 6, o = e & 63;
        uint v = Ob[e];
        int sw = o * 128 + (((k1 >> 3) ^ (o & 7)) << 3) + (k1 & 7);
        sBr[sw] = (ushort)(v & 0xffff);
        sBi[sw] = (ushort)(v >> 16);
    }
    __syncthreads();
    int lane = t & 63, w = t >> 6;
    int lm = lane & 15, kg = lane >> 4;
    for (int tid = w; tid < 20; tid += 8) {
        int mt = tid >> 2, nt = tid & 3;
        int am = mt * 16 + lm, bn = nt * 16 + lm;
        f32x4 rr = {0.f, 0.f, 0.f, 0.f}, ii = rr, ri = rr, ir = rr;
        #pragma unroll
        for (int st = 0; st < 3; ++st) {
            int blk = kg + st * 4;
            int off = ((blk ^ (lm & 7)) << 3);
            s16x8 axr = *(const s16x8*)(sAr + am * 128 + off);
            s16x8 axi = *(const s16x8*)(sAi + am * 128 + off);
            s16x8 bxr = *(const s16x8*)(sBr + bn * 128 + off);
            s16x8 bxi = *(const s16x8*)(sBi + bn * 128 + off);
            rr = __builtin_amdgcn_mfma_f32_16x16x32_bf16(axr, bxr, rr, 0, 0, 0);
            ii = __builtin_amdgcn_mfma_f32_16x16x32_bf16(axi, bxi, ii, 0, 0, 0);
            ri = __builtin_amdgcn_mfma_f32_16x16x32_bf16(axr, bxi, ri, 0, 0, 0);
            ir = __builtin_amdgcn_mfma_f32_16x16x32_bf16(axi, bxr, ir, 0, 0, 0);
        }
        #pragma unroll
        for (int g2 = 0; g2 < 4; ++g2) {
            int p = mt * 16 + kg * 4 + g2;
            if (p < 68)
                Zc[(((size_t)(nl * 68 + p)) * KH + k2) * 64 + nt * 16 + lm]
                    = pkbf(rr[g2] - ii[g2], ri[g2] + ir[g2]);
        }
    }
}

// ---------------- stage 5: inverse row DFT + overlap-add — bf16 MFMA --------
__global__ __launch_bounds__(512) void k_fused_inv(
        const uint* __restrict__ Z, const ushort* __restrict__ Wgb,
        const float* __restrict__ bias, float* __restrict__ out, int c0) {
    __shared__ __align__(16) ushort sWg[80 * 128];
    __shared__ __align__(16) ushort sBq[64 * 128];
    int lc = blockIdx.x / 1088;
    int rem = blockIdx.x % 1088;
    int nl = rem / 68, p = rem % 68;
    int b = c0 + lc;
    int tr = nl >> 2, tc = nl & 3;
    int y = 66 * tr + p;
    if (y >= 256) return;
    int t = threadIdx.x;
    const uint* Zb = Z + (size_t)lc * CHS + ((size_t)(nl * 68 + p)) * KH * 64;
    const uint4* wsrc = (const uint4*)Wgb;
    for (int e = t; e < 1280; e += 512) ((uint4*)sWg)[e] = wsrc[e];
    uint4 zz = {0, 0, 0, 0};
    for (int e = t; e < 1024; e += 512) ((uint4*)sBq)[e] = zz;
    __syncthreads();
    for (int e = t; e < KH * 64; e += 512) {
        int k2 = e >> 6, o = e & 63;
        uint v = Zb[e];
        int kb = k2 + KH;
        sBq[o * 128 + (((k2 >> 3) ^ (o & 7)) << 3) + (k2 & 7)] = (ushort)(v & 0xffff);
        sBq[o * 128 + (((kb >> 3) ^ (o & 7)) << 3) + (kb & 7)] = (ushort)(v >> 16);
    }
    __syncthreads();
    int lane = t & 63, w = t >> 6;
    int lm = lane & 15, kg = lane >> 4;
    bool rowu = !((p <= 1 && tr > 0) || (p >= 66 && tr < 3));
    float* orow = out + ((size_t)(b * 256 + y)) * 256 * 64;
    for (int tid = w; tid < 20; tid += 8) {
        int mt = tid >> 2, nt = tid & 3;
        int am = mt * 16 + lm, bn = nt * 16 + lm;
        f32x4 acc = {0.f, 0.f, 0.f, 0.f};
        #pragma unroll
        for (int st = 0; st < 3; ++st) {
            int blk = kg + st * 4;
            int off = ((blk ^ (lm & 7)) << 3);
            s16x8 av = *(const s16x8*)(sWg + am * 128 + off);
            s16x8 bv = *(const s16x8*)(sBq + bn * 128 + off);
            acc = __builtin_amdgcn_mfma_f32_16x16x32_bf16(av, bv, acc, 0, 0, 0);
        }
        int o = nt * 16 + lm;
        float bv = bias[o];
        #pragma unroll
        for (int g2 = 0; g2 < 4; ++g2) {
            int q = mt * 16 + kg * 4 + g2;
            if (q >= 68) continue;
            int xx = 66 * tc + q;
            if (xx >= 256) continue;
            bool colu = !((q <= 1 && tc > 0) || (q >= 66 && tc < 3));
            float v = acc[g2] + bv;
            float* addr = orow + (size_t)xx * 64 + o;
            if (rowu && colu) *addr = v;
            else              atomicAdd(addr, v);
        }
    }
}

extern "C" void kernel_launch(void* const* d_in, const int* in_sizes, int n_in,
                              void* d_out, int out_size, void* d_ws, size_t ws_size,
                              hipStream_t stream) {
    const float* x    = (const float*)d_in[0];
    const float* kr   = (const float*)d_in[1];
    const float* ki   = (const float*)d_in[2];
    const float* bias = (const float*)d_in[3];
    float* out = (float*)d_out;
    float* ws  = (float*)d_ws;

    int CH = 8;
    while (CH > 4 && (WS_HEAD + KTB_FLOATS + 2ull * CH * CHS) * 4ull > ws_size)
        CH >>= 1;

    ushort* Wfb  = (ushort*)(ws + 13976);
    ushort* Wib  = (ushort*)(ws + 19096);
    ushort* Wgb  = (ushort*)(ws + 29336);
    ushort* Ktb  = (ushort*)(ws + WS_HEAD);
    float*  bufA = ws + WS_HEAD + KTB_FLOATS;  // Y then O (as uint)
    float*  bufB = bufA + (size_t)CH * CHS;    // X then Z (also Kt scratch)

    k_twiddle<<<1, 256, 0, stream>>>(ws);
    k_ktrans<<<68 * 64, 256, 0, stream>>>(kr, ki, bufB);
    k_kconv<<<2380, 256, 0, stream>>>(bufB, Ktb);
    k_zero_seams<<<96, 256, 0, stream>>>(out);

    for (int s = 0; s < 8; s += CH) {
        k_fwd_row<<<CH * 256, 512, 0, stream>>>(x, Wfb, (uint*)bufA, s);
        k_fwd_col<<<CH * 560, 512, 0, stream>>>((const uint*)bufA, Wfb, (uint*)bufB);
        k_mix<<<CH * 2380, 256, 0, stream>>>((const uint*)bufB, Ktb, (uint*)bufA);
        k_inv_col<<<CH * 560, 512, 0, stream>>>((const uint*)bufA, Wib, (uint*)bufB);
        k_fused_inv<<<CH * 1088, 512, 0, stream>>>((const uint*)bufB, Wgb, bias, out, s);
    }
}

// Round 21
// 399.576 us; speedup vs baseline: 3.5263x; 1.0383x over previous
//
#include <hip/hip_runtime.h>
#include <hip/hip_bf16.h>

// FFT-tiled conv: B=8, IMG=256, CIN=COUT=64, TILE=64, FFT=68, PAD=2.
// Frequency-domain per-tile conv via DFT-as-matmul, Hermitian half-spectrum
// (k2 in [0,35)), direct overlap-add (plain stores interior, atomics on seams,
// seam bands pre-zeroed). ALL five stages run on bf16 MFMA.
// ALL intermediates (Y,X,O,Z) stored as packed bf16 complex (uint re|im<<16).
//
// Layouts (per 16-tile chunk slot of CHS uints, oversized):
//   Y  [nl][k2][r][i]    uint   ((nl*35+k2)*64+r)*64 + i
//   X  [nl][k1][k2][i]   uint   ((nl*68+k1)*35+k2)*64 + i
//   O  [nl][k2][k1][o]   uint   ((nl*35+k2)*68+k1)*64 + o
//   Z  [nl][p][k2][o]    uint   ((nl*68+p)*35+k2)*64 + o
//   Ktb[bin][2][o][i] bf16 pre-swizzled, 39 MB one-time (bin = k1*35+k2)
//
// Twiddle tables:
//   Wfb [2][80][64] bf16 rows>=68 zero              (5120 floats)
//   Wib [2][80][128] bf16 pre-swizzled, zero-pad    (10240 floats)
//   Wgb [80][128] bf16 pre-swizzled, K=[Wgr|-Wgi]   (5120 floats)

#define KH   35
#define CHS  4874240ull                       // elements per chunk slot
#define KTB_FLOATS 9748480ull
#define WS_HEAD 34456ull                      // legacy head layout kept

typedef float f32x4 __attribute__((ext_vector_type(4)));
typedef short s16x8 __attribute__((ext_vector_type(8)));

__device__ __forceinline__ ushort f2bf(float f) {
    __hip_bfloat16 h = __float2bfloat16(f);
    return *reinterpret_cast<ushort*>(&h);
}
__device__ __forceinline__ uint pkbf(float re, float im) {
    return (uint)f2bf(re) | ((uint)f2bf(im) << 16);
}

__global__ void k_twiddle(float* ws) {
    const float TWO_PI = 6.28318530717958647692f;
    int t = threadIdx.x;
    ushort* Wfb = (ushort*)(ws + 13976);  // [2][80][64] bf16
    for (int e = t; e < 80 * 64; e += 256) {
        int k = e >> 6, r = e & 63;
        float vr = 0.f, vi = 0.f;
        if (k < 68) {
            int ph = (k * (r + 2)) % 68;
            float a = TWO_PI * (float)ph / 68.0f;
            vr = cosf(a); vi = -sinf(a);
        }
        Wfb[e]        = f2bf(vr);
        Wfb[5120 + e] = f2bf(vi);
    }
    ushort* Wib = (ushort*)(ws + 19096);  // [2][80][128] bf16 pre-swizzled
    for (int e = t; e < 80 * 96; e += 256) {
        int p = e / 96, k = e % 96;
        float vr = 0.f, vi = 0.f;
        if (p < 68 && k < 68) {
            int ph = (p * k) % 68;
            float a = TWO_PI * (float)ph / 68.0f;
            vr = cosf(a) / 68.0f; vi = sinf(a) / 68.0f;
        }
        int dst = p * 128 + (((k >> 3) ^ (p & 7)) << 3) + (k & 7);
        Wib[dst]         = f2bf(vr);
        Wib[10240 + dst] = f2bf(vi);
    }
    ushort* Wgb = (ushort*)(ws + 29336);  // [80][128] bf16 pre-swizzled
    for (int e = t; e < 80 * 96; e += 256) {
        int q = e / 96, k = e % 96;
        float v = 0.f;
        if (q < 68 && k < 70) {
            int k2 = (k < KH) ? k : (k - KH);
            int ph = (q * k2) % 68;
            float a = TWO_PI * (float)ph / 68.0f;
            float alpha = (k2 == 0 || k2 == 34) ? 1.0f : 2.0f;
            v = (k < KH) ? (alpha * cosf(a) / 68.0f)
                         : (-alpha * sinf(a) / 68.0f);
        }
        int dst = q * 128 + (((k >> 3) ^ (q & 7)) << 3) + (k & 7);
        Wgb[dst] = f2bf(v);
    }
}

// zero only the seam bands (rows/cols 66,67,132,133,198,199 of each image)
__global__ void k_zero_seams(float* out) {
    int b = blockIdx.x / 12, line = blockIdx.x % 12;
    const int seam[6] = {66, 67, 132, 133, 198, 199};
    int t = threadIdx.x;
    if (line < 6) {
        int y = seam[line];
        float4* dst = (float4*)(out + ((size_t)(b * 256 + y)) * 256 * 64);
        for (int e = t; e < 4096; e += 256) dst[e] = make_float4(0, 0, 0, 0);
    } else {
        int x = seam[line - 6];
        float4* dst = (float4*)out;
        for (int e = t; e < 4096; e += 256) {
            int y = e >> 4, f = e & 15;
            dst[(((size_t)(b * 256 + y)) * 256 + x) * 16 + f] = make_float4(0, 0, 0, 0);
        }
    }
}

// ---------- one-time: kernel spectrum -> Ktb bf16 [bin][plane][o][i_swz] ----
// Direct (no fp32 scratch): block = (k1, o-quad), LDS transpose.
__global__ __launch_bounds__(256) void k_kprep(
        const float* __restrict__ kr, const float* __restrict__ ki,
        ushort* __restrict__ Ktb) {
    __shared__ float tr[4 * 64 * KH];   // [o'][i][k2] 35.8 KB
    __shared__ float ti[4 * 64 * KH];
    int k1 = blockIdx.x >> 4, oq = blockIdx.x & 15;
    int t = threadIdx.x;
    int op = t >> 6, i = t & 63;        // one (o',i) per thread
    int o = oq * 4 + op;
    const float* srcR = kr + ((size_t)(o * 64 + i) * 68 + k1) * 68;
    const float* srcI = ki + ((size_t)(o * 64 + i) * 68 + k1) * 68;
    float* tR = tr + (op * 64 + i) * KH;
    float* tI = ti + (op * 64 + i) * KH;
    #pragma unroll 7
    for (int k2 = 0; k2 < KH; ++k2) { tR[k2] = srcR[k2]; tI[k2] = srcI[k2]; }
    __syncthreads();
    for (int e = t; e < KH * 256; e += 256) {
        int k2 = e >> 8, rem = e & 255;
        int op2 = rem >> 6, i2 = rem & 63;
        int o2 = oq * 4 + op2;
        int sw = (((i2 >> 3) ^ (o2 & 7)) << 3) + (i2 & 7);
        size_t base = ((size_t)(k1 * KH + k2)) * 8192 + (size_t)o2 * 64 + sw;
        Ktb[base]        = f2bf(tr[(op2 * 64 + i2) * KH + k2]);
        Ktb[base + 4096] = f2bf(ti[(op2 * 64 + i2) * KH + k2]);
    }
}

// ---------------- stage 1: row DFT — bf16 MFMA ----------------
// Y[nl][k2][r][i] = sum_c x[b, tr*64+r, tc*64+c, i] * Wf[k2][c]
__global__ __launch_bounds__(512) void k_fwd_row(
        const float* __restrict__ x, const ushort* __restrict__ Wfb,
        uint* __restrict__ Y, int c0) {
    __shared__ __align__(16) ushort sAr[48 * 64];
    __shared__ __align__(16) ushort sAi[48 * 64];
    __shared__ __align__(16) ushort sB[4 * 64 * 64];
    int gid = blockIdx.x;
    int lc = gid >> 8;
    int rem = gid & 255;
    int nl = rem >> 4, rq = rem & 15;
    int n = (c0 + lc) * 16 + nl;
    int b = n >> 4, tr = (n >> 2) & 3, tc = n & 3;
    int t = threadIdx.x;
    for (int e = t; e < 3072; e += 512) {
        int m = e >> 6, c = e & 63;
        int sw = (m << 6) + (((c >> 3) ^ (m & 7)) << 3) + (c & 7);
        sAr[sw] = Wfb[e];
        sAi[sw] = Wfb[5120 + e];
    }
    for (int e = t; e < 4096; e += 512) {
        int rr = e >> 10, f = e & 1023;
        int c = f >> 4, i0 = (f & 15) << 2;
        int y = tr * 64 + rq * 4 + rr;
        const float4* src = (const float4*)(x + ((size_t)(b * 256 + y) * 256
                                                 + tc * 64) * 64 + (c << 6) + i0);
        float4 v = *src;
        float vv[4] = {v.x, v.y, v.z, v.w};
        #pragma unroll
        for (int u = 0; u < 4; ++u) {
            int i = i0 + u;
            sB[(rr << 12) + (i << 6) + (((c >> 3) ^ (i & 7)) << 3) + (c & 7)]
                = f2bf(vv[u]);
        }
    }
    __syncthreads();
    uint* Yc = Y + (size_t)lc * CHS;
    int lane = t & 63, w = t >> 6;
    int lm = lane & 15, kg = lane >> 4;
    int ba0 = ((kg ^ (lm & 7)) << 3);
    int ba1 = (((kg + 4) ^ (lm & 7)) << 3);
    for (int tid = w; tid < 48; tid += 8) {
        int rr = tid / 12, rem2 = tid % 12;
        int mt = rem2 >> 2, nt = rem2 & 3;
        int am = mt * 16 + lm, bn = nt * 16 + lm;
        s16x8 a0r = *(const s16x8*)(sAr + (am << 6) + ba0);
        s16x8 a1r = *(const s16x8*)(sAr + (am << 6) + ba1);
        s16x8 a0i = *(const s16x8*)(sAi + (am << 6) + ba0);
        s16x8 a1i = *(const s16x8*)(sAi + (am << 6) + ba1);
        s16x8 b0 = *(const s16x8*)(sB + (rr << 12) + (bn << 6) + ba0);
        s16x8 b1 = *(const s16x8*)(sB + (rr << 12) + (bn << 6) + ba1);
        f32x4 yr = {0.f, 0.f, 0.f, 0.f}, yi = yr;
        yr = __builtin_amdgcn_mfma_f32_16x16x32_bf16(a0r, b0, yr, 0, 0, 0);
        yr = __builtin_amdgcn_mfma_f32_16x16x32_bf16(a1r, b1, yr, 0, 0, 0);
        yi = __builtin_amdgcn_mfma_f32_16x16x32_bf16(a0i, b0, yi, 0, 0, 0);
        yi = __builtin_amdgcn_mfma_f32_16x16x32_bf16(a1i, b1, yi, 0, 0, 0);
        int r = rq * 4 + rr;
        #pragma unroll
        for (int g2 = 0; g2 < 4; ++g2) {
            int k2 = mt * 16 + kg * 4 + g2;
            if (k2 < KH)
                Yc[((size_t)(nl * KH + k2) * 64 + r) * 64 + nt * 16 + lm]
                    = pkbf(yr[g2], yi[g2]);
        }
    }
}

// ---------------- stage 2: column DFT — bf16 MFMA ----------------
// X[nl][k1][k2][i] = sum_r Wf[k1][r] * Y[nl][k2][r][i]
__global__ __launch_bounds__(512) void k_fwd_col(
        const uint* __restrict__ Y, const ushort* __restrict__ Wfb,
        uint* __restrict__ X) {
    __shared__ __align__(16) ushort sAr[80 * 64];
    __shared__ __align__(16) ushort sAi[80 * 64];
    __shared__ __align__(16) ushort sBr[64 * 64];
    __shared__ __align__(16) ushort sBi[64 * 64];
    int lc = blockIdx.x / 560;
    int rem = blockIdx.x % 560;
    int nl = rem / KH, k2 = rem % KH;
    const uint* Yg = Y + (size_t)lc * CHS + ((size_t)(nl * KH + k2)) * 4096;
    uint* Xc = X + (size_t)lc * CHS;
    int t = threadIdx.x;
    for (int e = t; e < 5120; e += 512) {
        int m = e >> 6, r = e & 63;
        int sw = (m << 6) + ((((r >> 3) ^ (m & 7))) << 3) + (r & 7);
        sAr[sw] = Wfb[e];
        sAi[sw] = Wfb[5120 + e];
    }
    for (int e = t; e < 4096; e += 512) {
        int i = e & 63, r = e >> 6;
        uint v = Yg[e];
        int sw = (i << 6) + ((((r >> 3) ^ (i & 7))) << 3) + (r & 7);
        sBr[sw] = (ushort)(v & 0xffff);
        sBi[sw] = (ushort)(v >> 16);
    }
    __syncthreads();
    int lane = t & 63, w = t >> 6;
    int lm = lane & 15, kg = lane >> 4;
    int ba0 = ((kg ^ (lm & 7)) << 3);
    int ba1 = (((kg + 4) ^ (lm & 7)) << 3);
    for (int tid = w; tid < 20; tid += 8) {
        int mt = tid >> 2, nt = tid & 3;
        int am = mt * 16 + lm, bn = nt * 16 + lm;
        s16x8 ar0 = *(const s16x8*)(sAr + (am << 6) + ba0);
        s16x8 ar1 = *(const s16x8*)(sAr + (am << 6) + ba1);
        s16x8 ai0 = *(const s16x8*)(sAi + (am << 6) + ba0);
        s16x8 ai1 = *(const s16x8*)(sAi + (am << 6) + ba1);
        s16x8 br0 = *(const s16x8*)(sBr + (bn << 6) + ba0);
        s16x8 br1 = *(const s16x8*)(sBr + (bn << 6) + ba1);
        s16x8 bi0 = *(const s16x8*)(sBi + (bn << 6) + ba0);
        s16x8 bi1 = *(const s16x8*)(sBi + (bn << 6) + ba1);
        f32x4 rr = {0.f, 0.f, 0.f, 0.f}, ii = rr, ri = rr, ir = rr;
        rr = __builtin_amdgcn_mfma_f32_16x16x32_bf16(ar0, br0, rr, 0, 0, 0);
        rr = __builtin_amdgcn_mfma_f32_16x16x32_bf16(ar1, br1, rr, 0, 0, 0);
        ii = __builtin_amdgcn_mfma_f32_16x16x32_bf16(ai0, bi0, ii, 0, 0, 0);
        ii = __builtin_amdgcn_mfma_f32_16x16x32_bf16(ai1, bi1, ii, 0, 0, 0);
        ri = __builtin_amdgcn_mfma_f32_16x16x32_bf16(ar0, bi0, ri, 0, 0, 0);
        ri = __builtin_amdgcn_mfma_f32_16x16x32_bf16(ar1, bi1, ri, 0, 0, 0);
        ir = __builtin_amdgcn_mfma_f32_16x16x32_bf16(ai0, br0, ir, 0, 0, 0);
        ir = __builtin_amdgcn_mfma_f32_16x16x32_bf16(ai1, br1, ir, 0, 0, 0);
        #pragma unroll
        for (int g2 = 0; g2 < 4; ++g2) {
            int k1 = mt * 16 + kg * 4 + g2;
            if (k1 < 68)
                Xc[((size_t)(nl * 68 + k1) * KH + k2) * 64 + nt * 16 + lm]
                    = pkbf(rr[g2] - ii[g2], ri[g2] + ir[g2]);
        }
    }
}

// ---------------- stage 3: channel mix — bf16 MFMA ----------------
// O[nl][k2][k1][o] = sum_i X[nl][k1][k2][i] * K[bin][i][o]
__global__ __launch_bounds__(256) void k_mix(
        const uint* __restrict__ X, const ushort* __restrict__ Ktb,
        uint* __restrict__ O) {
    __shared__ __align__(16) ushort sAr[16 * 64];
    __shared__ __align__(16) ushort sAi[16 * 64];
    __shared__ __align__(16) ushort sB[2 * 64 * 64];
    int lc = blockIdx.x / 2380;
    int bin = blockIdx.x % 2380;
    int k1 = bin / KH, k2 = bin % KH;
    const uint* Xc = X + (size_t)lc * CHS;
    uint* Oc = O + (size_t)lc * CHS;
    int t = threadIdx.x;
    for (int e = t; e < 1024; e += 256) {
        int n = e >> 6, i = e & 63;
        uint v = Xc[((size_t)(n * 68 + k1) * KH + k2) * 64 + i];
        int sw = (n << 6) + (((i >> 3) ^ (n & 7)) << 3) + (i & 7);
        sAr[sw] = (ushort)(v & 0xffff);
        sAi[sw] = (ushort)(v >> 16);
    }
    const uint4* ksrc = (const uint4*)(Ktb + (size_t)bin * 8192);
    for (int e = t; e < 1024; e += 256) ((uint4*)sB)[e] = ksrc[e];
    __syncthreads();
    const ushort* sBr = sB;
    const ushort* sBi = sB + 4096;
    int lane = t & 63, w = t >> 6;
    int lm = lane & 15, kg = lane >> 4;
    f32x4 rr = {0.f, 0.f, 0.f, 0.f}, ii = rr, ri = rr, ir = rr;
    #pragma unroll
    for (int st = 0; st < 2; ++st) {
        int blk = kg + st * 4;
        int ao = (lm << 6) + ((blk ^ (lm & 7)) << 3);
        int bo = ((w * 16 + lm) << 6) + ((blk ^ (lm & 7)) << 3);
        s16x8 axr = *(const s16x8*)(sAr + ao);
        s16x8 axi = *(const s16x8*)(sAi + ao);
        s16x8 bxr = *(const s16x8*)(sBr + bo);
        s16x8 bxi = *(const s16x8*)(sBi + bo);
        rr = __builtin_amdgcn_mfma_f32_16x16x32_bf16(axr, bxr, rr, 0, 0, 0);
        ii = __builtin_amdgcn_mfma_f32_16x16x32_bf16(axi, bxi, ii, 0, 0, 0);
        ri = __builtin_amdgcn_mfma_f32_16x16x32_bf16(axr, bxi, ri, 0, 0, 0);
        ir = __builtin_amdgcn_mfma_f32_16x16x32_bf16(axi, bxr, ir, 0, 0, 0);
    }
    #pragma unroll
    for (int g2 = 0; g2 < 4; ++g2) {
        int n = kg * 4 + g2;
        int o = w * 16 + lm;
        Oc[(((size_t)n * KH + k2) * 68 + k1) * 64 + o]
            = pkbf(rr[g2] - ii[g2], ri[g2] + ir[g2]);
    }
}

// ---------------- stage 4: inverse column DFT — bf16 MFMA ----------------
// Z[nl][p][k2][o] = sum_k1 Wi[p][k1] * O[nl][k2][k1][o]
__global__ __launch_bounds__(512) void k_inv_col(
        const uint* __restrict__ O, const ushort* __restrict__ Wib,
        uint* __restrict__ Z) {
    __shared__ __align__(16) ushort sAr[80 * 128];
    __shared__ __align__(16) ushort sAi[80 * 128];
    __shared__ __align__(16) ushort sBr[64 * 128];
    __shared__ __align__(16) ushort sBi[64 * 128];
    int lc = blockIdx.x / 560;
    int rem = blockIdx.x % 560;
    int nl = rem / KH, k2 = rem % KH;
    int t = threadIdx.x;
    const uint* Ob = O + (size_t)lc * CHS + ((size_t)nl * KH + k2) * 68 * 64;
    uint* Zc = Z + (size_t)lc * CHS;
    const uint4* wsrc = (const uint4*)Wib;
    for (int e = t; e < 1280; e += 512) ((uint4*)sAr)[e] = wsrc[e];
    for (int e = t; e < 1280; e += 512) ((uint4*)sAi)[e] = wsrc[1280 + e];
    uint4 zz = {0, 0, 0, 0};
    for (int e = t; e < 1024; e += 512) { ((uint4*)sBr)[e] = zz; ((uint4*)sBi)[e] = zz; }
    __syncthreads();
    for (int e = t; e < 4352; e += 512) {
        int k1 = e >> 6, o = e & 63;
        uint v = Ob[e];
        int sw = o * 128 + (((k1 >> 3) ^ (o & 7)) << 3) + (k1 & 7);
        sBr[sw] = (ushort)(v & 0xffff);
        sBi[sw] = (ushort)(v >> 16);
    }
    __syncthreads();
    int lane = t & 63, w = t >> 6;
    int lm = lane & 15, kg = lane >> 4;
    for (int tid = w; tid < 20; tid += 8) {
        int mt = tid >> 2, nt = tid & 3;
        int am = mt * 16 + lm, bn = nt * 16 + lm;
        f32x4 rr = {0.f, 0.f, 0.f, 0.f}, ii = rr, ri = rr, ir = rr;
        #pragma unroll
        for (int st = 0; st < 3; ++st) {
            int blk = kg + st * 4;
            int off = ((blk ^ (lm & 7)) << 3);
            s16x8 axr = *(const s16x8*)(sAr + am * 128 + off);
            s16x8 axi = *(const s16x8*)(sAi + am * 128 + off);
            s16x8 bxr = *(const s16x8*)(sBr + bn * 128 + off);
            s16x8 bxi = *(const s16x8*)(sBi + bn * 128 + off);
            rr = __builtin_amdgcn_mfma_f32_16x16x32_bf16(axr, bxr, rr, 0, 0, 0);
            ii = __builtin_amdgcn_mfma_f32_16x16x32_bf16(axi, bxi, ii, 0, 0, 0);
            ri = __builtin_amdgcn_mfma_f32_16x16x32_bf16(axr, bxi, ri, 0, 0, 0);
            ir = __builtin_amdgcn_mfma_f32_16x16x32_bf16(axi, bxr, ir, 0, 0, 0);
        }
        #pragma unroll
        for (int g2 = 0; g2 < 4; ++g2) {
            int p = mt * 16 + kg * 4 + g2;
            if (p < 68)
                Zc[(((size_t)(nl * 68 + p)) * KH + k2) * 64 + nt * 16 + lm]
                    = pkbf(rr[g2] - ii[g2], ri[g2] + ir[g2]);
        }
    }
}

// ---------------- stage 5: inverse row DFT + overlap-add — bf16 MFMA --------
// Block = (lc, nl, p-quad): Wgb staged once, 4 p-rows, double-buffered B.
__global__ __launch_bounds__(512) void k_fused_inv(
        const uint* __restrict__ Z, const ushort* __restrict__ Wgb,
        const float* __restrict__ bias, float* __restrict__ out, int c0) {
    __shared__ __align__(16) ushort sWg[80 * 128];      // 20 KB
    __shared__ __align__(16) ushort sBq[2][64 * 128];   // 32 KB
    int bid = blockIdx.x;
    int lc = bid / 272;
    int rem = bid % 272;
    int nl = rem / 17, pq = rem % 17;
    int b = c0 + lc;
    int tr = nl >> 2, tc = nl & 3;
    int t = threadIdx.x;
    const uint4* wsrc = (const uint4*)Wgb;
    for (int e = t; e < 1280; e += 512) ((uint4*)sWg)[e] = wsrc[e];
    uint4 zz = {0, 0, 0, 0};
    for (int e = t; e < 2048; e += 512) ((uint4*)sBq[0])[e] = zz;  // both bufs
    int lane = t & 63, w = t >> 6;
    int lm = lane & 15, kg = lane >> 4;
    float bv4[4];
    #pragma unroll
    for (int nt = 0; nt < 4; ++nt) bv4[nt] = bias[nt * 16 + lm];
    __syncthreads();
    for (int pp = 0; pp < 4; ++pp) {
        int p = pq * 4 + pp;
        int y = 66 * tr + p;
        if (y >= 256) break;            // block-uniform
        ushort* Bq = sBq[pp & 1];
        const uint* Zb = Z + (size_t)lc * CHS + ((size_t)(nl * 68 + p)) * KH * 64;
        for (int e = t; e < KH * 64; e += 512) {
            int k2 = e >> 6, o = e & 63;
            uint v = Zb[e];
            int kb = k2 + KH;
            Bq[o * 128 + (((k2 >> 3) ^ (o & 7)) << 3) + (k2 & 7)] = (ushort)(v & 0xffff);
            Bq[o * 128 + (((kb >> 3) ^ (o & 7)) << 3) + (kb & 7)] = (ushort)(v >> 16);
        }
        __syncthreads();
        bool rowu = !((p <= 1 && tr > 0) || (p >= 66 && tr < 3));
        float* orow = out + ((size_t)(b * 256 + y)) * 256 * 64;
        for (int tid = w; tid < 20; tid += 8) {
            int mt = tid >> 2, nt = tid & 3;
            int am = mt * 16 + lm, bn = nt * 16 + lm;
            f32x4 acc = {0.f, 0.f, 0.f, 0.f};
            #pragma unroll
            for (int st = 0; st < 3; ++st) {
                int blk = kg + st * 4;
                int off = ((blk ^ (lm & 7)) << 3);
                s16x8 av = *(const s16x8*)(sWg + am * 128 + off);
                s16x8 bv = *(const s16x8*)(Bq + bn * 128 + off);
                acc = __builtin_amdgcn_mfma_f32_16x16x32_bf16(av, bv, acc, 0, 0, 0);
            }
            int o = nt * 16 + lm;
            #pragma unroll
            for (int g2 = 0; g2 < 4; ++g2) {
                int q = mt * 16 + kg * 4 + g2;
                if (q >= 68) continue;
                int xx = 66 * tc + q;
                if (xx >= 256) continue;
                bool colu = !((q <= 1 && tc > 0) || (q >= 66 && tc < 3));
                float v = acc[g2] + bv4[nt];
                float* addr = orow + (size_t)xx * 64 + o;
                if (rowu && colu) *addr = v;
                else              atomicAdd(addr, v);
            }
        }
    }
}

extern "C" void kernel_launch(void* const* d_in, const int* in_sizes, int n_in,
                              void* d_out, int out_size, void* d_ws, size_t ws_size,
                              hipStream_t stream) {
    const float* x    = (const float*)d_in[0];
    const float* kr   = (const float*)d_in[1];
    const float* ki   = (const float*)d_in[2];
    const float* bias = (const float*)d_in[3];
    float* out = (float*)d_out;
    float* ws  = (float*)d_ws;

    int CH = 8;
    while (CH > 4 && (WS_HEAD + KTB_FLOATS + 2ull * CH * CHS) * 4ull > ws_size)
        CH >>= 1;

    ushort* Wfb  = (ushort*)(ws + 13976);
    ushort* Wib  = (ushort*)(ws + 19096);
    ushort* Wgb  = (ushort*)(ws + 29336);
    ushort* Ktb  = (ushort*)(ws + WS_HEAD);
    float*  bufA = ws + WS_HEAD + KTB_FLOATS;  // Y then O (as uint)
    float*  bufB = bufA + (size_t)CH * CHS;    // X then Z

    k_twiddle<<<1, 256, 0, stream>>>(ws);
    k_kprep<<<68 * 16, 256, 0, stream>>>(kr, ki, Ktb);
    k_zero_seams<<<96, 256, 0, stream>>>(out);

    for (int s = 0; s < 8; s += CH) {
        k_fwd_row<<<CH * 256, 512, 0, stream>>>(x, Wfb, (uint*)bufA, s);
        k_fwd_col<<<CH * 560, 512, 0, stream>>>((const uint*)bufA, Wfb, (uint*)bufB);
        k_mix<<<CH * 2380, 256, 0, stream>>>((const uint*)bufB, Ktb, (uint*)bufA);
        k_inv_col<<<CH * 560, 512, 0, stream>>>((const uint*)bufA, Wib, (uint*)bufB);
        k_fused_inv<<<CH * 272, 512, 0, stream>>>((const uint*)bufB, Wgb, bias, out, s);
    }
}

// Round 22
// 382.570 us; speedup vs baseline: 3.6830x; 1.0445x over previous
//
#include <hip/hip_runtime.h>
#include <hip/hip_bf16.h>

// FFT-tiled conv: B=8, IMG=256, CIN=COUT=64, TILE=64, FFT=68, PAD=2.
// Frequency-domain per-tile conv via DFT-as-matmul, Hermitian half-spectrum
// (k2 in [0,35)), direct overlap-add (plain stores interior, atomics on seams,
// seam bands pre-zeroed). ALL five stages run on bf16 MFMA.
// ALL intermediates (Y,X,O,Z) stored as packed bf16 complex (uint re|im<<16).
//
// Layouts (per 16-tile chunk slot of CHS uints, oversized):
//   Y  [nl][k2][r][i]    uint   ((nl*35+k2)*64+r)*64 + i
//   X  [nl][k1][k2][i]   uint   ((nl*68+k1)*35+k2)*64 + i
//   O  [nl][k2][k1][o]   uint   ((nl*35+k2)*68+k1)*64 + o
//   Z  [nl][p][k2][o]    uint   ((nl*68+p)*35+k2)*64 + o
//   Ktb[bin][2][o][i] bf16 pre-swizzled, 39 MB one-time (bin = k1*35+k2)
//
// Twiddle tables:
//   Wfb [2][80][64] bf16 rows>=68 zero              (5120 floats)
//   Wib [2][80][128] bf16 pre-swizzled, zero-pad    (10240 floats)
//   Wgb [80][128] bf16 pre-swizzled, K=[Wgr|-Wgi]   (5120 floats)

#define KH   35
#define CHS  4874240ull                       // elements per chunk slot
#define KTB_FLOATS 9748480ull
#define WS_HEAD 34456ull

typedef float f32x4 __attribute__((ext_vector_type(4)));
typedef short s16x8 __attribute__((ext_vector_type(8)));

__device__ __forceinline__ ushort f2bf(float f) {
    __hip_bfloat16 h = __float2bfloat16(f);
    return *reinterpret_cast<ushort*>(&h);
}
__device__ __forceinline__ uint pkbf(float re, float im) {
    return (uint)f2bf(re) | ((uint)f2bf(im) << 16);
}

__global__ void k_twiddle(float* ws) {
    const float TWO_PI = 6.28318530717958647692f;
    int t = threadIdx.x;
    ushort* Wfb = (ushort*)(ws + 13976);  // [2][80][64] bf16
    for (int e = t; e < 80 * 64; e += 256) {
        int k = e >> 6, r = e & 63;
        float vr = 0.f, vi = 0.f;
        if (k < 68) {
            int ph = (k * (r + 2)) % 68;
            float a = TWO_PI * (float)ph / 68.0f;
            vr = cosf(a); vi = -sinf(a);
        }
        Wfb[e]        = f2bf(vr);
        Wfb[5120 + e] = f2bf(vi);
    }
    ushort* Wib = (ushort*)(ws + 19096);  // [2][80][128] bf16 pre-swizzled
    for (int e = t; e < 80 * 96; e += 256) {
        int p = e / 96, k = e % 96;
        float vr = 0.f, vi = 0.f;
        if (p < 68 && k < 68) {
            int ph = (p * k) % 68;
            float a = TWO_PI * (float)ph / 68.0f;
            vr = cosf(a) / 68.0f; vi = sinf(a) / 68.0f;
        }
        int dst = p * 128 + (((k >> 3) ^ (p & 7)) << 3) + (k & 7);
        Wib[dst]         = f2bf(vr);
        Wib[10240 + dst] = f2bf(vi);
    }
    ushort* Wgb = (ushort*)(ws + 29336);  // [80][128] bf16 pre-swizzled
    for (int e = t; e < 80 * 96; e += 256) {
        int q = e / 96, k = e % 96;
        float v = 0.f;
        if (q < 68 && k < 70) {
            int k2 = (k < KH) ? k : (k - KH);
            int ph = (q * k2) % 68;
            float a = TWO_PI * (float)ph / 68.0f;
            float alpha = (k2 == 0 || k2 == 34) ? 1.0f : 2.0f;
            v = (k < KH) ? (alpha * cosf(a) / 68.0f)
                         : (-alpha * sinf(a) / 68.0f);
        }
        int dst = q * 128 + (((k >> 3) ^ (q & 7)) << 3) + (k & 7);
        Wgb[dst] = f2bf(v);
    }
}

// zero only the seam bands (rows/cols 66,67,132,133,198,199 of each image)
__global__ void k_zero_seams(float* out) {
    int b = blockIdx.x / 12, line = blockIdx.x % 12;
    const int seam[6] = {66, 67, 132, 133, 198, 199};
    int t = threadIdx.x;
    if (line < 6) {
        int y = seam[line];
        float4* dst = (float4*)(out + ((size_t)(b * 256 + y)) * 256 * 64);
        for (int e = t; e < 4096; e += 256) dst[e] = make_float4(0, 0, 0, 0);
    } else {
        int x = seam[line - 6];
        float4* dst = (float4*)out;
        for (int e = t; e < 4096; e += 256) {
            int y = e >> 4, f = e & 15;
            dst[(((size_t)(b * 256 + y)) * 256 + x) * 16 + f] = make_float4(0, 0, 0, 0);
        }
    }
}

// ---------- one-time: kernel spectrum -> Ktb bf16 [bin][plane][o][i_swz] ----
// Block = (k1, o-pair). 256 thr = 2 o x 64 i x 2 halves; float4 row reads.
__global__ __launch_bounds__(256) void k_kprep(
        const float* __restrict__ kr, const float* __restrict__ ki,
        ushort* __restrict__ Ktb) {
    __shared__ float tr[2 * 64 * KH];   // [op][i][k2] 17.9 KB
    __shared__ float ti[2 * 64 * KH];
    int k1 = blockIdx.x >> 5, opr = blockIdx.x & 31;
    int t = threadIdx.x;
    int h = t >> 7;                     // row half
    int rem = t & 127;
    int op = rem >> 6, i = rem & 63;
    int o = opr * 2 + op;
    const float* srcR = kr + ((size_t)(o * 64 + i) * 68 + k1) * 68;
    const float* srcI = ki + ((size_t)(o * 64 + i) * 68 + k1) * 68;
    float* tR = tr + (op * 64 + i) * KH;
    float* tI = ti + (op * 64 + i) * KH;
    #pragma unroll
    for (int j = 0; j < 4; ++j) {
        int k0 = (h * 4 + j) * 4;       // 16B-aligned (rows are mult-of-4 floats)
        float4 v = *(const float4*)(srcR + k0);
        float4 w = *(const float4*)(srcI + k0);
        tR[k0] = v.x; tR[k0 + 1] = v.y; tR[k0 + 2] = v.z; tR[k0 + 3] = v.w;
        tI[k0] = w.x; tI[k0 + 1] = w.y; tI[k0 + 2] = w.z; tI[k0 + 3] = w.w;
    }
    if (h) {
        float2 v2 = *(const float2*)(srcR + 32);
        float2 w2 = *(const float2*)(srcI + 32);
        tR[32] = v2.x; tR[33] = v2.y; tR[34] = srcR[34];
        tI[32] = w2.x; tI[33] = w2.y; tI[34] = srcI[34];
    }
    __syncthreads();
    for (int e = t; e < KH * 128; e += 256) {
        int k2 = e >> 7, rem2 = e & 127;
        int op2 = rem2 >> 6, i2 = rem2 & 63;
        int o2 = opr * 2 + op2;
        int sw = (((i2 >> 3) ^ (o2 & 7)) << 3) + (i2 & 7);
        size_t base = ((size_t)(k1 * KH + k2)) * 8192 + (size_t)o2 * 64 + sw;
        Ktb[base]        = f2bf(tr[(op2 * 64 + i2) * KH + k2]);
        Ktb[base + 4096] = f2bf(ti[(op2 * 64 + i2) * KH + k2]);
    }
}

// ---------------- stage 1: row DFT — bf16 MFMA ----------------
// Y[nl][k2][r][i] = sum_c x[b, tr*64+r, tc*64+c, i] * Wf[k2][c]
__global__ __launch_bounds__(512) void k_fwd_row(
        const float* __restrict__ x, const ushort* __restrict__ Wfb,
        uint* __restrict__ Y, int c0) {
    __shared__ __align__(16) ushort sAr[48 * 64];
    __shared__ __align__(16) ushort sAi[48 * 64];
    __shared__ __align__(16) ushort sB[4 * 64 * 64];
    int gid = blockIdx.x;
    int lc = gid >> 8;
    int rem = gid & 255;
    int nl = rem >> 4, rq = rem & 15;
    int n = (c0 + lc) * 16 + nl;
    int b = n >> 4, tr = (n >> 2) & 3, tc = n & 3;
    int t = threadIdx.x;
    for (int e = t; e < 3072; e += 512) {
        int m = e >> 6, c = e & 63;
        int sw = (m << 6) + (((c >> 3) ^ (m & 7)) << 3) + (c & 7);
        sAr[sw] = Wfb[e];
        sAi[sw] = Wfb[5120 + e];
    }
    for (int e = t; e < 4096; e += 512) {
        int rr = e >> 10, f = e & 1023;
        int c = f >> 4, i0 = (f & 15) << 2;
        int y = tr * 64 + rq * 4 + rr;
        const float4* src = (const float4*)(x + ((size_t)(b * 256 + y) * 256
                                                 + tc * 64) * 64 + (c << 6) + i0);
        float4 v = *src;
        float vv[4] = {v.x, v.y, v.z, v.w};
        #pragma unroll
        for (int u = 0; u < 4; ++u) {
            int i = i0 + u;
            sB[(rr << 12) + (i << 6) + (((c >> 3) ^ (i & 7)) << 3) + (c & 7)]
                = f2bf(vv[u]);
        }
    }
    __syncthreads();
    uint* Yc = Y + (size_t)lc * CHS;
    int lane = t & 63, w = t >> 6;
    int lm = lane & 15, kg = lane >> 4;
    int ba0 = ((kg ^ (lm & 7)) << 3);
    int ba1 = (((kg + 4) ^ (lm & 7)) << 3);
    for (int tid = w; tid < 48; tid += 8) {
        int rr = tid / 12, rem2 = tid % 12;
        int mt = rem2 >> 2, nt = rem2 & 3;
        int am = mt * 16 + lm, bn = nt * 16 + lm;
        s16x8 a0r = *(const s16x8*)(sAr + (am << 6) + ba0);
        s16x8 a1r = *(const s16x8*)(sAr + (am << 6) + ba1);
        s16x8 a0i = *(const s16x8*)(sAi + (am << 6) + ba0);
        s16x8 a1i = *(const s16x8*)(sAi + (am << 6) + ba1);
        s16x8 b0 = *(const s16x8*)(sB + (rr << 12) + (bn << 6) + ba0);
        s16x8 b1 = *(const s16x8*)(sB + (rr << 12) + (bn << 6) + ba1);
        f32x4 yr = {0.f, 0.f, 0.f, 0.f}, yi = yr;
        yr = __builtin_amdgcn_mfma_f32_16x16x32_bf16(a0r, b0, yr, 0, 0, 0);
        yr = __builtin_amdgcn_mfma_f32_16x16x32_bf16(a1r, b1, yr, 0, 0, 0);
        yi = __builtin_amdgcn_mfma_f32_16x16x32_bf16(a0i, b0, yi, 0, 0, 0);
        yi = __builtin_amdgcn_mfma_f32_16x16x32_bf16(a1i, b1, yi, 0, 0, 0);
        int r = rq * 4 + rr;
        #pragma unroll
        for (int g2 = 0; g2 < 4; ++g2) {
            int k2 = mt * 16 + kg * 4 + g2;
            if (k2 < KH)
                Yc[((size_t)(nl * KH + k2) * 64 + r) * 64 + nt * 16 + lm]
                    = pkbf(yr[g2], yi[g2]);
        }
    }
}

// ---------------- stage 2: column DFT — bf16 MFMA ----------------
// X[nl][k1][k2][i] = sum_r Wf[k1][r] * Y[nl][k2][r][i]
__global__ __launch_bounds__(512) void k_fwd_col(
        const uint* __restrict__ Y, const ushort* __restrict__ Wfb,
        uint* __restrict__ X) {
    __shared__ __align__(16) ushort sAr[80 * 64];
    __shared__ __align__(16) ushort sAi[80 * 64];
    __shared__ __align__(16) ushort sBr[64 * 64];
    __shared__ __align__(16) ushort sBi[64 * 64];
    int lc = blockIdx.x / 560;
    int rem = blockIdx.x % 560;
    int nl = rem / KH, k2 = rem % KH;
    const uint* Yg = Y + (size_t)lc * CHS + ((size_t)(nl * KH + k2)) * 4096;
    uint* Xc = X + (size_t)lc * CHS;
    int t = threadIdx.x;
    for (int e = t; e < 5120; e += 512) {
        int m = e >> 6, r = e & 63;
        int sw = (m << 6) + ((((r >> 3) ^ (m & 7))) << 3) + (r & 7);
        sAr[sw] = Wfb[e];
        sAi[sw] = Wfb[5120 + e];
    }
    for (int e = t; e < 4096; e += 512) {
        int i = e & 63, r = e >> 6;
        uint v = Yg[e];
        int sw = (i << 6) + ((((r >> 3) ^ (i & 7))) << 3) + (r & 7);
        sBr[sw] = (ushort)(v & 0xffff);
        sBi[sw] = (ushort)(v >> 16);
    }
    __syncthreads();
    int lane = t & 63, w = t >> 6;
    int lm = lane & 15, kg = lane >> 4;
    int ba0 = ((kg ^ (lm & 7)) << 3);
    int ba1 = (((kg + 4) ^ (lm & 7)) << 3);
    for (int tid = w; tid < 20; tid += 8) {
        int mt = tid >> 2, nt = tid & 3;
        int am = mt * 16 + lm, bn = nt * 16 + lm;
        s16x8 ar0 = *(const s16x8*)(sAr + (am << 6) + ba0);
        s16x8 ar1 = *(const s16x8*)(sAr + (am << 6) + ba1);
        s16x8 ai0 = *(const s16x8*)(sAi + (am << 6) + ba0);
        s16x8 ai1 = *(const s16x8*)(sAi + (am << 6) + ba1);
        s16x8 br0 = *(const s16x8*)(sBr + (bn << 6) + ba0);
        s16x8 br1 = *(const s16x8*)(sBr + (bn << 6) + ba1);
        s16x8 bi0 = *(const s16x8*)(sBi + (bn << 6) + ba0);
        s16x8 bi1 = *(const s16x8*)(sBi + (bn << 6) + ba1);
        f32x4 rr = {0.f, 0.f, 0.f, 0.f}, ii = rr, ri = rr, ir = rr;
        rr = __builtin_amdgcn_mfma_f32_16x16x32_bf16(ar0, br0, rr, 0, 0, 0);
        rr = __builtin_amdgcn_mfma_f32_16x16x32_bf16(ar1, br1, rr, 0, 0, 0);
        ii = __builtin_amdgcn_mfma_f32_16x16x32_bf16(ai0, bi0, ii, 0, 0, 0);
        ii = __builtin_amdgcn_mfma_f32_16x16x32_bf16(ai1, bi1, ii, 0, 0, 0);
        ri = __builtin_amdgcn_mfma_f32_16x16x32_bf16(ar0, bi0, ri, 0, 0, 0);
        ri = __builtin_amdgcn_mfma_f32_16x16x32_bf16(ar1, bi1, ri, 0, 0, 0);
        ir = __builtin_amdgcn_mfma_f32_16x16x32_bf16(ai0, br0, ir, 0, 0, 0);
        ir = __builtin_amdgcn_mfma_f32_16x16x32_bf16(ai1, br1, ir, 0, 0, 0);
        #pragma unroll
        for (int g2 = 0; g2 < 4; ++g2) {
            int k1 = mt * 16 + kg * 4 + g2;
            if (k1 < 68)
                Xc[((size_t)(nl * 68 + k1) * KH + k2) * 64 + nt * 16 + lm]
                    = pkbf(rr[g2] - ii[g2], ri[g2] + ir[g2]);
        }
    }
}

// ---------------- stage 3: channel mix — bf16 MFMA ----------------
// O[nl][k2][k1][o] = sum_i X[nl][k1][k2][i] * K[bin][i][o]
// Grid is bin-major: CH consecutive blocks share one Ktb bin (L2 reuse).
__global__ __launch_bounds__(256) void k_mix(
        const uint* __restrict__ X, const ushort* __restrict__ Ktb,
        uint* __restrict__ O, int CH) {
    __shared__ __align__(16) ushort sAr[16 * 64];
    __shared__ __align__(16) ushort sAi[16 * 64];
    __shared__ __align__(16) ushort sB[2 * 64 * 64];
    int bin = blockIdx.x / CH;
    int lc  = blockIdx.x % CH;
    int k1 = bin / KH, k2 = bin % KH;
    const uint* Xc = X + (size_t)lc * CHS;
    uint* Oc = O + (size_t)lc * CHS;
    int t = threadIdx.x;
    for (int e = t; e < 1024; e += 256) {
        int n = e >> 6, i = e & 63;
        uint v = Xc[((size_t)(n * 68 + k1) * KH + k2) * 64 + i];
        int sw = (n << 6) + (((i >> 3) ^ (n & 7)) << 3) + (i & 7);
        sAr[sw] = (ushort)(v & 0xffff);
        sAi[sw] = (ushort)(v >> 16);
    }
    const uint4* ksrc = (const uint4*)(Ktb + (size_t)bin * 8192);
    for (int e = t; e < 1024; e += 256) ((uint4*)sB)[e] = ksrc[e];
    __syncthreads();
    const ushort* sBr = sB;
    const ushort* sBi = sB + 4096;
    int lane = t & 63, w = t >> 6;
    int lm = lane & 15, kg = lane >> 4;
    f32x4 rr = {0.f, 0.f, 0.f, 0.f}, ii = rr, ri = rr, ir = rr;
    #pragma unroll
    for (int st = 0; st < 2; ++st) {
        int blk = kg + st * 4;
        int ao = (lm << 6) + ((blk ^ (lm & 7)) << 3);
        int bo = ((w * 16 + lm) << 6) + ((blk ^ (lm & 7)) << 3);
        s16x8 axr = *(const s16x8*)(sAr + ao);
        s16x8 axi = *(const s16x8*)(sAi + ao);
        s16x8 bxr = *(const s16x8*)(sBr + bo);
        s16x8 bxi = *(const s16x8*)(sBi + bo);
        rr = __builtin_amdgcn_mfma_f32_16x16x32_bf16(axr, bxr, rr, 0, 0, 0);
        ii = __builtin_amdgcn_mfma_f32_16x16x32_bf16(axi, bxi, ii, 0, 0, 0);
        ri = __builtin_amdgcn_mfma_f32_16x16x32_bf16(axr, bxi, ri, 0, 0, 0);
        ir = __builtin_amdgcn_mfma_f32_16x16x32_bf16(axi, bxr, ir, 0, 0, 0);
    }
    #pragma unroll
    for (int g2 = 0; g2 < 4; ++g2) {
        int n = kg * 4 + g2;
        int o = w * 16 + lm;
        Oc[(((size_t)n * KH + k2) * 68 + k1) * 64 + o]
            = pkbf(rr[g2] - ii[g2], ri[g2] + ir[g2]);
    }
}

// ---------------- stage 4: inverse column DFT — bf16 MFMA ----------------
// Z[nl][p][k2][o] = sum_k1 Wi[p][k1] * O[nl][k2][k1][o]
__global__ __launch_bounds__(512) void k_inv_col(
        const uint* __restrict__ O, const ushort* __restrict__ Wib,
        uint* __restrict__ Z) {
    __shared__ __align__(16) ushort sAr[80 * 128];
    __shared__ __align__(16) ushort sAi[80 * 128];
    __shared__ __align__(16) ushort sBr[64 * 128];
    __shared__ __align__(16) ushort sBi[64 * 128];
    int lc = blockIdx.x / 560;
    int rem = blockIdx.x % 560;
    int nl = rem / KH, k2 = rem % KH;
    int t = threadIdx.x;
    const uint* Ob = O + (size_t)lc * CHS + ((size_t)nl * KH + k2) * 68 * 64;
    uint* Zc = Z + (size_t)lc * CHS;
    const uint4* wsrc = (const uint4*)Wib;
    for (int e = t; e < 1280; e += 512) ((uint4*)sAr)[e] = wsrc[e];
    for (int e = t; e < 1280; e += 512) ((uint4*)sAi)[e] = wsrc[1280 + e];
    uint4 zz = {0, 0, 0, 0};
    for (int e = t; e < 1024; e += 512) { ((uint4*)sBr)[e] = zz; ((uint4*)sBi)[e] = zz; }
    __syncthreads();
    for (int e = t; e < 4352; e += 512) {
        int k1 = e >> 6, o = e & 63;
        uint v = Ob[e];
        int sw = o * 128 + (((k1 >> 3) ^ (o & 7)) << 3) + (k1 & 7);
        sBr[sw] = (ushort)(v & 0xffff);
        sBi[sw] = (ushort)(v >> 16);
    }
    __syncthreads();
    int lane = t & 63, w = t >> 6;
    int lm = lane & 15, kg = lane >> 4;
    for (int tid = w; tid < 20; tid += 8) {
        int mt = tid >> 2, nt = tid & 3;
        int am = mt * 16 + lm, bn = nt * 16 + lm;
        f32x4 rr = {0.f, 0.f, 0.f, 0.f}, ii = rr, ri = rr, ir = rr;
        #pragma unroll
        for (int st = 0; st < 3; ++st) {
            int blk = kg + st * 4;
            int off = ((blk ^ (lm & 7)) << 3);
            s16x8 axr = *(const s16x8*)(sAr + am * 128 + off);
            s16x8 axi = *(const s16x8*)(sAi + am * 128 + off);
            s16x8 bxr = *(const s16x8*)(sBr + bn * 128 + off);
            s16x8 bxi = *(const s16x8*)(sBi + bn * 128 + off);
            rr = __builtin_amdgcn_mfma_f32_16x16x32_bf16(axr, bxr, rr, 0, 0, 0);
            ii = __builtin_amdgcn_mfma_f32_16x16x32_bf16(axi, bxi, ii, 0, 0, 0);
            ri = __builtin_amdgcn_mfma_f32_16x16x32_bf16(axr, bxi, ri, 0, 0, 0);
            ir = __builtin_amdgcn_mfma_f32_16x16x32_bf16(axi, bxr, ir, 0, 0, 0);
        }
        #pragma unroll
        for (int g2 = 0; g2 < 4; ++g2) {
            int p = mt * 16 + kg * 4 + g2;
            if (p < 68)
                Zc[(((size_t)(nl * 68 + p)) * KH + k2) * 64 + nt * 16 + lm]
                    = pkbf(rr[g2] - ii[g2], ri[g2] + ir[g2]);
        }
    }
}

// ---------------- stage 5: inverse row DFT + overlap-add — bf16 MFMA --------
// Block = (lc, nl, p-quad): Wgb staged once, 4 p-rows, double-buffered B.
__global__ __launch_bounds__(512) void k_fused_inv(
        const uint* __restrict__ Z, const ushort* __restrict__ Wgb,
        const float* __restrict__ bias, float* __restrict__ out, int c0) {
    __shared__ __align__(16) ushort sWg[80 * 128];      // 20 KB
    __shared__ __align__(16) ushort sBq[2][64 * 128];   // 32 KB
    int bid = blockIdx.x;
    int lc = bid / 272;
    int rem = bid % 272;
    int nl = rem / 17, pq = rem % 17;
    int b = c0 + lc;
    int tr = nl >> 2, tc = nl & 3;
    int t = threadIdx.x;
    const uint4* wsrc = (const uint4*)Wgb;
    for (int e = t; e < 1280; e += 512) ((uint4*)sWg)[e] = wsrc[e];
    uint4 zz = {0, 0, 0, 0};
    for (int e = t; e < 2048; e += 512) ((uint4*)sBq[0])[e] = zz;  // both bufs
    int lane = t & 63, w = t >> 6;
    int lm = lane & 15, kg = lane >> 4;
    float bv4[4];
    #pragma unroll
    for (int nt = 0; nt < 4; ++nt) bv4[nt] = bias[nt * 16 + lm];
    __syncthreads();
    for (int pp = 0; pp < 4; ++pp) {
        int p = pq * 4 + pp;
        int y = 66 * tr + p;
        if (y >= 256) break;            // block-uniform
        ushort* Bq = sBq[pp & 1];
        const uint* Zb = Z + (size_t)lc * CHS + ((size_t)(nl * 68 + p)) * KH * 64;
        for (int e = t; e < KH * 64; e += 512) {
            int k2 = e >> 6, o = e & 63;
            uint v = Zb[e];
            int kb = k2 + KH;
            Bq[o * 128 + (((k2 >> 3) ^ (o & 7)) << 3) + (k2 & 7)] = (ushort)(v & 0xffff);
            Bq[o * 128 + (((kb >> 3) ^ (o & 7)) << 3) + (kb & 7)] = (ushort)(v >> 16);
        }
        __syncthreads();
        bool rowu = !((p <= 1 && tr > 0) || (p >= 66 && tr < 3));
        float* orow = out + ((size_t)(b * 256 + y)) * 256 * 64;
        for (int tid = w; tid < 20; tid += 8) {
            int mt = tid >> 2, nt = tid & 3;
            int am = mt * 16 + lm, bn = nt * 16 + lm;
            f32x4 acc = {0.f, 0.f, 0.f, 0.f};
            #pragma unroll
            for (int st = 0; st < 3; ++st) {
                int blk = kg + st * 4;
                int off = ((blk ^ (lm & 7)) << 3);
                s16x8 av = *(const s16x8*)(sWg + am * 128 + off);
                s16x8 bv = *(const s16x8*)(Bq + bn * 128 + off);
                acc = __builtin_amdgcn_mfma_f32_16x16x32_bf16(av, bv, acc, 0, 0, 0);
            }
            int o = nt * 16 + lm;
            #pragma unroll
            for (int g2 = 0; g2 < 4; ++g2) {
                int q = mt * 16 + kg * 4 + g2;
                if (q >= 68) continue;
                int xx = 66 * tc + q;
                if (xx >= 256) continue;
                bool colu = !((q <= 1 && tc > 0) || (q >= 66 && tc < 3));
                float v = acc[g2] + bv4[nt];
                float* addr = orow + (size_t)xx * 64 + o;
                if (rowu && colu) *addr = v;
                else              atomicAdd(addr, v);
            }
        }
    }
}

extern "C" void kernel_launch(void* const* d_in, const int* in_sizes, int n_in,
                              void* d_out, int out_size, void* d_ws, size_t ws_size,
                              hipStream_t stream) {
    const float* x    = (const float*)d_in[0];
    const float* kr   = (const float*)d_in[1];
    const float* ki   = (const float*)d_in[2];
    const float* bias = (const float*)d_in[3];
    float* out = (float*)d_out;
    float* ws  = (float*)d_ws;

    int CH = 8;
    while (CH > 4 && (WS_HEAD + KTB_FLOATS + 2ull * CH * CHS) * 4ull > ws_size)
        CH >>= 1;

    ushort* Wfb  = (ushort*)(ws + 13976);
    ushort* Wib  = (ushort*)(ws + 19096);
    ushort* Wgb  = (ushort*)(ws + 29336);
    ushort* Ktb  = (ushort*)(ws + WS_HEAD);
    float*  bufA = ws + WS_HEAD + KTB_FLOATS;  // Y then O (as uint)
    float*  bufB = bufA + (size_t)CH * CHS;    // X then Z

    k_twiddle<<<1, 256, 0, stream>>>(ws);
    k_kprep<<<68 * 32, 256, 0, stream>>>(kr, ki, Ktb);
    k_zero_seams<<<96, 256, 0, stream>>>(out);

    for (int s = 0; s < 8; s += CH) {
        k_fwd_row<<<CH * 256, 512, 0, stream>>>(x, Wfb, (uint*)bufA, s);
        k_fwd_col<<<CH * 560, 512, 0, stream>>>((const uint*)bufA, Wfb, (uint*)bufB);
        k_mix<<<CH * 2380, 256, 0, stream>>>((const uint*)bufB, Ktb, (uint*)bufA, CH);
        k_inv_col<<<CH * 560, 512, 0, stream>>>((const uint*)bufA, Wib, (uint*)bufB);
        k_fused_inv<<<CH * 272, 512, 0, stream>>>((const uint*)bufB, Wgb, bias, out, s);
    }
}

// Round 23
// 361.432 us; speedup vs baseline: 3.8984x; 1.0585x over previous
//
#include <hip/hip_runtime.h>
#include <hip/hip_bf16.h>

// FFT-tiled conv: B=8, IMG=256, CIN=COUT=64, TILE=64, FFT=68, PAD=2.
// Frequency-domain per-tile conv via DFT-as-matmul, Hermitian half-spectrum
// (k2 in [0,35)), direct overlap-add (plain stores interior, atomics on seams,
// seam bands pre-zeroed). ALL five stages run on bf16 MFMA.
// ALL intermediates (Y,X,O,Z) stored as packed bf16 complex (uint re|im<<16).
//
// Layouts (per 16-tile chunk slot of CHS uints, oversized):
//   Y  [nl][k2][r][i]    uint   ((nl*35+k2)*64+r)*64 + i
//   X  [nl][k1][k2][i]   uint   ((nl*68+k1)*35+k2)*64 + i
//   O  [nl][k2][k1][o]   uint   ((nl*35+k2)*68+k1)*64 + o
//   Z  [nl][p][k2][o]    uint   ((nl*68+p)*35+k2)*64 + o
//   Ktb[bin][2][o][i] bf16 pre-swizzled, 39 MB one-time (bin = k1*35+k2)
//
// Twiddle tables:
//   Wfb [2][80][64] bf16 rows>=68 zero              (5120 floats)
//   Wib [2][80][128] bf16 pre-swizzled, zero-pad    (10240 floats)
//   Wgb [80][128] bf16 pre-swizzled, K=[Wgr|-Wgi]   (5120 floats)

#define KH   35
#define CHS  4874240ull                       // elements per chunk slot
#define KTB_FLOATS 9748480ull
#define WS_HEAD 34456ull

typedef float f32x4 __attribute__((ext_vector_type(4)));
typedef short s16x8 __attribute__((ext_vector_type(8)));

__device__ __forceinline__ ushort f2bf(float f) {
    __hip_bfloat16 h = __float2bfloat16(f);
    return *reinterpret_cast<ushort*>(&h);
}
__device__ __forceinline__ uint pkbf(float re, float im) {
    return (uint)f2bf(re) | ((uint)f2bf(im) << 16);
}

__global__ void k_twiddle(float* ws) {
    const float TWO_PI = 6.28318530717958647692f;
    int t = threadIdx.x;
    ushort* Wfb = (ushort*)(ws + 13976);  // [2][80][64] bf16
    for (int e = t; e < 80 * 64; e += 256) {
        int k = e >> 6, r = e & 63;
        float vr = 0.f, vi = 0.f;
        if (k < 68) {
            int ph = (k * (r + 2)) % 68;
            float a = TWO_PI * (float)ph / 68.0f;
            vr = cosf(a); vi = -sinf(a);
        }
        Wfb[e]        = f2bf(vr);
        Wfb[5120 + e] = f2bf(vi);
    }
    ushort* Wib = (ushort*)(ws + 19096);  // [2][80][128] bf16 pre-swizzled
    for (int e = t; e < 80 * 96; e += 256) {
        int p = e / 96, k = e % 96;
        float vr = 0.f, vi = 0.f;
        if (p < 68 && k < 68) {
            int ph = (p * k) % 68;
            float a = TWO_PI * (float)ph / 68.0f;
            vr = cosf(a) / 68.0f; vi = sinf(a) / 68.0f;
        }
        int dst = p * 128 + (((k >> 3) ^ (p & 7)) << 3) + (k & 7);
        Wib[dst]         = f2bf(vr);
        Wib[10240 + dst] = f2bf(vi);
    }
    ushort* Wgb = (ushort*)(ws + 29336);  // [80][128] bf16 pre-swizzled
    for (int e = t; e < 80 * 96; e += 256) {
        int q = e / 96, k = e % 96;
        float v = 0.f;
        if (q < 68 && k < 70) {
            int k2 = (k < KH) ? k : (k - KH);
            int ph = (q * k2) % 68;
            float a = TWO_PI * (float)ph / 68.0f;
            float alpha = (k2 == 0 || k2 == 34) ? 1.0f : 2.0f;
            v = (k < KH) ? (alpha * cosf(a) / 68.0f)
                         : (-alpha * sinf(a) / 68.0f);
        }
        int dst = q * 128 + (((k >> 3) ^ (q & 7)) << 3) + (k & 7);
        Wgb[dst] = f2bf(v);
    }
}

// zero only the seam bands (rows/cols 66,67,132,133,198,199 of each image)
__global__ void k_zero_seams(float* out) {
    int b = blockIdx.x / 12, line = blockIdx.x % 12;
    const int seam[6] = {66, 67, 132, 133, 198, 199};
    int t = threadIdx.x;
    if (line < 6) {
        int y = seam[line];
        float4* dst = (float4*)(out + ((size_t)(b * 256 + y)) * 256 * 64);
        for (int e = t; e < 4096; e += 256) dst[e] = make_float4(0, 0, 0, 0);
    } else {
        int x = seam[line - 6];
        float4* dst = (float4*)out;
        for (int e = t; e < 4096; e += 256) {
            int y = e >> 4, f = e & 15;
            dst[(((size_t)(b * 256 + y)) * 256 + x) * 16 + f] = make_float4(0, 0, 0, 0);
        }
    }
}

// ---------- one-time: kernel spectrum -> Ktb bf16 [bin][plane][o][i_swz] ----
// Block = (k1, o). 256 thr = 64 i x 4 q; q reads float4 slots q, q+4 (+tail).
__global__ __launch_bounds__(256) void k_kprep(
        const float* __restrict__ kr, const float* __restrict__ ki,
        ushort* __restrict__ Ktb) {
    __shared__ float tr[64 * KH];   // [i][k2] 8.75 KB
    __shared__ float ti[64 * KH];
    int k1 = blockIdx.x >> 6, o = blockIdx.x & 63;
    int t = threadIdx.x;
    int i = t & 63, q = t >> 6;     // q in 0..3
    const float* srcR = kr + ((size_t)(o * 64 + i) * 68 + k1) * 68;
    const float* srcI = ki + ((size_t)(o * 64 + i) * 68 + k1) * 68;
    float* tR = tr + i * KH;
    float* tI = ti + i * KH;
    #pragma unroll
    for (int s = 0; s < 2; ++s) {
        int k0 = (q + 4 * s) * 4;   // 0..31, 16B-aligned
        float4 v = *(const float4*)(srcR + k0);
        float4 w = *(const float4*)(srcI + k0);
        tR[k0] = v.x; tR[k0 + 1] = v.y; tR[k0 + 2] = v.z; tR[k0 + 3] = v.w;
        tI[k0] = w.x; tI[k0 + 1] = w.y; tI[k0 + 2] = w.z; tI[k0 + 3] = w.w;
    }
    if (q == 3) {
        float2 v2 = *(const float2*)(srcR + 32);
        float2 w2 = *(const float2*)(srcI + 32);
        tR[32] = v2.x; tR[33] = v2.y; tR[34] = srcR[34];
        tI[32] = w2.x; tI[33] = w2.y; tI[34] = srcI[34];
    }
    __syncthreads();
    for (int e = t; e < KH * 64; e += 256) {
        int k2 = e >> 6, i2 = e & 63;
        int sw = (((i2 >> 3) ^ (o & 7)) << 3) + (i2 & 7);
        size_t base = ((size_t)(k1 * KH + k2)) * 8192 + (size_t)o * 64 + sw;
        Ktb[base]        = f2bf(tr[i2 * KH + k2]);
        Ktb[base + 4096] = f2bf(ti[i2 * KH + k2]);
    }
}

// ---------------- stage 1: row DFT — bf16 MFMA ----------------
// Y[nl][k2][r][i] = sum_c x[b, tr*64+r, tc*64+c, i] * Wf[k2][c]
__global__ __launch_bounds__(512) void k_fwd_row(
        const float* __restrict__ x, const ushort* __restrict__ Wfb,
        uint* __restrict__ Y, int c0) {
    __shared__ __align__(16) ushort sAr[48 * 64];
    __shared__ __align__(16) ushort sAi[48 * 64];
    __shared__ __align__(16) ushort sB[4 * 64 * 64];
    int gid = blockIdx.x;
    int lc = gid >> 8;
    int rem = gid & 255;
    int nl = rem >> 4, rq = rem & 15;
    int n = (c0 + lc) * 16 + nl;
    int b = n >> 4, tr = (n >> 2) & 3, tc = n & 3;
    int t = threadIdx.x;
    for (int e = t; e < 3072; e += 512) {
        int m = e >> 6, c = e & 63;
        int sw = (m << 6) + (((c >> 3) ^ (m & 7)) << 3) + (c & 7);
        sAr[sw] = Wfb[e];
        sAi[sw] = Wfb[5120 + e];
    }
    for (int e = t; e < 4096; e += 512) {
        int rr = e >> 10, f = e & 1023;
        int c = f >> 4, i0 = (f & 15) << 2;
        int y = tr * 64 + rq * 4 + rr;
        const float4* src = (const float4*)(x + ((size_t)(b * 256 + y) * 256
                                                 + tc * 64) * 64 + (c << 6) + i0);
        float4 v = *src;
        float vv[4] = {v.x, v.y, v.z, v.w};
        #pragma unroll
        for (int u = 0; u < 4; ++u) {
            int i = i0 + u;
            sB[(rr << 12) + (i << 6) + (((c >> 3) ^ (i & 7)) << 3) + (c & 7)]
                = f2bf(vv[u]);
        }
    }
    __syncthreads();
    uint* Yc = Y + (size_t)lc * CHS;
    int lane = t & 63, w = t >> 6;
    int lm = lane & 15, kg = lane >> 4;
    int ba0 = ((kg ^ (lm & 7)) << 3);
    int ba1 = (((kg + 4) ^ (lm & 7)) << 3);
    for (int tid = w; tid < 48; tid += 8) {
        int rr = tid / 12, rem2 = tid % 12;
        int mt = rem2 >> 2, nt = rem2 & 3;
        int am = mt * 16 + lm, bn = nt * 16 + lm;
        s16x8 a0r = *(const s16x8*)(sAr + (am << 6) + ba0);
        s16x8 a1r = *(const s16x8*)(sAr + (am << 6) + ba1);
        s16x8 a0i = *(const s16x8*)(sAi + (am << 6) + ba0);
        s16x8 a1i = *(const s16x8*)(sAi + (am << 6) + ba1);
        s16x8 b0 = *(const s16x8*)(sB + (rr << 12) + (bn << 6) + ba0);
        s16x8 b1 = *(const s16x8*)(sB + (rr << 12) + (bn << 6) + ba1);
        f32x4 yr = {0.f, 0.f, 0.f, 0.f}, yi = yr;
        yr = __builtin_amdgcn_mfma_f32_16x16x32_bf16(a0r, b0, yr, 0, 0, 0);
        yr = __builtin_amdgcn_mfma_f32_16x16x32_bf16(a1r, b1, yr, 0, 0, 0);
        yi = __builtin_amdgcn_mfma_f32_16x16x32_bf16(a0i, b0, yi, 0, 0, 0);
        yi = __builtin_amdgcn_mfma_f32_16x16x32_bf16(a1i, b1, yi, 0, 0, 0);
        int r = rq * 4 + rr;
        #pragma unroll
        for (int g2 = 0; g2 < 4; ++g2) {
            int k2 = mt * 16 + kg * 4 + g2;
            if (k2 < KH)
                Yc[((size_t)(nl * KH + k2) * 64 + r) * 64 + nt * 16 + lm]
                    = pkbf(yr[g2], yi[g2]);
        }
    }
}

// ---------------- stage 2: column DFT — bf16 MFMA ----------------
// X[nl][k1][k2][i] = sum_r Wf[k1][r] * Y[nl][k2][r][i]
__global__ __launch_bounds__(512) void k_fwd_col(
        const uint* __restrict__ Y, const ushort* __restrict__ Wfb,
        uint* __restrict__ X) {
    __shared__ __align__(16) ushort sAr[80 * 64];
    __shared__ __align__(16) ushort sAi[80 * 64];
    __shared__ __align__(16) ushort sBr[64 * 64];
    __shared__ __align__(16) ushort sBi[64 * 64];
    int lc = blockIdx.x / 560;
    int rem = blockIdx.x % 560;
    int nl = rem / KH, k2 = rem % KH;
    const uint* Yg = Y + (size_t)lc * CHS + ((size_t)(nl * KH + k2)) * 4096;
    uint* Xc = X + (size_t)lc * CHS;
    int t = threadIdx.x;
    for (int e = t; e < 5120; e += 512) {
        int m = e >> 6, r = e & 63;
        int sw = (m << 6) + ((((r >> 3) ^ (m & 7))) << 3) + (r & 7);
        sAr[sw] = Wfb[e];
        sAi[sw] = Wfb[5120 + e];
    }
    for (int e = t; e < 4096; e += 512) {
        int i = e & 63, r = e >> 6;
        uint v = Yg[e];
        int sw = (i << 6) + ((((r >> 3) ^ (i & 7))) << 3) + (r & 7);
        sBr[sw] = (ushort)(v & 0xffff);
        sBi[sw] = (ushort)(v >> 16);
    }
    __syncthreads();
    int lane = t & 63, w = t >> 6;
    int lm = lane & 15, kg = lane >> 4;
    int ba0 = ((kg ^ (lm & 7)) << 3);
    int ba1 = (((kg + 4) ^ (lm & 7)) << 3);
    for (int tid = w; tid < 20; tid += 8) {
        int mt = tid >> 2, nt = tid & 3;
        int am = mt * 16 + lm, bn = nt * 16 + lm;
        s16x8 ar0 = *(const s16x8*)(sAr + (am << 6) + ba0);
        s16x8 ar1 = *(const s16x8*)(sAr + (am << 6) + ba1);
        s16x8 ai0 = *(const s16x8*)(sAi + (am << 6) + ba0);
        s16x8 ai1 = *(const s16x8*)(sAi + (am << 6) + ba1);
        s16x8 br0 = *(const s16x8*)(sBr + (bn << 6) + ba0);
        s16x8 br1 = *(const s16x8*)(sBr + (bn << 6) + ba1);
        s16x8 bi0 = *(const s16x8*)(sBi + (bn << 6) + ba0);
        s16x8 bi1 = *(const s16x8*)(sBi + (bn << 6) + ba1);
        f32x4 rr = {0.f, 0.f, 0.f, 0.f}, ii = rr, ri = rr, ir = rr;
        rr = __builtin_amdgcn_mfma_f32_16x16x32_bf16(ar0, br0, rr, 0, 0, 0);
        rr = __builtin_amdgcn_mfma_f32_16x16x32_bf16(ar1, br1, rr, 0, 0, 0);
        ii = __builtin_amdgcn_mfma_f32_16x16x32_bf16(ai0, bi0, ii, 0, 0, 0);
        ii = __builtin_amdgcn_mfma_f32_16x16x32_bf16(ai1, bi1, ii, 0, 0, 0);
        ri = __builtin_amdgcn_mfma_f32_16x16x32_bf16(ar0, bi0, ri, 0, 0, 0);
        ri = __builtin_amdgcn_mfma_f32_16x16x32_bf16(ar1, bi1, ri, 0, 0, 0);
        ir = __builtin_amdgcn_mfma_f32_16x16x32_bf16(ai0, br0, ir, 0, 0, 0);
        ir = __builtin_amdgcn_mfma_f32_16x16x32_bf16(ai1, br1, ir, 0, 0, 0);
        #pragma unroll
        for (int g2 = 0; g2 < 4; ++g2) {
            int k1 = mt * 16 + kg * 4 + g2;
            if (k1 < 68)
                Xc[((size_t)(nl * 68 + k1) * KH + k2) * 64 + nt * 16 + lm]
                    = pkbf(rr[g2] - ii[g2], ri[g2] + ir[g2]);
        }
    }
}

// ---------------- stage 3: channel mix — bf16 MFMA ----------------
// O[nl][k2][k1][o] = sum_i X[nl][k1][k2][i] * K[bin][i][o]
// Block = bin; Ktb staged ONCE in LDS, loop over all CH chunks.
__global__ __launch_bounds__(256) void k_mix(
        const uint* __restrict__ X, const ushort* __restrict__ Ktb,
        uint* __restrict__ O, int CH) {
    __shared__ __align__(16) ushort sAr[16 * 64];
    __shared__ __align__(16) ushort sAi[16 * 64];
    __shared__ __align__(16) ushort sB[2 * 64 * 64];
    int bin = blockIdx.x;
    int k1 = bin / KH, k2 = bin % KH;
    int t = threadIdx.x;
    const uint4* ksrc = (const uint4*)(Ktb + (size_t)bin * 8192);
    for (int e = t; e < 1024; e += 256) ((uint4*)sB)[e] = ksrc[e];
    const ushort* sBr = sB;
    const ushort* sBi = sB + 4096;
    int lane = t & 63, w = t >> 6;
    int lm = lane & 15, kg = lane >> 4;
    for (int lc = 0; lc < CH; ++lc) {
        const uint* Xc = X + (size_t)lc * CHS;
        uint* Oc = O + (size_t)lc * CHS;
        for (int e = t; e < 1024; e += 256) {
            int n = e >> 6, i = e & 63;
            uint v = Xc[((size_t)(n * 68 + k1) * KH + k2) * 64 + i];
            int sw = (n << 6) + (((i >> 3) ^ (n & 7)) << 3) + (i & 7);
            sAr[sw] = (ushort)(v & 0xffff);
            sAi[sw] = (ushort)(v >> 16);
        }
        __syncthreads();                 // covers sB on first iteration too
        f32x4 rr = {0.f, 0.f, 0.f, 0.f}, ii = rr, ri = rr, ir = rr;
        #pragma unroll
        for (int st = 0; st < 2; ++st) {
            int blk = kg + st * 4;
            int ao = (lm << 6) + ((blk ^ (lm & 7)) << 3);
            int bo = ((w * 16 + lm) << 6) + ((blk ^ (lm & 7)) << 3);
            s16x8 axr = *(const s16x8*)(sAr + ao);
            s16x8 axi = *(const s16x8*)(sAi + ao);
            s16x8 bxr = *(const s16x8*)(sBr + bo);
            s16x8 bxi = *(const s16x8*)(sBi + bo);
            rr = __builtin_amdgcn_mfma_f32_16x16x32_bf16(axr, bxr, rr, 0, 0, 0);
            ii = __builtin_amdgcn_mfma_f32_16x16x32_bf16(axi, bxi, ii, 0, 0, 0);
            ri = __builtin_amdgcn_mfma_f32_16x16x32_bf16(axr, bxi, ri, 0, 0, 0);
            ir = __builtin_amdgcn_mfma_f32_16x16x32_bf16(axi, bxr, ir, 0, 0, 0);
        }
        #pragma unroll
        for (int g2 = 0; g2 < 4; ++g2) {
            int n = kg * 4 + g2;
            int o = w * 16 + lm;
            Oc[(((size_t)n * KH + k2) * 68 + k1) * 64 + o]
                = pkbf(rr[g2] - ii[g2], ri[g2] + ir[g2]);
        }
        __syncthreads();                 // sA reads (reg loads) done before restage
    }
}

// ---------------- stage 4: inverse column DFT — bf16 MFMA ----------------
// Z[nl][p][k2][o] = sum_k1 Wi[p][k1] * O[nl][k2][k1][o]
__global__ __launch_bounds__(512) void k_inv_col(
        const uint* __restrict__ O, const ushort* __restrict__ Wib,
        uint* __restrict__ Z) {
    __shared__ __align__(16) ushort sAr[80 * 128];
    __shared__ __align__(16) ushort sAi[80 * 128];
    __shared__ __align__(16) ushort sBr[64 * 128];
    __shared__ __align__(16) ushort sBi[64 * 128];
    int lc = blockIdx.x / 560;
    int rem = blockIdx.x % 560;
    int nl = rem / KH, k2 = rem % KH;
    int t = threadIdx.x;
    const uint* Ob = O + (size_t)lc * CHS + ((size_t)nl * KH + k2) * 68 * 64;
    uint* Zc = Z + (size_t)lc * CHS;
    const uint4* wsrc = (const uint4*)Wib;
    for (int e = t; e < 1280; e += 512) ((uint4*)sAr)[e] = wsrc[e];
    for (int e = t; e < 1280; e += 512) ((uint4*)sAi)[e] = wsrc[1280 + e];
    uint4 zz = {0, 0, 0, 0};
    for (int e = t; e < 1024; e += 512) { ((uint4*)sBr)[e] = zz; ((uint4*)sBi)[e] = zz; }
    __syncthreads();
    for (int e = t; e < 4352; e += 512) {
        int k1 = e >> 6, o = e & 63;
        uint v = Ob[e];
        int sw = o * 128 + (((k1 >> 3) ^ (o & 7)) << 3) + (k1 & 7);
        sBr[sw] = (ushort)(v & 0xffff);
        sBi[sw] = (ushort)(v >> 16);
    }
    __syncthreads();
    int lane = t & 63, w = t >> 6;
    int lm = lane & 15, kg = lane >> 4;
    for (int tid = w; tid < 20; tid += 8) {
        int mt = tid >> 2, nt = tid & 3;
        int am = mt * 16 + lm, bn = nt * 16 + lm;
        f32x4 rr = {0.f, 0.f, 0.f, 0.f}, ii = rr, ri = rr, ir = rr;
        #pragma unroll
        for (int st = 0; st < 3; ++st) {
            int blk = kg + st * 4;
            int off = ((blk ^ (lm & 7)) << 3);
            s16x8 axr = *(const s16x8*)(sAr + am * 128 + off);
            s16x8 axi = *(const s16x8*)(sAi + am * 128 + off);
            s16x8 bxr = *(const s16x8*)(sBr + bn * 128 + off);
            s16x8 bxi = *(const s16x8*)(sBi + bn * 128 + off);
            rr = __builtin_amdgcn_mfma_f32_16x16x32_bf16(axr, bxr, rr, 0, 0, 0);
            ii = __builtin_amdgcn_mfma_f32_16x16x32_bf16(axi, bxi, ii, 0, 0, 0);
            ri = __builtin_amdgcn_mfma_f32_16x16x32_bf16(axr, bxi, ri, 0, 0, 0);
            ir = __builtin_amdgcn_mfma_f32_16x16x32_bf16(axi, bxr, ir, 0, 0, 0);
        }
        #pragma unroll
        for (int g2 = 0; g2 < 4; ++g2) {
            int p = mt * 16 + kg * 4 + g2;
            if (p < 68)
                Zc[(((size_t)(nl * 68 + p)) * KH + k2) * 64 + nt * 16 + lm]
                    = pkbf(rr[g2] - ii[g2], ri[g2] + ir[g2]);
        }
    }
}

// ---------------- stage 5: inverse row DFT + overlap-add — bf16 MFMA --------
// Block = (lc, nl, p-quad): Wgb staged once, 4 p-rows, double-buffered B.
__global__ __launch_bounds__(512) void k_fused_inv(
        const uint* __restrict__ Z, const ushort* __restrict__ Wgb,
        const float* __restrict__ bias, float* __restrict__ out, int c0) {
    __shared__ __align__(16) ushort sWg[80 * 128];      // 20 KB
    __shared__ __align__(16) ushort sBq[2][64 * 128];   // 32 KB
    int bid = blockIdx.x;
    int lc = bid / 272;
    int rem = bid % 272;
    int nl = rem / 17, pq = rem % 17;
    int b = c0 + lc;
    int tr = nl >> 2, tc = nl & 3;
    int t = threadIdx.x;
    const uint4* wsrc = (const uint4*)Wgb;
    for (int e = t; e < 1280; e += 512) ((uint4*)sWg)[e] = wsrc[e];
    uint4 zz = {0, 0, 0, 0};
    for (int e = t; e < 2048; e += 512) ((uint4*)sBq[0])[e] = zz;  // both bufs
    int lane = t & 63, w = t >> 6;
    int lm = lane & 15, kg = lane >> 4;
    float bv4[4];
    #pragma unroll
    for (int nt = 0; nt < 4; ++nt) bv4[nt] = bias[nt * 16 + lm];
    __syncthreads();
    for (int pp = 0; pp < 4; ++pp) {
        int p = pq * 4 + pp;
        int y = 66 * tr + p;
        if (y >= 256) break;            // block-uniform
        ushort* Bq = sBq[pp & 1];
        const uint* Zb = Z + (size_t)lc * CHS + ((size_t)(nl * 68 + p)) * KH * 64;
        for (int e = t; e < KH * 64; e += 512) {
            int k2 = e >> 6, o = e & 63;
            uint v = Zb[e];
            int kb = k2 + KH;
            Bq[o * 128 + (((k2 >> 3) ^ (o & 7)) << 3) + (k2 & 7)] = (ushort)(v & 0xffff);
            Bq[o * 128 + (((kb >> 3) ^ (o & 7)) << 3) + (kb & 7)] = (ushort)(v >> 16);
        }
        __syncthreads();
        bool rowu = !((p <= 1 && tr > 0) || (p >= 66 && tr < 3));
        float* orow = out + ((size_t)(b * 256 + y)) * 256 * 64;
        for (int tid = w; tid < 20; tid += 8) {
            int mt = tid >> 2, nt = tid & 3;
            int am = mt * 16 + lm, bn = nt * 16 + lm;
            f32x4 acc = {0.f, 0.f, 0.f, 0.f};
            #pragma unroll
            for (int st = 0; st < 3; ++st) {
                int blk = kg + st * 4;
                int off = ((blk ^ (lm & 7)) << 3);
                s16x8 av = *(const s16x8*)(sWg + am * 128 + off);
                s16x8 bv = *(const s16x8*)(Bq + bn * 128 + off);
                acc = __builtin_amdgcn_mfma_f32_16x16x32_bf16(av, bv, acc, 0, 0, 0);
            }
            int o = nt * 16 + lm;
            #pragma unroll
            for (int g2 = 0; g2 < 4; ++g2) {
                int q = mt * 16 + kg * 4 + g2;
                if (q >= 68) continue;
                int xx = 66 * tc + q;
                if (xx >= 256) continue;
                bool colu = !((q <= 1 && tc > 0) || (q >= 66 && tc < 3));
                float v = acc[g2] + bv4[nt];
                float* addr = orow + (size_t)xx * 64 + o;
                if (rowu && colu) *addr = v;
                else              atomicAdd(addr, v);
            }
        }
    }
}

extern "C" void kernel_launch(void* const* d_in, const int* in_sizes, int n_in,
                              void* d_out, int out_size, void* d_ws, size_t ws_size,
                              hipStream_t stream) {
    const float* x    = (const float*)d_in[0];
    const float* kr   = (const float*)d_in[1];
    const float* ki   = (const float*)d_in[2];
    const float* bias = (const float*)d_in[3];
    float* out = (float*)d_out;
    float* ws  = (float*)d_ws;

    int CH = 8;
    while (CH > 4 && (WS_HEAD + KTB_FLOATS + 2ull * CH * CHS) * 4ull > ws_size)
        CH >>= 1;

    ushort* Wfb  = (ushort*)(ws + 13976);
    ushort* Wib  = (ushort*)(ws + 19096);
    ushort* Wgb  = (ushort*)(ws + 29336);
    ushort* Ktb  = (ushort*)(ws + WS_HEAD);
    float*  bufA = ws + WS_HEAD + KTB_FLOATS;  // Y then O (as uint)
    float*  bufB = bufA + (size_t)CH * CHS;    // X then Z

    k_twiddle<<<1, 256, 0, stream>>>(ws);
    k_kprep<<<68 * 64, 256, 0, stream>>>(kr, ki, Ktb);
    k_zero_seams<<<96, 256, 0, stream>>>(out);

    for (int s = 0; s < 8; s += CH) {
        k_fwd_row<<<CH * 256, 512, 0, stream>>>(x, Wfb, (uint*)bufA, s);
        k_fwd_col<<<CH * 560, 512, 0, stream>>>((const uint*)bufA, Wfb, (uint*)bufB);
        k_mix<<<2380, 256, 0, stream>>>((const uint*)bufB, Ktb, (uint*)bufA, CH);
        k_inv_col<<<CH * 560, 512, 0, stream>>>((const uint*)bufA, Wib, (uint*)bufB);
        k_fused_inv<<<CH * 272, 512, 0, stream>>>((const uint*)bufB, Wgb, bias, out, s);
    }
}